// Round 8
// baseline (1544.921 us; speedup 1.0000x reference)
//
#include <hip/hip_runtime.h>
#include <hip/hip_bf16.h>
#include <cstdint>
#include <cstddef>

// ---------------------------------------------------------------------------
// Transformer encoder, 6 layers: B=2,S=2048,D=1024,H=16,HD=64,F=4096.
// QKV+FFN1: 256^2-tile 8-wave GEMM, counted-vmcnt double buffer (T2+T3+T4+T5).
// FFN2: same structure, split-K=4 -> fp32 partials. O-proj: split-K 128^2.
// Flash attention: swapped QK^T, T2 swizzle, global_load_lds staging with
// counted vmcnt (same schedule as gemm256). fp32 LN fused with SK-reduce.
// ---------------------------------------------------------------------------

typedef __bf16 bf16;
typedef __bf16 bf16x2 __attribute__((ext_vector_type(2)));
typedef __bf16 bf16x4 __attribute__((ext_vector_type(4)));
typedef __bf16 bf16x8 __attribute__((ext_vector_type(8)));
typedef float  f32x4  __attribute__((ext_vector_type(4)));

#define MFMA16(a, b, c) __builtin_amdgcn_mfma_f32_16x16x32_bf16((a), (b), (c), 0, 0, 0)

static __device__ __forceinline__ void load_lds16(const void* g, void* l) {
  __builtin_amdgcn_global_load_lds((const __attribute__((address_space(1))) void*)g,
                                   (__attribute__((address_space(3))) void*)l, 16, 0, 0);
}

#define BAR()   __builtin_amdgcn_s_barrier()
#define SCH0()  __builtin_amdgcn_sched_barrier(0)
#define VMCNT8() asm volatile("s_waitcnt vmcnt(8)" ::: "memory")
#define VMCNT4() asm volatile("s_waitcnt vmcnt(4)" ::: "memory")
#define VMCNT0() asm volatile("s_waitcnt vmcnt(0)" ::: "memory")

// ---------------- embedding + positional encoding -> bf16 x ----------------
__global__ __launch_bounds__(256) void embed_kernel(const int* __restrict__ tok,
                                                    const float* __restrict__ emb,
                                                    bf16* __restrict__ xo) {
  const int row = blockIdx.x;          // b*2048 + s
  const int s = row & 2047;
  const int t = tok[row];
  const int d0 = threadIdx.x * 4;
  const float4 e = *(const float4*)&emb[(size_t)t * 1024 + d0];
  const float* ef = (const float*)&e;
  bf16x4 o4;
#pragma unroll
  for (int j = 0; j < 4; ++j) {
    const int d = d0 + j;
    const float div = __expf(-(float)(d & ~1) * 0.00899447301950864f); // ln(1e4)/1024
    const float arg = (float)s * div;
    const float pe = (d & 1) ? cosf(arg) : sinf(arg);
    o4[j] = (bf16)(ef[j] + pe);
  }
  *(bf16x4*)&xo[(size_t)row * 1024 + d0] = o4;
}

// ------------- weight transpose: fp32 [K][N] -> bf16 [N][K], batched --------
struct TJob { const float* src; bf16* dst; int K; int N; int t0; };
struct TArgs { TJob j[6]; };

__global__ __launch_bounds__(256) void wtrans_kernel(TArgs a) {
  __shared__ float t[32][33];
  const int blk = blockIdx.x;
  const float* src = a.j[0].src; bf16* dst = a.j[0].dst;
  int K = a.j[0].K, N = a.j[0].N, t0 = a.j[0].t0;
#pragma unroll
  for (int q = 1; q < 6; ++q)
    if (blk >= a.j[q].t0) { src = a.j[q].src; dst = a.j[q].dst; K = a.j[q].K; N = a.j[q].N; t0 = a.j[q].t0; }
  const int tj = blk - t0;
  const int tilesK = K >> 5;
  const int tk = (tj % tilesK) << 5;
  const int tn = (tj / tilesK) << 5;
  const int lx = threadIdx.x & 31, ly = threadIdx.x >> 5;
#pragma unroll
  for (int i = 0; i < 4; ++i)
    t[ly + 8 * i][lx] = src[(size_t)(tk + ly + 8 * i) * N + tn + lx];
  __syncthreads();
#pragma unroll
  for (int i = 0; i < 4; ++i)
    dst[(size_t)(tn + ly + 8 * i) * K + tk + lx] = (bf16)t[lx][ly + 8 * i];
}

// -------- V transpose per layer: [bh][s][64] bf16 -> [bh][64][s] bf16 -------
__global__ __launch_bounds__(256) void vtrans_kernel(const bf16* __restrict__ v,
                                                     bf16* __restrict__ vt) {
  __shared__ bf16 t[64][72];
  const int bh = blockIdx.y;
  const int s0 = blockIdx.x * 64;
  const int tid = threadIdx.x;
#pragma unroll
  for (int it = 0; it < 2; ++it) {
    const int idx = tid + it * 256;
    const int sr = idx >> 3, h8 = (idx & 7) * 8;
    *(bf16x8*)&t[sr][h8] = *(const bf16x8*)&v[((size_t)bh * 2048 + s0 + sr) * 64 + h8];
  }
  __syncthreads();
#pragma unroll
  for (int it = 0; it < 2; ++it) {
    const int idx = tid + it * 256;
    const int hd = idx >> 3, s8 = (idx & 7) * 8;
    bf16x8 o;
#pragma unroll
    for (int j = 0; j < 8; ++j) o[j] = t[s8 + j][hd];
    *(bf16x8*)&vt[((size_t)bh * 64 + hd) * 2048 + s0 + s8] = o;
  }
}

// ================= 256x256-tile 8-wave GEMM, counted-vmcnt =================
static __device__ __forceinline__ bf16x8 ldsfrag(const bf16* base, int row, int colb) {
  int off = row * 128 + colb;
  off ^= ((off >> 7) & 7) << 4;
  return *(const bf16x8*)((const char*)base + off);
}

static __device__ __forceinline__ void stage_tile(const bf16* __restrict__ Ag,
    const bf16* __restrict__ Bg, int Kstr, int kt, bf16* lA, bf16* lB, int tid) {
  const char* wbaseA = (const char*)lA + ((tid >> 6) << 10);
  const char* wbaseB = (const char*)lB + ((tid >> 6) << 10);
#pragma unroll
  for (int s = 0; s < 4; ++s) {
    const int L = s * 8192 + tid * 16;
    const int off = L ^ (((L >> 7) & 7) << 4);
    load_lds16(Ag + (size_t)(off >> 7) * Kstr + kt * 64 + ((off & 127) >> 1),
               (void*)(wbaseA + s * 8192));
  }
#pragma unroll
  for (int s = 0; s < 4; ++s) {
    const int L = s * 8192 + tid * 16;
    const int off = L ^ (((L >> 7) & 7) << 4);
    load_lds16(Bg + (size_t)(off >> 7) * Kstr + kt * 64 + ((off & 127) >> 1),
               (void*)(wbaseB + s * 8192));
  }
}

static __device__ __forceinline__ void compute_tile(const bf16* lA, const bf16* lB,
    int wm, int wn, int lr, int lg, f32x4 (&acc)[8][4]) {
  bf16x8 bfr[4][2];
#pragma unroll
  for (int n = 0; n < 4; ++n)
#pragma unroll
    for (int kk = 0; kk < 2; ++kk)
      bfr[n][kk] = ldsfrag(lB, wn * 64 + n * 16 + lr, kk * 64 + lg * 16);
#pragma unroll
  for (int m = 0; m < 8; ++m) {
    const bf16x8 a0 = ldsfrag(lA, wm * 128 + m * 16 + lr, lg * 16);
    const bf16x8 a1 = ldsfrag(lA, wm * 128 + m * 16 + lr, 64 + lg * 16);
    __builtin_amdgcn_s_setprio(1);
#pragma unroll
    for (int n = 0; n < 4; ++n) {
      acc[m][n] = MFMA16(a0, bfr[n][0], acc[m][n]);
      acc[m][n] = MFMA16(a1, bfr[n][1], acc[m][n]);
    }
    __builtin_amdgcn_s_setprio(0);
  }
}

template <int EPI>
__global__ __launch_bounds__(512, 2) void gemm256(
    const bf16* __restrict__ A, const bf16* __restrict__ Bt,
    int Kstr, int Kloop, int Nn, int nbx,
    const float* __restrict__ bias0, const float* __restrict__ bias1,
    const float* __restrict__ bias2, bf16* __restrict__ outb,
    float* __restrict__ pout,
    bf16* __restrict__ q_out, bf16* __restrict__ k_out, bf16* __restrict__ v_out) {
  __shared__ __align__(16) bf16 lds[4][16384];   // A0,B0,A1,B1 (32KB each)
  const int bz = blockIdx.y;
  const bf16* Abase = A + (size_t)bz * Kloop;
  const bf16* Bbase = Bt + (size_t)bz * Kloop;
  const int cpx = gridDim.x >> 3;
  const int wg = (blockIdx.x & 7) * cpx + (blockIdx.x >> 3);
  const int bx = wg % nbx, by = wg / nbx;
  const int tid = threadIdx.x;
  const int lane = tid & 63, wave = tid >> 6;
  const int lr = lane & 15, lg = lane >> 4;
  const int wm = wave >> 2, wn = wave & 3;
  const int m0 = by * 256, n0 = bx * 256;

  const bf16* Ag = Abase + (size_t)m0 * Kstr;
  const bf16* Bg = Bbase + (size_t)n0 * Kstr;
  bf16* LA0 = lds[0]; bf16* LB0 = lds[1];
  bf16* LA1 = lds[2]; bf16* LB1 = lds[3];

  f32x4 acc[8][4] = {};
  const int T = Kloop >> 6;

  stage_tile(Ag, Bg, Kstr, 0, LA0, LB0, tid);
  stage_tile(Ag, Bg, Kstr, 1, LA1, LB1, tid);
  VMCNT8(); BAR(); SCH0();

  for (int t = 0; t + 3 < T; t += 2) {
    compute_tile(LA0, LB0, wm, wn, lr, lg, acc);
    BAR(); SCH0();
    stage_tile(Ag, Bg, Kstr, t + 2, LA0, LB0, tid);
    VMCNT8(); BAR(); SCH0();
    compute_tile(LA1, LB1, wm, wn, lr, lg, acc);
    BAR(); SCH0();
    stage_tile(Ag, Bg, Kstr, t + 3, LA1, LB1, tid);
    VMCNT8(); BAR(); SCH0();
  }
  compute_tile(LA0, LB0, wm, wn, lr, lg, acc);   // tile T-2
  VMCNT0(); BAR(); SCH0();                       // tile T-1 landed
  compute_tile(LA1, LB1, wm, wn, lr, lg, acc);   // tile T-1

#pragma unroll
  for (int m = 0; m < 8; ++m)
#pragma unroll
    for (int n = 0; n < 4; ++n)
#pragma unroll
      for (int r = 0; r < 4; ++r) {
        const int row = m0 + wm * 128 + m * 16 + lg * 4 + r;
        const int col = n0 + wn * 64 + n * 16 + lr;
        float val = acc[m][n][r];
        if (EPI == 0) {
          const int which = col >> 10, hc = col & 1023;
          const float* bs = (which == 0) ? bias0 : (which == 1) ? bias1 : bias2;
          bf16* dst = (which == 0) ? q_out : (which == 1) ? k_out : v_out;
          val += bs[hc];
          const int b = row >> 11, s = row & 2047;
          const int h = hc >> 6, hd = hc & 63;
          dst[(((size_t)b * 16 + h) * 2048 + s) * 64 + hd] = (bf16)val;
        } else if (EPI == 1) {
          pout[(size_t)bz * 4096 * 1024 + (size_t)row * 1024 + col] = val;
        } else {
          val += bias0[col];
          outb[(size_t)row * Nn + col] = (bf16)(val > 0.f ? val : 0.f);
        }
      }
}

// -------- split-K GEMM, 128x128 tile, N=1024: partial fp32, no bias --------
__global__ __launch_bounds__(256) void gemm_sk(
    const bf16* __restrict__ A, const bf16* __restrict__ Bt,
    int Kstride, int Kloop, int nbx, float* __restrict__ pout) {
  __shared__ __align__(16) bf16 As[128 * 32];
  __shared__ __align__(16) bf16 Bs[128 * 32];
  const int bz = blockIdx.y;
  const bf16* Ab = A + (size_t)bz * Kloop;
  const bf16* Bb = Bt + (size_t)bz * Kloop;
  float* pb = pout + (size_t)bz * 4096 * 1024;
  const int cpx = gridDim.x >> 3;
  const int wg = (blockIdx.x & 7) * cpx + (blockIdx.x >> 3);
  const int bx = wg % nbx, by = wg / nbx;
  const int tid = threadIdx.x;
  const int lane = tid & 63;
  const int wave = tid >> 6;
  const int lr = lane & 15, lg = lane >> 4;
  const int m0 = by * 128;
  const int n0 = bx * 128;
  const int wr = (wave >> 1) * 64, wc = (wave & 1) * 64;

  f32x4 acc[4][4] = {};

  const int idx0 = tid, idx1 = tid + 256;
  const char* gA0 = (const char*)(Ab + (size_t)(m0 + (idx0 >> 2)) * Kstride) + (idx0 & 3) * 16;
  const char* gA1 = (const char*)(Ab + (size_t)(m0 + (idx1 >> 2)) * Kstride) + (idx1 & 3) * 16;
  const char* gB0 = (const char*)(Bb + (size_t)(n0 + (idx0 >> 2)) * Kstride) + (idx0 & 3) * 16;
  const char* gB1 = (const char*)(Bb + (size_t)(n0 + (idx1 >> 2)) * Kstride) + (idx1 & 3) * 16;
  bf16* lA0 = &As[(wave * 64) * 8];
  bf16* lA1 = &As[(256 + wave * 64) * 8];
  bf16* lB0 = &Bs[(wave * 64) * 8];
  bf16* lB1 = &Bs[(256 + wave * 64) * 8];

  const int ksteps = Kloop >> 5;
  for (int kt = 0; kt < ksteps; ++kt) {
    load_lds16(gA0, lA0); load_lds16(gA1, lA1);
    load_lds16(gB0, lB0); load_lds16(gB1, lB1);
    gA0 += 64; gA1 += 64; gB0 += 64; gB1 += 64;
    __syncthreads();
    bf16x8 af[2], bfr[2];
    bf16x8 af2[2], bfr2[2];
#pragma unroll
    for (int i = 0; i < 4; ++i) {
      bf16x8 a = *(const bf16x8*)&As[(wr + i * 16 + lr) * 32 + lg * 8];
      if (i < 2) af[i] = a; else af2[i - 2] = a;
    }
#pragma unroll
    for (int j = 0; j < 4; ++j) {
      bf16x8 b = *(const bf16x8*)&Bs[(wc + j * 16 + lr) * 32 + lg * 8];
      if (j < 2) bfr[j] = b; else bfr2[j - 2] = b;
    }
#pragma unroll
    for (int i = 0; i < 4; ++i)
#pragma unroll
      for (int j = 0; j < 4; ++j) {
        const bf16x8 a = (i < 2) ? af[i & 1] : af2[i & 1];
        const bf16x8 b = (j < 2) ? bfr[j & 1] : bfr2[j & 1];
        acc[i][j] = MFMA16(a, b, acc[i][j]);
      }
    __syncthreads();
  }

#pragma unroll
  for (int i = 0; i < 4; ++i)
#pragma unroll
    for (int j = 0; j < 4; ++j)
#pragma unroll
      for (int r = 0; r < 4; ++r) {
        const int row = m0 + wr + i * 16 + lg * 4 + r;
        const int col = n0 + wc + j * 16 + lr;
        pb[(size_t)row * 1024 + col] = acc[i][j][r];
      }
}

// ------------------------- flash attention (per b,h) ------------------------
// grid: (S/64, B*H), 4 waves. K [bh][s][64], V^T [bh][64][s].
// Staging: global_load_lds, pre-swizzled SOURCE + linear LDS dest (rule #21),
// double-buffered with counted vmcnt(4) (gemm256 schedule). Read side uses
// the same involution: byte ^= ((row&7)<<4).
__global__ __launch_bounds__(256) void attn_kernel(const bf16* __restrict__ q,
                                                   const bf16* __restrict__ k,
                                                   const bf16* __restrict__ vt,
                                                   bf16* __restrict__ ctxo) {
  __shared__ __align__(16) bf16 Kl[2][4096];   // [64][64] swizzled
  __shared__ __align__(16) bf16 Vl[2][4096];   // rows = hd, cols = key
  __shared__ __align__(16) bf16 Pl[4][16][64];
  const int tid = threadIdx.x;
  const int lane = tid & 63, w = tid >> 6;
  const int lr = lane & 15, lg = lane >> 4;
  const int swz = lr & 7;
  const int bh = blockIdx.y;
  const int q0 = blockIdx.x * 64;

  const bf16* qp = q + ((size_t)bh * 2048 + q0 + w * 16) * 64;
  bf16x8 qf0 = *(const bf16x8*)&qp[lr * 64 + lg * 8];
  bf16x8 qf1 = *(const bf16x8*)&qp[lr * 64 + lg * 8 + 32];
  const float qs = 0.18033688011112042f;      // (1/8)*log2(e)
#pragma unroll
  for (int j = 0; j < 8; ++j) {
    qf0[j] = (bf16)((float)qf0[j] * qs);
    qf1[j] = (bf16)((float)qf1[j] * qs);
  }
  bf16x8 ones8;
#pragma unroll
  for (int j = 0; j < 8; ++j) ones8[j] = (bf16)1.0f;

  const bf16* kbase = k + (size_t)bh * 2048 * 64;
  const bf16* vtb = vt + (size_t)bh * 64 * 2048;
  const int wb = w << 10;                      // wave's 1KB slice per 4KB half

  f32x4 acc[4] = {};
  f32x4 accl = {};
  float mq = -1e30f;

  // stage one 64x64 K-chunk + V-chunk: 4 load_lds/thread, linear dest,
  // swizzled source (off = L ^ ((L>>7)&7)<<4; row=off>>7, colbytes=off&127)
  auto stage = [&](int c, bf16* dK, bf16* dV) {
    const bf16* gK = kbase + (size_t)c * 64 * 64;
    const bf16* gV = vtb + c * 64;
#pragma unroll
    for (int s = 0; s < 2; ++s) {
      const int L = s * 4096 + tid * 16;
      const int off = L ^ (((L >> 7) & 7) << 4);
      load_lds16(gK + (size_t)(off >> 7) * 64 + ((off & 127) >> 1),
                 (char*)dK + s * 4096 + wb);
      load_lds16(gV + (size_t)(off >> 7) * 2048 + ((off & 127) >> 1),
                 (char*)dV + s * 4096 + wb);
    }
  };

  auto body = [&](const bf16* Kb, const bf16* Vb) {
    // --- swapped QK^T: st[ks][r] = S*log2e [q=lr][key = ks*16 + lg*4 + r] ---
    f32x4 st[4];
    __builtin_amdgcn_s_setprio(1);
#pragma unroll
    for (int ks = 0; ks < 4; ++ks) {
      const bf16x8 kf0 = *(const bf16x8*)&Kb[(ks * 16 + lr) * 64 + ((lg ^ swz) << 3)];
      const bf16x8 kf1 = *(const bf16x8*)&Kb[(ks * 16 + lr) * 64 + (((lg + 4) ^ swz) << 3)];
      f32x4 sa = {};
      sa = MFMA16(kf0, qf0, sa);
      sa = MFMA16(kf1, qf1, sa);
      st[ks] = sa;
    }
    __builtin_amdgcn_s_setprio(0);

    // --- in-lane online softmax (log2 domain), tree max ---
    float mk[4];
#pragma unroll
    for (int ks = 0; ks < 4; ++ks)
      mk[ks] = fmaxf(fmaxf(st[ks][0], st[ks][1]), fmaxf(st[ks][2], st[ks][3]));
    float mx = fmaxf(fmaxf(mk[0], mk[1]), fmaxf(mk[2], mk[3]));
    mx = fmaxf(mx, __shfl_xor(mx, 16));
    mx = fmaxf(mx, __shfl_xor(mx, 32));
    if (!__all(mx - mq <= 8.0f)) {               // defer-max (T13)
      const float resc = exp2f(mq - mx);
      mq = mx;
      float rq[4];
#pragma unroll
      for (int r = 0; r < 4; ++r) rq[r] = __shfl(resc, lg * 4 + r);
#pragma unroll
      for (int r = 0; r < 4; ++r) {
        accl[r] *= rq[r];
#pragma unroll
        for (int jn = 0; jn < 4; ++jn) acc[jn][r] *= rq[r];
      }
    }
#pragma unroll
    for (int ks = 0; ks < 4; ++ks) {             // P pack + vectorized store
      bf16x4 pk;
#pragma unroll
      for (int r = 0; r < 4; ++r) pk[r] = (bf16)exp2f(st[ks][r] - mq);
      const int col = (((ks * 2 + (lg >> 1)) ^ swz) << 3) + ((lg & 1) << 2);
      *(bf16x4*)&Pl[w][lr][col] = pk;
    }

    // --- PV + denominators ---
    const bf16x8 pf0 = *(const bf16x8*)&Pl[w][lr][(lg ^ swz) << 3];
    const bf16x8 pf1 = *(const bf16x8*)&Pl[w][lr][((lg + 4) ^ swz) << 3];
    __builtin_amdgcn_s_setprio(1);
#pragma unroll
    for (int jn = 0; jn < 4; ++jn) {
      const bf16x8 vf0 = *(const bf16x8*)&Vb[(jn * 16 + lr) * 64 + ((lg ^ swz) << 3)];
      const bf16x8 vf1 = *(const bf16x8*)&Vb[(jn * 16 + lr) * 64 + (((lg + 4) ^ swz) << 3)];
      acc[jn] = MFMA16(pf0, vf0, acc[jn]);
      acc[jn] = MFMA16(pf1, vf1, acc[jn]);
    }
    accl = MFMA16(pf0, ones8, accl);
    accl = MFMA16(pf1, ones8, accl);
    __builtin_amdgcn_s_setprio(0);
  };

  stage(0, Kl[0], Vl[0]);
  stage(1, Kl[1], Vl[1]);
  VMCNT4(); BAR(); SCH0();                       // chunk 0 landed

  for (int c = 0; c + 3 < 32; c += 2) {
    body(Kl[0], Vl[0]);                          // chunk c
    BAR(); SCH0();                               // done reading buf0
    stage(c + 2, Kl[0], Vl[0]);
    VMCNT4(); BAR(); SCH0();                     // chunk c+1 landed
    body(Kl[1], Vl[1]);                          // chunk c+1
    BAR(); SCH0();
    stage(c + 3, Kl[1], Vl[1]);
    VMCNT4(); BAR(); SCH0();                     // chunk c+2 landed
  }
  body(Kl[0], Vl[0]);                            // chunk 30
  VMCNT0(); BAR(); SCH0();                       // chunk 31 landed
  body(Kl[1], Vl[1]);                            // chunk 31

  const int bb = bh >> 4, hh = bh & 15;
#pragma unroll
  for (int r = 0; r < 4; ++r) {
    const float inv = 1.f / accl[r];
    const size_t rowg = (size_t)bb * 2048 + q0 + w * 16 + lg * 4 + r;
#pragma unroll
    for (int jn = 0; jn < 4; ++jn)
      ctxo[rowg * 1024 + hh * 64 + jn * 16 + lr] = (bf16)(acc[jn][r] * inv);
  }
}

// ---------- fused split-K reduce + bias + residual + LayerNorm --------------
template <int NP>
__global__ __launch_bounds__(256) void ln2_kernel(const float* __restrict__ p,
                                                  const bf16* __restrict__ resid,
                                                  const float* __restrict__ bias,
                                                  const float* __restrict__ g,
                                                  const float* __restrict__ be,
                                                  bf16* __restrict__ xo) {
  const int row = blockIdx.x, tid = threadIdx.x;
  const bf16x4 rv = *(const bf16x4*)&resid[(size_t)row * 1024 + tid * 4];
  const float4 bb = ((const float4*)bias)[tid];
  float4 v;
  v.x = bb.x + (float)rv[0];
  v.y = bb.y + (float)rv[1];
  v.z = bb.z + (float)rv[2];
  v.w = bb.w + (float)rv[3];
#pragma unroll
  for (int pl = 0; pl < NP; ++pl) {
    const float4 a = ((const float4*)(p + (size_t)pl * 4096 * 1024 + (size_t)row * 1024))[tid];
    v.x += a.x; v.y += a.y; v.z += a.z; v.w += a.w;
  }
  float s = v.x + v.y + v.z + v.w;
  float s2 = v.x * v.x + v.y * v.y + v.z * v.z + v.w * v.w;
#pragma unroll
  for (int o = 32; o > 0; o >>= 1) { s += __shfl_down(s, o); s2 += __shfl_down(s2, o); }
  __shared__ float red[8];
  if ((tid & 63) == 0) { red[tid >> 6] = s; red[4 + (tid >> 6)] = s2; }
  __syncthreads();
  s = red[0] + red[1] + red[2] + red[3];
  s2 = red[4] + red[5] + red[6] + red[7];
  const float mean = s * (1.f / 1024.f);
  const float var = s2 * (1.f / 1024.f) - mean * mean;
  const float rstd = rsqrtf(var + 1e-5f);
  const float4 gv = ((const float4*)g)[tid];
  const float4 bv = ((const float4*)be)[tid];
  bf16x4 o4;
  o4[0] = (bf16)((v.x - mean) * rstd * gv.x + bv.x);
  o4[1] = (bf16)((v.y - mean) * rstd * gv.y + bv.y);
  o4[2] = (bf16)((v.z - mean) * rstd * gv.z + bv.z);
  o4[3] = (bf16)((v.w - mean) * rstd * gv.w + bv.w);
  *(bf16x4*)&xo[(size_t)row * 1024 + tid * 4] = o4;
}

// ------------------------------ bf16 -> fp32 --------------------------------
__global__ __launch_bounds__(256) void to_f32_kernel(const bf16* __restrict__ x,
                                                     float* __restrict__ o) {
  const size_t i = ((size_t)blockIdx.x * 256 + threadIdx.x) * 4;
  const bf16x4 v = *(const bf16x4*)&x[i];
  float4 f;
  f.x = (float)v[0]; f.y = (float)v[1]; f.z = (float)v[2]; f.w = (float)v[3];
  *(float4*)&o[i] = f;
}

// ----------------------------------------------------------------------------
extern "C" void kernel_launch(void* const* d_in, const int* in_sizes, int n_in,
                              void* d_out, int out_size, void* d_ws, size_t ws_size,
                              hipStream_t stream) {
  const int* tokens = (const int*)d_in[0];
  const float* emb = (const float*)d_in[2];
  const float* Wq = (const float*)d_in[3];
  const float* bq = (const float*)d_in[4];
  const float* Wk = (const float*)d_in[5];
  const float* bk = (const float*)d_in[6];
  const float* Wv = (const float*)d_in[7];
  const float* bv = (const float*)d_in[8];
  const float* Wo = (const float*)d_in[9];
  const float* bo = (const float*)d_in[10];
  const float* W1 = (const float*)d_in[11];
  const float* b1 = (const float*)d_in[12];
  const float* W2 = (const float*)d_in[13];
  const float* b2 = (const float*)d_in[14];
  const float* g1 = (const float*)d_in[15];
  const float* be1 = (const float*)d_in[16];
  const float* g2 = (const float*)d_in[17];
  const float* be2 = (const float*)d_in[18];

  char* p = (char*)d_ws;
  auto carve = [&](size_t bytes) { char* r = p; p += (bytes + 255) & ~(size_t)255; return r; };
  bf16* wt_qkv = (bf16*)carve((size_t)3072 * 1024 * 2);
  bf16* wt_o   = (bf16*)carve((size_t)1024 * 1024 * 2);
  bf16* wt_1   = (bf16*)carve((size_t)4096 * 1024 * 2);
  bf16* wt_2   = (bf16*)carve((size_t)1024 * 4096 * 2);
  bf16* xb     = (bf16*)carve((size_t)4096 * 1024 * 2);
  bf16* qb     = (bf16*)carve((size_t)4096 * 1024 * 2);
  bf16* kb     = (bf16*)carve((size_t)4096 * 1024 * 2);
  bf16* vb     = (bf16*)carve((size_t)4096 * 1024 * 2);
  bf16* vtb    = (bf16*)carve((size_t)4096 * 1024 * 2);
  bf16* ctxb   = (bf16*)carve((size_t)4096 * 1024 * 2);
  float* pb    = (float*)carve((size_t)4 * 4096 * 1024 * 4);   // split-K partials
  bf16* hb     = (bf16*)carve((size_t)4096 * 4096 * 2);

  embed_kernel<<<4096, 256, 0, stream>>>(tokens, emb, xb);

  for (int l = 0; l < 6; ++l) {
    TArgs ta;
    ta.j[0] = { Wq + (size_t)l * 1024 * 1024, wt_qkv,                  1024, 1024, 0 };
    ta.j[1] = { Wk + (size_t)l * 1024 * 1024, wt_qkv + 1024 * 1024,    1024, 1024, 1024 };
    ta.j[2] = { Wv + (size_t)l * 1024 * 1024, wt_qkv + 2 * 1024 * 1024,1024, 1024, 2048 };
    ta.j[3] = { Wo + (size_t)l * 1024 * 1024, wt_o,                    1024, 1024, 3072 };
    ta.j[4] = { W1 + (size_t)l * 1024 * 4096, wt_1,                    1024, 4096, 4096 };
    ta.j[5] = { W2 + (size_t)l * 4096 * 1024, wt_2,                    4096, 1024, 8192 };
    wtrans_kernel<<<12288, 256, 0, stream>>>(ta);

    // QKV: 256^2 tile, grid 16x12 = 192
    gemm256<0><<<192, 512, 0, stream>>>(xb, wt_qkv, 1024, 1024, 3072, 12,
        bq + (size_t)l * 1024, bk + (size_t)l * 1024, bv + (size_t)l * 1024,
        nullptr, nullptr, qb, kb, vb);

    vtrans_kernel<<<dim3(32, 32), 256, 0, stream>>>(vb, vtb);

    attn_kernel<<<dim3(32, 32), 256, 0, stream>>>(qb, kb, vtb, ctxb);

    // O-proj: split-K=2 over K=1024 (128^2)
    gemm_sk<<<dim3(256, 2), 256, 0, stream>>>(ctxb, wt_o, 1024, 512, 8, pb);
    ln2_kernel<2><<<4096, 256, 0, stream>>>(pb, xb, bo + (size_t)l * 1024,
        g1 + (size_t)l * 1024, be1 + (size_t)l * 1024, xb);

    // FFN1: 256^2 tile, grid 16x16 = 256
    gemm256<2><<<256, 512, 0, stream>>>(xb, wt_1, 1024, 1024, 4096, 16,
        b1 + (size_t)l * 4096, nullptr, nullptr, hb,
        nullptr, nullptr, nullptr, nullptr);

    // FFN2: 256^2 tile split-K=4 (K-slice 1024), grid (64,4) = 256 blocks
    gemm256<1><<<dim3(64, 4), 512, 0, stream>>>(hb, wt_2, 4096, 1024, 1024, 4,
        nullptr, nullptr, nullptr, nullptr, pb,
        nullptr, nullptr, nullptr);
    ln2_kernel<4><<<4096, 256, 0, stream>>>(pb, xb, b2 + (size_t)l * 1024,
        g2 + (size_t)l * 1024, be2 + (size_t)l * 1024, xb);
  }

  to_f32_kernel<<<4096, 256, 0, stream>>>(xb, (float*)d_out);
}

// Round 9
// 1443.064 us; speedup vs baseline: 1.0706x; 1.0706x over previous
//
#include <hip/hip_runtime.h>
#include <hip/hip_bf16.h>
#include <cstdint>
#include <cstddef>

// ---------------------------------------------------------------------------
// Transformer encoder, 6 layers: B=2,S=2048,D=1024,H=16,HD=64,F=4096.
// QKV+FFN1: 256^2-tile 8-wave GEMM, counted-vmcnt double buffer (T2+T3+T4+T5).
// FFN2: same structure, split-K=4 -> fp32 partials. O-proj: split-K 128^2.
// Flash attention: 8-wave blocks (Q=128), swapped QK^T, T2 swizzle,
// reg-staged K/V double buffer. fp32 LN fused with SK-reduce.
// ---------------------------------------------------------------------------

typedef __bf16 bf16;
typedef __bf16 bf16x2 __attribute__((ext_vector_type(2)));
typedef __bf16 bf16x4 __attribute__((ext_vector_type(4)));
typedef __bf16 bf16x8 __attribute__((ext_vector_type(8)));
typedef float  f32x4  __attribute__((ext_vector_type(4)));

#define MFMA16(a, b, c) __builtin_amdgcn_mfma_f32_16x16x32_bf16((a), (b), (c), 0, 0, 0)

static __device__ __forceinline__ void load_lds16(const void* g, void* l) {
  __builtin_amdgcn_global_load_lds((const __attribute__((address_space(1))) void*)g,
                                   (__attribute__((address_space(3))) void*)l, 16, 0, 0);
}

#define BAR()   __builtin_amdgcn_s_barrier()
#define SCH0()  __builtin_amdgcn_sched_barrier(0)
#define VMCNT8() asm volatile("s_waitcnt vmcnt(8)" ::: "memory")
#define VMCNT0() asm volatile("s_waitcnt vmcnt(0)" ::: "memory")

// ---------------- embedding + positional encoding -> bf16 x ----------------
__global__ __launch_bounds__(256) void embed_kernel(const int* __restrict__ tok,
                                                    const float* __restrict__ emb,
                                                    bf16* __restrict__ xo) {
  const int row = blockIdx.x;          // b*2048 + s
  const int s = row & 2047;
  const int t = tok[row];
  const int d0 = threadIdx.x * 4;
  const float4 e = *(const float4*)&emb[(size_t)t * 1024 + d0];
  const float* ef = (const float*)&e;
  bf16x4 o4;
#pragma unroll
  for (int j = 0; j < 4; ++j) {
    const int d = d0 + j;
    const float div = __expf(-(float)(d & ~1) * 0.00899447301950864f); // ln(1e4)/1024
    const float arg = (float)s * div;
    const float pe = (d & 1) ? cosf(arg) : sinf(arg);
    o4[j] = (bf16)(ef[j] + pe);
  }
  *(bf16x4*)&xo[(size_t)row * 1024 + d0] = o4;
}

// ------------- weight transpose: fp32 [K][N] -> bf16 [N][K], batched --------
struct TJob { const float* src; bf16* dst; int K; int N; int t0; };
struct TArgs { TJob j[6]; };

__global__ __launch_bounds__(256) void wtrans_kernel(TArgs a) {
  __shared__ float t[32][33];
  const int blk = blockIdx.x;
  const float* src = a.j[0].src; bf16* dst = a.j[0].dst;
  int K = a.j[0].K, N = a.j[0].N, t0 = a.j[0].t0;
#pragma unroll
  for (int q = 1; q < 6; ++q)
    if (blk >= a.j[q].t0) { src = a.j[q].src; dst = a.j[q].dst; K = a.j[q].K; N = a.j[q].N; t0 = a.j[q].t0; }
  const int tj = blk - t0;
  const int tilesK = K >> 5;
  const int tk = (tj % tilesK) << 5;
  const int tn = (tj / tilesK) << 5;
  const int lx = threadIdx.x & 31, ly = threadIdx.x >> 5;
#pragma unroll
  for (int i = 0; i < 4; ++i)
    t[ly + 8 * i][lx] = src[(size_t)(tk + ly + 8 * i) * N + tn + lx];
  __syncthreads();
#pragma unroll
  for (int i = 0; i < 4; ++i)
    dst[(size_t)(tn + ly + 8 * i) * K + tk + lx] = (bf16)t[lx][ly + 8 * i];
}

// -------- V transpose per layer: [bh][s][64] bf16 -> [bh][64][s] bf16 -------
__global__ __launch_bounds__(256) void vtrans_kernel(const bf16* __restrict__ v,
                                                     bf16* __restrict__ vt) {
  __shared__ bf16 t[64][72];
  const int bh = blockIdx.y;
  const int s0 = blockIdx.x * 64;
  const int tid = threadIdx.x;
#pragma unroll
  for (int it = 0; it < 2; ++it) {
    const int idx = tid + it * 256;
    const int sr = idx >> 3, h8 = (idx & 7) * 8;
    *(bf16x8*)&t[sr][h8] = *(const bf16x8*)&v[((size_t)bh * 2048 + s0 + sr) * 64 + h8];
  }
  __syncthreads();
#pragma unroll
  for (int it = 0; it < 2; ++it) {
    const int idx = tid + it * 256;
    const int hd = idx >> 3, s8 = (idx & 7) * 8;
    bf16x8 o;
#pragma unroll
    for (int j = 0; j < 8; ++j) o[j] = t[s8 + j][hd];
    *(bf16x8*)&vt[((size_t)bh * 64 + hd) * 2048 + s0 + s8] = o;
  }
}

// ================= 256x256-tile 8-wave GEMM, counted-vmcnt =================
static __device__ __forceinline__ bf16x8 ldsfrag(const bf16* base, int row, int colb) {
  int off = row * 128 + colb;
  off ^= ((off >> 7) & 7) << 4;
  return *(const bf16x8*)((const char*)base + off);
}

static __device__ __forceinline__ void stage_tile(const bf16* __restrict__ Ag,
    const bf16* __restrict__ Bg, int Kstr, int kt, bf16* lA, bf16* lB, int tid) {
  const char* wbaseA = (const char*)lA + ((tid >> 6) << 10);
  const char* wbaseB = (const char*)lB + ((tid >> 6) << 10);
#pragma unroll
  for (int s = 0; s < 4; ++s) {
    const int L = s * 8192 + tid * 16;
    const int off = L ^ (((L >> 7) & 7) << 4);
    load_lds16(Ag + (size_t)(off >> 7) * Kstr + kt * 64 + ((off & 127) >> 1),
               (void*)(wbaseA + s * 8192));
  }
#pragma unroll
  for (int s = 0; s < 4; ++s) {
    const int L = s * 8192 + tid * 16;
    const int off = L ^ (((L >> 7) & 7) << 4);
    load_lds16(Bg + (size_t)(off >> 7) * Kstr + kt * 64 + ((off & 127) >> 1),
               (void*)(wbaseB + s * 8192));
  }
}

static __device__ __forceinline__ void compute_tile(const bf16* lA, const bf16* lB,
    int wm, int wn, int lr, int lg, f32x4 (&acc)[8][4]) {
  bf16x8 bfr[4][2];
#pragma unroll
  for (int n = 0; n < 4; ++n)
#pragma unroll
    for (int kk = 0; kk < 2; ++kk)
      bfr[n][kk] = ldsfrag(lB, wn * 64 + n * 16 + lr, kk * 64 + lg * 16);
#pragma unroll
  for (int m = 0; m < 8; ++m) {
    const bf16x8 a0 = ldsfrag(lA, wm * 128 + m * 16 + lr, lg * 16);
    const bf16x8 a1 = ldsfrag(lA, wm * 128 + m * 16 + lr, 64 + lg * 16);
    __builtin_amdgcn_s_setprio(1);
#pragma unroll
    for (int n = 0; n < 4; ++n) {
      acc[m][n] = MFMA16(a0, bfr[n][0], acc[m][n]);
      acc[m][n] = MFMA16(a1, bfr[n][1], acc[m][n]);
    }
    __builtin_amdgcn_s_setprio(0);
  }
}

template <int EPI>
__global__ __launch_bounds__(512, 2) void gemm256(
    const bf16* __restrict__ A, const bf16* __restrict__ Bt,
    int Kstr, int Kloop, int Nn, int nbx,
    const float* __restrict__ bias0, const float* __restrict__ bias1,
    const float* __restrict__ bias2, bf16* __restrict__ outb,
    float* __restrict__ pout,
    bf16* __restrict__ q_out, bf16* __restrict__ k_out, bf16* __restrict__ v_out) {
  __shared__ __align__(16) bf16 lds[4][16384];   // A0,B0,A1,B1 (32KB each)
  const int bz = blockIdx.y;
  const bf16* Abase = A + (size_t)bz * Kloop;
  const bf16* Bbase = Bt + (size_t)bz * Kloop;
  const int cpx = gridDim.x >> 3;
  const int wg = (blockIdx.x & 7) * cpx + (blockIdx.x >> 3);
  const int bx = wg % nbx, by = wg / nbx;
  const int tid = threadIdx.x;
  const int lane = tid & 63, wave = tid >> 6;
  const int lr = lane & 15, lg = lane >> 4;
  const int wm = wave >> 2, wn = wave & 3;
  const int m0 = by * 256, n0 = bx * 256;

  const bf16* Ag = Abase + (size_t)m0 * Kstr;
  const bf16* Bg = Bbase + (size_t)n0 * Kstr;
  bf16* LA0 = lds[0]; bf16* LB0 = lds[1];
  bf16* LA1 = lds[2]; bf16* LB1 = lds[3];

  f32x4 acc[8][4] = {};
  const int T = Kloop >> 6;

  stage_tile(Ag, Bg, Kstr, 0, LA0, LB0, tid);
  stage_tile(Ag, Bg, Kstr, 1, LA1, LB1, tid);
  VMCNT8(); BAR(); SCH0();

  for (int t = 0; t + 3 < T; t += 2) {
    compute_tile(LA0, LB0, wm, wn, lr, lg, acc);
    BAR(); SCH0();
    stage_tile(Ag, Bg, Kstr, t + 2, LA0, LB0, tid);
    VMCNT8(); BAR(); SCH0();
    compute_tile(LA1, LB1, wm, wn, lr, lg, acc);
    BAR(); SCH0();
    stage_tile(Ag, Bg, Kstr, t + 3, LA1, LB1, tid);
    VMCNT8(); BAR(); SCH0();
  }
  compute_tile(LA0, LB0, wm, wn, lr, lg, acc);   // tile T-2
  VMCNT0(); BAR(); SCH0();                       // tile T-1 landed
  compute_tile(LA1, LB1, wm, wn, lr, lg, acc);   // tile T-1

#pragma unroll
  for (int m = 0; m < 8; ++m)
#pragma unroll
    for (int n = 0; n < 4; ++n)
#pragma unroll
      for (int r = 0; r < 4; ++r) {
        const int row = m0 + wm * 128 + m * 16 + lg * 4 + r;
        const int col = n0 + wn * 64 + n * 16 + lr;
        float val = acc[m][n][r];
        if (EPI == 0) {
          const int which = col >> 10, hc = col & 1023;
          const float* bs = (which == 0) ? bias0 : (which == 1) ? bias1 : bias2;
          bf16* dst = (which == 0) ? q_out : (which == 1) ? k_out : v_out;
          val += bs[hc];
          const int b = row >> 11, s = row & 2047;
          const int h = hc >> 6, hd = hc & 63;
          dst[(((size_t)b * 16 + h) * 2048 + s) * 64 + hd] = (bf16)val;
        } else if (EPI == 1) {
          pout[(size_t)bz * 4096 * 1024 + (size_t)row * 1024 + col] = val;
        } else {
          val += bias0[col];
          outb[(size_t)row * Nn + col] = (bf16)(val > 0.f ? val : 0.f);
        }
      }
}

// -------- split-K GEMM, 128x128 tile, N=1024: partial fp32, no bias --------
__global__ __launch_bounds__(256) void gemm_sk(
    const bf16* __restrict__ A, const bf16* __restrict__ Bt,
    int Kstride, int Kloop, int nbx, float* __restrict__ pout) {
  __shared__ __align__(16) bf16 As[128 * 32];
  __shared__ __align__(16) bf16 Bs[128 * 32];
  const int bz = blockIdx.y;
  const bf16* Ab = A + (size_t)bz * Kloop;
  const bf16* Bb = Bt + (size_t)bz * Kloop;
  float* pb = pout + (size_t)bz * 4096 * 1024;
  const int cpx = gridDim.x >> 3;
  const int wg = (blockIdx.x & 7) * cpx + (blockIdx.x >> 3);
  const int bx = wg % nbx, by = wg / nbx;
  const int tid = threadIdx.x;
  const int lane = tid & 63;
  const int wave = tid >> 6;
  const int lr = lane & 15, lg = lane >> 4;
  const int m0 = by * 128;
  const int n0 = bx * 128;
  const int wr = (wave >> 1) * 64, wc = (wave & 1) * 64;

  f32x4 acc[4][4] = {};

  const int idx0 = tid, idx1 = tid + 256;
  const char* gA0 = (const char*)(Ab + (size_t)(m0 + (idx0 >> 2)) * Kstride) + (idx0 & 3) * 16;
  const char* gA1 = (const char*)(Ab + (size_t)(m0 + (idx1 >> 2)) * Kstride) + (idx1 & 3) * 16;
  const char* gB0 = (const char*)(Bb + (size_t)(n0 + (idx0 >> 2)) * Kstride) + (idx0 & 3) * 16;
  const char* gB1 = (const char*)(Bb + (size_t)(n0 + (idx1 >> 2)) * Kstride) + (idx1 & 3) * 16;
  bf16* lA0 = &As[(wave * 64) * 8];
  bf16* lA1 = &As[(256 + wave * 64) * 8];
  bf16* lB0 = &Bs[(wave * 64) * 8];
  bf16* lB1 = &Bs[(256 + wave * 64) * 8];

  const int ksteps = Kloop >> 5;
  for (int kt = 0; kt < ksteps; ++kt) {
    load_lds16(gA0, lA0); load_lds16(gA1, lA1);
    load_lds16(gB0, lB0); load_lds16(gB1, lB1);
    gA0 += 64; gA1 += 64; gB0 += 64; gB1 += 64;
    __syncthreads();
    bf16x8 af[2], bfr[2];
    bf16x8 af2[2], bfr2[2];
#pragma unroll
    for (int i = 0; i < 4; ++i) {
      bf16x8 a = *(const bf16x8*)&As[(wr + i * 16 + lr) * 32 + lg * 8];
      if (i < 2) af[i] = a; else af2[i - 2] = a;
    }
#pragma unroll
    for (int j = 0; j < 4; ++j) {
      bf16x8 b = *(const bf16x8*)&Bs[(wc + j * 16 + lr) * 32 + lg * 8];
      if (j < 2) bfr[j] = b; else bfr2[j - 2] = b;
    }
#pragma unroll
    for (int i = 0; i < 4; ++i)
#pragma unroll
      for (int j = 0; j < 4; ++j) {
        const bf16x8 a = (i < 2) ? af[i & 1] : af2[i & 1];
        const bf16x8 b = (j < 2) ? bfr[j & 1] : bfr2[j & 1];
        acc[i][j] = MFMA16(a, b, acc[i][j]);
      }
    __syncthreads();
  }

#pragma unroll
  for (int i = 0; i < 4; ++i)
#pragma unroll
    for (int j = 0; j < 4; ++j)
#pragma unroll
      for (int r = 0; r < 4; ++r) {
        const int row = m0 + wr + i * 16 + lg * 4 + r;
        const int col = n0 + wc + j * 16 + lr;
        pb[(size_t)row * 1024 + col] = acc[i][j][r];
      }
}

// ------------------------- flash attention (per b,h) ------------------------
// grid: (S/128, B*H). block: 512 = 8 waves; wave w owns q-rows [128*bx+16w,+16)
// K in [bh][s][64]; V^T in [bh][64][s]. Reg-staged K/V double buffer (proven
// r5 structure); 8 waves share each 64-key chunk -> staging & barriers
// amortized over 2x work. XOR-swizzled LDS (col8 ^= row&7), swapped QK^T,
// log2-domain softmax with defer-max.
// NOTE: chunk loop MUST be unrolled by 2 (rule #20: runtime-indexed
// ext_vector arrays go to scratch -> 7x slowdown, round 3).
__global__ __launch_bounds__(512) void attn_kernel(const bf16* __restrict__ q,
                                                   const bf16* __restrict__ k,
                                                   const bf16* __restrict__ vt,
                                                   bf16* __restrict__ ctxo) {
  __shared__ __align__(16) bf16 Kl[64][64];
  __shared__ __align__(16) bf16 Vt[64][64];   // rows = hd, cols = key
  __shared__ __align__(16) bf16 Pl[8][16][64];
  const int tid = threadIdx.x;
  const int lane = tid & 63, w = tid >> 6;
  const int lr = lane & 15, lg = lane >> 4;
  const int swz = lr & 7;
  const int bh = blockIdx.y;
  const int q0 = blockIdx.x * 128;

  // Q fragment (B-operand rows = q), pre-scaled by (1/sqrt(64))*log2(e)
  const bf16* qp = q + ((size_t)bh * 2048 + q0 + w * 16) * 64;
  bf16x8 qf0 = *(const bf16x8*)&qp[lr * 64 + lg * 8];
  bf16x8 qf1 = *(const bf16x8*)&qp[lr * 64 + lg * 8 + 32];
  const float qs = 0.18033688011112042f;
#pragma unroll
  for (int j = 0; j < 8; ++j) {
    qf0[j] = (bf16)((float)qf0[j] * qs);
    qf1[j] = (bf16)((float)qf1[j] * qs);
  }
  bf16x8 ones8;
#pragma unroll
  for (int j = 0; j < 8; ++j) ones8[j] = (bf16)1.0f;

  const bf16* kbase = k + (size_t)bh * 2048 * 64;
  const bf16* vtb = vt + (size_t)bh * 64 * 2048;

  const int sr0 = tid >> 3;                       // 0..63: staging row
  const int c0 = (tid & 7) * 8;                   // unswizzled col
  const int cs0 = c0 ^ ((sr0 & 7) << 3);          // swizzled col

  f32x4 acc[4] = {};
  f32x4 accl = {};                                // P row-sums via ones-MFMA
  float mq = -1e30f;                              // per-lane running max (q=lr)

  bf16x8 kr[2], vr[2];
  kr[0] = *(const bf16x8*)&kbase[(size_t)sr0 * 64 + c0];
  vr[0] = *(const bf16x8*)&vtb[(size_t)sr0 * 2048 + c0];

#pragma unroll 2
  for (int c = 0; c < 32; ++c) {
    const int pp = c & 1;
    *(bf16x8*)&Kl[sr0][cs0] = kr[pp];
    *(bf16x8*)&Vt[sr0][cs0] = vr[pp];
    if (c + 1 < 32) {                              // next-chunk loads, pre-barrier
      const int key0n = (c + 1) * 64;
      kr[pp ^ 1] = *(const bf16x8*)&kbase[(size_t)(key0n + sr0) * 64 + c0];
      vr[pp ^ 1] = *(const bf16x8*)&vtb[(size_t)sr0 * 2048 + key0n + c0];
    }
    __syncthreads();

    // --- swapped QK^T: st[ks][r] = S*log2e [q=lr][key = ks*16 + lg*4 + r] ---
    f32x4 st[4];
    __builtin_amdgcn_s_setprio(1);
#pragma unroll
    for (int ks = 0; ks < 4; ++ks) {
      const bf16x8 kf0 = *(const bf16x8*)&Kl[ks * 16 + lr][(lg ^ swz) << 3];
      const bf16x8 kf1 = *(const bf16x8*)&Kl[ks * 16 + lr][((lg + 4) ^ swz) << 3];
      f32x4 sa = {};
      sa = MFMA16(kf0, qf0, sa);
      sa = MFMA16(kf1, qf1, sa);
      st[ks] = sa;
    }
    __builtin_amdgcn_s_setprio(0);

    // --- in-lane online softmax (log2 domain) ---
    float mx = st[0][0];
#pragma unroll
    for (int ks = 0; ks < 4; ++ks)
#pragma unroll
      for (int r = 0; r < 4; ++r) mx = fmaxf(mx, st[ks][r]);
    mx = fmaxf(mx, __shfl_xor(mx, 16));
    mx = fmaxf(mx, __shfl_xor(mx, 32));
    if (!__all(mx - mq <= 8.0f)) {                 // defer-max (T13)
      const float resc = exp2f(mq - mx);
      mq = mx;
      float rq[4];
#pragma unroll
      for (int r = 0; r < 4; ++r) rq[r] = __shfl(resc, lg * 4 + r);
#pragma unroll
      for (int r = 0; r < 4; ++r) {
        accl[r] *= rq[r];
#pragma unroll
        for (int jn = 0; jn < 4; ++jn) acc[jn][r] *= rq[r];
      }
    }
#pragma unroll
    for (int ks = 0; ks < 4; ++ks) {               // P pack + vectorized store
      bf16x4 pk;
#pragma unroll
      for (int r = 0; r < 4; ++r) pk[r] = (bf16)exp2f(st[ks][r] - mq);
      const int col = (((ks * 2 + (lg >> 1)) ^ swz) << 3) + ((lg & 1) << 2);
      *(bf16x4*)&Pl[w][lr][col] = pk;
    }

    // --- PV + denominators ---
    const bf16x8 pf0 = *(const bf16x8*)&Pl[w][lr][(lg ^ swz) << 3];
    const bf16x8 pf1 = *(const bf16x8*)&Pl[w][lr][((lg + 4) ^ swz) << 3];
    __builtin_amdgcn_s_setprio(1);
#pragma unroll
    for (int jn = 0; jn < 4; ++jn) {
      const bf16x8 vf0 = *(const bf16x8*)&Vt[jn * 16 + lr][(lg ^ swz) << 3];
      const bf16x8 vf1 = *(const bf16x8*)&Vt[jn * 16 + lr][((lg + 4) ^ swz) << 3];
      acc[jn] = MFMA16(pf0, vf0, acc[jn]);
      acc[jn] = MFMA16(pf1, vf1, acc[jn]);
    }
    accl = MFMA16(pf0, ones8, accl);
    accl = MFMA16(pf1, ones8, accl);
    __builtin_amdgcn_s_setprio(0);
    __syncthreads();
  }

  const int bb = bh >> 4, hh = bh & 15;
#pragma unroll
  for (int r = 0; r < 4; ++r) {
    const float inv = 1.f / accl[r];
    const size_t rowg = (size_t)bb * 2048 + q0 + w * 16 + lg * 4 + r;
#pragma unroll
    for (int jn = 0; jn < 4; ++jn)
      ctxo[rowg * 1024 + hh * 64 + jn * 16 + lr] = (bf16)(acc[jn][r] * inv);
  }
}

// ---------- fused split-K reduce + bias + residual + LayerNorm --------------
template <int NP>
__global__ __launch_bounds__(256) void ln2_kernel(const float* __restrict__ p,
                                                  const bf16* __restrict__ resid,
                                                  const float* __restrict__ bias,
                                                  const float* __restrict__ g,
                                                  const float* __restrict__ be,
                                                  bf16* __restrict__ xo) {
  const int row = blockIdx.x, tid = threadIdx.x;
  const bf16x4 rv = *(const bf16x4*)&resid[(size_t)row * 1024 + tid * 4];
  const float4 bb = ((const float4*)bias)[tid];
  float4 v;
  v.x = bb.x + (float)rv[0];
  v.y = bb.y + (float)rv[1];
  v.z = bb.z + (float)rv[2];
  v.w = bb.w + (float)rv[3];
#pragma unroll
  for (int pl = 0; pl < NP; ++pl) {
    const float4 a = ((const float4*)(p + (size_t)pl * 4096 * 1024 + (size_t)row * 1024))[tid];
    v.x += a.x; v.y += a.y; v.z += a.z; v.w += a.w;
  }
  float s = v.x + v.y + v.z + v.w;
  float s2 = v.x * v.x + v.y * v.y + v.z * v.z + v.w * v.w;
#pragma unroll
  for (int o = 32; o > 0; o >>= 1) { s += __shfl_down(s, o); s2 += __shfl_down(s2, o); }
  __shared__ float red[8];
  if ((tid & 63) == 0) { red[tid >> 6] = s; red[4 + (tid >> 6)] = s2; }
  __syncthreads();
  s = red[0] + red[1] + red[2] + red[3];
  s2 = red[4] + red[5] + red[6] + red[7];
  const float mean = s * (1.f / 1024.f);
  const float var = s2 * (1.f / 1024.f) - mean * mean;
  const float rstd = rsqrtf(var + 1e-5f);
  const float4 gv = ((const float4*)g)[tid];
  const float4 bv = ((const float4*)be)[tid];
  bf16x4 o4;
  o4[0] = (bf16)((v.x - mean) * rstd * gv.x + bv.x);
  o4[1] = (bf16)((v.y - mean) * rstd * gv.y + bv.y);
  o4[2] = (bf16)((v.z - mean) * rstd * gv.z + bv.z);
  o4[3] = (bf16)((v.w - mean) * rstd * gv.w + bv.w);
  *(bf16x4*)&xo[(size_t)row * 1024 + tid * 4] = o4;
}

// ------------------------------ bf16 -> fp32 --------------------------------
__global__ __launch_bounds__(256) void to_f32_kernel(const bf16* __restrict__ x,
                                                     float* __restrict__ o) {
  const size_t i = ((size_t)blockIdx.x * 256 + threadIdx.x) * 4;
  const bf16x4 v = *(const bf16x4*)&x[i];
  float4 f;
  f.x = (float)v[0]; f.y = (float)v[1]; f.z = (float)v[2]; f.w = (float)v[3];
  *(float4*)&o[i] = f;
}

// ----------------------------------------------------------------------------
extern "C" void kernel_launch(void* const* d_in, const int* in_sizes, int n_in,
                              void* d_out, int out_size, void* d_ws, size_t ws_size,
                              hipStream_t stream) {
  const int* tokens = (const int*)d_in[0];
  const float* emb = (const float*)d_in[2];
  const float* Wq = (const float*)d_in[3];
  const float* bq = (const float*)d_in[4];
  const float* Wk = (const float*)d_in[5];
  const float* bk = (const float*)d_in[6];
  const float* Wv = (const float*)d_in[7];
  const float* bv = (const float*)d_in[8];
  const float* Wo = (const float*)d_in[9];
  const float* bo = (const float*)d_in[10];
  const float* W1 = (const float*)d_in[11];
  const float* b1 = (const float*)d_in[12];
  const float* W2 = (const float*)d_in[13];
  const float* b2 = (const float*)d_in[14];
  const float* g1 = (const float*)d_in[15];
  const float* be1 = (const float*)d_in[16];
  const float* g2 = (const float*)d_in[17];
  const float* be2 = (const float*)d_in[18];

  char* p = (char*)d_ws;
  auto carve = [&](size_t bytes) { char* r = p; p += (bytes + 255) & ~(size_t)255; return r; };
  bf16* wt_qkv = (bf16*)carve((size_t)3072 * 1024 * 2);
  bf16* wt_o   = (bf16*)carve((size_t)1024 * 1024 * 2);
  bf16* wt_1   = (bf16*)carve((size_t)4096 * 1024 * 2);
  bf16* wt_2   = (bf16*)carve((size_t)1024 * 4096 * 2);
  bf16* xb     = (bf16*)carve((size_t)4096 * 1024 * 2);
  bf16* qb     = (bf16*)carve((size_t)4096 * 1024 * 2);
  bf16* kb     = (bf16*)carve((size_t)4096 * 1024 * 2);
  bf16* vb     = (bf16*)carve((size_t)4096 * 1024 * 2);
  bf16* vtb    = (bf16*)carve((size_t)4096 * 1024 * 2);
  bf16* ctxb   = (bf16*)carve((size_t)4096 * 1024 * 2);
  float* pb    = (float*)carve((size_t)4 * 4096 * 1024 * 4);   // split-K partials
  bf16* hb     = (bf16*)carve((size_t)4096 * 4096 * 2);

  embed_kernel<<<4096, 256, 0, stream>>>(tokens, emb, xb);

  for (int l = 0; l < 6; ++l) {
    TArgs ta;
    ta.j[0] = { Wq + (size_t)l * 1024 * 1024, wt_qkv,                  1024, 1024, 0 };
    ta.j[1] = { Wk + (size_t)l * 1024 * 1024, wt_qkv + 1024 * 1024,    1024, 1024, 1024 };
    ta.j[2] = { Wv + (size_t)l * 1024 * 1024, wt_qkv + 2 * 1024 * 1024,1024, 1024, 2048 };
    ta.j[3] = { Wo + (size_t)l * 1024 * 1024, wt_o,                    1024, 1024, 3072 };
    ta.j[4] = { W1 + (size_t)l * 1024 * 4096, wt_1,                    1024, 4096, 4096 };
    ta.j[5] = { W2 + (size_t)l * 4096 * 1024, wt_2,                    4096, 1024, 8192 };
    wtrans_kernel<<<12288, 256, 0, stream>>>(ta);

    // QKV: 256^2 tile, grid 16x12 = 192
    gemm256<0><<<192, 512, 0, stream>>>(xb, wt_qkv, 1024, 1024, 3072, 12,
        bq + (size_t)l * 1024, bk + (size_t)l * 1024, bv + (size_t)l * 1024,
        nullptr, nullptr, qb, kb, vb);

    vtrans_kernel<<<dim3(32, 32), 256, 0, stream>>>(vb, vtb);

    attn_kernel<<<dim3(16, 32), 512, 0, stream>>>(qb, kb, vtb, ctxb);

    // O-proj: split-K=2 over K=1024 (128^2)
    gemm_sk<<<dim3(256, 2), 256, 0, stream>>>(ctxb, wt_o, 1024, 512, 8, pb);
    ln2_kernel<2><<<4096, 256, 0, stream>>>(pb, xb, bo + (size_t)l * 1024,
        g1 + (size_t)l * 1024, be1 + (size_t)l * 1024, xb);

    // FFN1: 256^2 tile, grid 16x16 = 256
    gemm256<2><<<256, 512, 0, stream>>>(xb, wt_1, 1024, 1024, 4096, 16,
        b1 + (size_t)l * 4096, nullptr, nullptr, hb,
        nullptr, nullptr, nullptr, nullptr);

    // FFN2: 256^2 tile split-K=4 (K-slice 1024), grid (64,4) = 256 blocks
    gemm256<1><<<dim3(64, 4), 512, 0, stream>>>(hb, wt_2, 4096, 1024, 1024, 4,
        nullptr, nullptr, nullptr, nullptr, pb,
        nullptr, nullptr, nullptr);
    ln2_kernel<4><<<4096, 256, 0, stream>>>(pb, xb, b2 + (size_t)l * 1024,
        g2 + (size_t)l * 1024, be2 + (size_t)l * 1024, xb);
  }

  to_f32_kernel<<<4096, 256, 0, stream>>>(xb, (float*)d_out);
}

// Round 10
// 1428.695 us; speedup vs baseline: 1.0814x; 1.0101x over previous
//
#include <hip/hip_runtime.h>
#include <hip/hip_bf16.h>
#include <cstdint>
#include <cstddef>

// ---------------------------------------------------------------------------
// Transformer encoder, 6 layers: B=2,S=2048,D=1024,H=16,HD=64,F=4096.
// QKV+FFN1: 256^2-tile 8-wave GEMM, counted-vmcnt double buffer (T2+T3+T4+T5).
// O-proj+FFN2: 128^2-tile 4-wave GEMM, same schedule, single-pass K,
// epilogue bias+residual -> fp32 y. Flash attention: 8-wave blocks (Q=128),
// swapped QK^T, T2 swizzle, reg-staged K/V double buffer. fp32 LN.
// ---------------------------------------------------------------------------

typedef __bf16 bf16;
typedef __bf16 bf16x2 __attribute__((ext_vector_type(2)));
typedef __bf16 bf16x4 __attribute__((ext_vector_type(4)));
typedef __bf16 bf16x8 __attribute__((ext_vector_type(8)));
typedef float  f32x4  __attribute__((ext_vector_type(4)));

#define MFMA16(a, b, c) __builtin_amdgcn_mfma_f32_16x16x32_bf16((a), (b), (c), 0, 0, 0)

static __device__ __forceinline__ void load_lds16(const void* g, void* l) {
  __builtin_amdgcn_global_load_lds((const __attribute__((address_space(1))) void*)g,
                                   (__attribute__((address_space(3))) void*)l, 16, 0, 0);
}

#define BAR()   __builtin_amdgcn_s_barrier()
#define SCH0()  __builtin_amdgcn_sched_barrier(0)
#define VMCNT8() asm volatile("s_waitcnt vmcnt(8)" ::: "memory")
#define VMCNT0() asm volatile("s_waitcnt vmcnt(0)" ::: "memory")

// ---------------- embedding + positional encoding -> bf16 x ----------------
__global__ __launch_bounds__(256) void embed_kernel(const int* __restrict__ tok,
                                                    const float* __restrict__ emb,
                                                    bf16* __restrict__ xo) {
  const int row = blockIdx.x;          // b*2048 + s
  const int s = row & 2047;
  const int t = tok[row];
  const int d0 = threadIdx.x * 4;
  const float4 e = *(const float4*)&emb[(size_t)t * 1024 + d0];
  const float* ef = (const float*)&e;
  bf16x4 o4;
#pragma unroll
  for (int j = 0; j < 4; ++j) {
    const int d = d0 + j;
    const float div = __expf(-(float)(d & ~1) * 0.00899447301950864f); // ln(1e4)/1024
    const float arg = (float)s * div;
    const float pe = (d & 1) ? cosf(arg) : sinf(arg);
    o4[j] = (bf16)(ef[j] + pe);
  }
  *(bf16x4*)&xo[(size_t)row * 1024 + d0] = o4;
}

// ------------- weight transpose: fp32 [K][N] -> bf16 [N][K], batched --------
struct TJob { const float* src; bf16* dst; int K; int N; int t0; };
struct TArgs { TJob j[6]; };

__global__ __launch_bounds__(256) void wtrans_kernel(TArgs a) {
  __shared__ float t[32][33];
  const int blk = blockIdx.x;
  const float* src = a.j[0].src; bf16* dst = a.j[0].dst;
  int K = a.j[0].K, N = a.j[0].N, t0 = a.j[0].t0;
#pragma unroll
  for (int q = 1; q < 6; ++q)
    if (blk >= a.j[q].t0) { src = a.j[q].src; dst = a.j[q].dst; K = a.j[q].K; N = a.j[q].N; t0 = a.j[q].t0; }
  const int tj = blk - t0;
  const int tilesK = K >> 5;
  const int tk = (tj % tilesK) << 5;
  const int tn = (tj / tilesK) << 5;
  const int lx = threadIdx.x & 31, ly = threadIdx.x >> 5;
#pragma unroll
  for (int i = 0; i < 4; ++i)
    t[ly + 8 * i][lx] = src[(size_t)(tk + ly + 8 * i) * N + tn + lx];
  __syncthreads();
#pragma unroll
  for (int i = 0; i < 4; ++i)
    dst[(size_t)(tn + ly + 8 * i) * K + tk + lx] = (bf16)t[lx][ly + 8 * i];
}

// -------- V transpose per layer: [bh][s][64] bf16 -> [bh][64][s] bf16 -------
__global__ __launch_bounds__(256) void vtrans_kernel(const bf16* __restrict__ v,
                                                     bf16* __restrict__ vt) {
  __shared__ bf16 t[64][72];
  const int bh = blockIdx.y;
  const int s0 = blockIdx.x * 64;
  const int tid = threadIdx.x;
#pragma unroll
  for (int it = 0; it < 2; ++it) {
    const int idx = tid + it * 256;
    const int sr = idx >> 3, h8 = (idx & 7) * 8;
    *(bf16x8*)&t[sr][h8] = *(const bf16x8*)&v[((size_t)bh * 2048 + s0 + sr) * 64 + h8];
  }
  __syncthreads();
#pragma unroll
  for (int it = 0; it < 2; ++it) {
    const int idx = tid + it * 256;
    const int hd = idx >> 3, s8 = (idx & 7) * 8;
    bf16x8 o;
#pragma unroll
    for (int j = 0; j < 8; ++j) o[j] = t[s8 + j][hd];
    *(bf16x8*)&vt[((size_t)bh * 64 + hd) * 2048 + s0 + s8] = o;
  }
}

// ======================= shared GEMM building blocks ========================
static __device__ __forceinline__ bf16x8 ldsfrag(const bf16* base, int row, int colb) {
  int off = row * 128 + colb;
  off ^= ((off >> 7) & 7) << 4;
  return *(const bf16x8*)((const char*)base + off);
}

// ================= 256x256-tile 8-wave GEMM, counted-vmcnt =================
static __device__ __forceinline__ void stage_tile(const bf16* __restrict__ Ag,
    const bf16* __restrict__ Bg, int Kstr, int kt, bf16* lA, bf16* lB, int tid) {
  const char* wbaseA = (const char*)lA + ((tid >> 6) << 10);
  const char* wbaseB = (const char*)lB + ((tid >> 6) << 10);
#pragma unroll
  for (int s = 0; s < 4; ++s) {
    const int L = s * 8192 + tid * 16;
    const int off = L ^ (((L >> 7) & 7) << 4);
    load_lds16(Ag + (size_t)(off >> 7) * Kstr + kt * 64 + ((off & 127) >> 1),
               (void*)(wbaseA + s * 8192));
  }
#pragma unroll
  for (int s = 0; s < 4; ++s) {
    const int L = s * 8192 + tid * 16;
    const int off = L ^ (((L >> 7) & 7) << 4);
    load_lds16(Bg + (size_t)(off >> 7) * Kstr + kt * 64 + ((off & 127) >> 1),
               (void*)(wbaseB + s * 8192));
  }
}

static __device__ __forceinline__ void compute_tile(const bf16* lA, const bf16* lB,
    int wm, int wn, int lr, int lg, f32x4 (&acc)[8][4]) {
  bf16x8 bfr[4][2];
#pragma unroll
  for (int n = 0; n < 4; ++n)
#pragma unroll
    for (int kk = 0; kk < 2; ++kk)
      bfr[n][kk] = ldsfrag(lB, wn * 64 + n * 16 + lr, kk * 64 + lg * 16);
#pragma unroll
  for (int m = 0; m < 8; ++m) {
    const bf16x8 a0 = ldsfrag(lA, wm * 128 + m * 16 + lr, lg * 16);
    const bf16x8 a1 = ldsfrag(lA, wm * 128 + m * 16 + lr, 64 + lg * 16);
    __builtin_amdgcn_s_setprio(1);
#pragma unroll
    for (int n = 0; n < 4; ++n) {
      acc[m][n] = MFMA16(a0, bfr[n][0], acc[m][n]);
      acc[m][n] = MFMA16(a1, bfr[n][1], acc[m][n]);
    }
    __builtin_amdgcn_s_setprio(0);
  }
}

template <int EPI>   // 0: qkv scatter, 2: bias+relu->bf16
__global__ __launch_bounds__(512, 2) void gemm256(
    const bf16* __restrict__ A, const bf16* __restrict__ Bt,
    int Kstr, int Kloop, int Nn, int nbx,
    const float* __restrict__ bias0, const float* __restrict__ bias1,
    const float* __restrict__ bias2, bf16* __restrict__ outb,
    bf16* __restrict__ q_out, bf16* __restrict__ k_out, bf16* __restrict__ v_out) {
  __shared__ __align__(16) bf16 lds[4][16384];   // A0,B0,A1,B1 (32KB each)
  const int cpx = gridDim.x >> 3;
  const int wg = (blockIdx.x & 7) * cpx + (blockIdx.x >> 3);
  const int bx = wg % nbx, by = wg / nbx;
  const int tid = threadIdx.x;
  const int lane = tid & 63, wave = tid >> 6;
  const int lr = lane & 15, lg = lane >> 4;
  const int wm = wave >> 2, wn = wave & 3;
  const int m0 = by * 256, n0 = bx * 256;

  const bf16* Ag = A + (size_t)m0 * Kstr;
  const bf16* Bg = Bt + (size_t)n0 * Kstr;
  bf16* LA0 = lds[0]; bf16* LB0 = lds[1];
  bf16* LA1 = lds[2]; bf16* LB1 = lds[3];

  f32x4 acc[8][4] = {};
  const int T = Kloop >> 6;

  stage_tile(Ag, Bg, Kstr, 0, LA0, LB0, tid);
  stage_tile(Ag, Bg, Kstr, 1, LA1, LB1, tid);
  VMCNT8(); BAR(); SCH0();

  for (int t = 0; t + 3 < T; t += 2) {
    compute_tile(LA0, LB0, wm, wn, lr, lg, acc);
    BAR(); SCH0();
    stage_tile(Ag, Bg, Kstr, t + 2, LA0, LB0, tid);
    VMCNT8(); BAR(); SCH0();
    compute_tile(LA1, LB1, wm, wn, lr, lg, acc);
    BAR(); SCH0();
    stage_tile(Ag, Bg, Kstr, t + 3, LA1, LB1, tid);
    VMCNT8(); BAR(); SCH0();
  }
  compute_tile(LA0, LB0, wm, wn, lr, lg, acc);   // tile T-2
  VMCNT0(); BAR(); SCH0();                       // tile T-1 landed
  compute_tile(LA1, LB1, wm, wn, lr, lg, acc);   // tile T-1

#pragma unroll
  for (int m = 0; m < 8; ++m)
#pragma unroll
    for (int n = 0; n < 4; ++n)
#pragma unroll
      for (int r = 0; r < 4; ++r) {
        const int row = m0 + wm * 128 + m * 16 + lg * 4 + r;
        const int col = n0 + wn * 64 + n * 16 + lr;
        float val = acc[m][n][r];
        if (EPI == 0) {
          const int which = col >> 10, hc = col & 1023;
          const float* bs = (which == 0) ? bias0 : (which == 1) ? bias1 : bias2;
          bf16* dst = (which == 0) ? q_out : (which == 1) ? k_out : v_out;
          val += bs[hc];
          const int b = row >> 11, s = row & 2047;
          const int h = hc >> 6, hd = hc & 63;
          dst[(((size_t)b * 16 + h) * 2048 + s) * 64 + hd] = (bf16)val;
        } else {
          val += bias0[col];
          outb[(size_t)row * Nn + col] = (bf16)(val > 0.f ? val : 0.f);
        }
      }
}

// ========== 128x128-tile 4-wave GEMM, counted-vmcnt, N=1024 shapes ==========
// Single-pass K (T = K/64). Epilogue: + bias + residual(bf16) -> fp32 y.
// Same stage/swizzle/schedule as gemm256, tile rows halved. 64KB LDS.
static __device__ __forceinline__ void stage128(const bf16* __restrict__ Ag,
    const bf16* __restrict__ Bg, int Kstr, int kt, bf16* lA, bf16* lB, int tid) {
  const char* dA = (const char*)lA + ((tid >> 6) << 10);
  const char* dB = (const char*)lB + ((tid >> 6) << 10);
#pragma unroll
  for (int s = 0; s < 4; ++s) {
    const int L = s * 4096 + tid * 16;
    const int off = L ^ (((L >> 7) & 7) << 4);
    load_lds16(Ag + (size_t)(off >> 7) * Kstr + kt * 64 + ((off & 127) >> 1),
               (void*)(dA + s * 4096));
  }
#pragma unroll
  for (int s = 0; s < 4; ++s) {
    const int L = s * 4096 + tid * 16;
    const int off = L ^ (((L >> 7) & 7) << 4);
    load_lds16(Bg + (size_t)(off >> 7) * Kstr + kt * 64 + ((off & 127) >> 1),
               (void*)(dB + s * 4096));
  }
}

static __device__ __forceinline__ void compute128(const bf16* lA, const bf16* lB,
    int wm, int wn, int lr, int lg, f32x4 (&acc)[4][4]) {
  bf16x8 bfr[4][2];
#pragma unroll
  for (int n = 0; n < 4; ++n)
#pragma unroll
    for (int kk = 0; kk < 2; ++kk)
      bfr[n][kk] = ldsfrag(lB, wn * 64 + n * 16 + lr, kk * 64 + lg * 16);
#pragma unroll
  for (int m = 0; m < 4; ++m) {
    const bf16x8 a0 = ldsfrag(lA, wm * 64 + m * 16 + lr, lg * 16);
    const bf16x8 a1 = ldsfrag(lA, wm * 64 + m * 16 + lr, 64 + lg * 16);
    __builtin_amdgcn_s_setprio(1);
#pragma unroll
    for (int n = 0; n < 4; ++n) {
      acc[m][n] = MFMA16(a0, bfr[n][0], acc[m][n]);
      acc[m][n] = MFMA16(a1, bfr[n][1], acc[m][n]);
    }
    __builtin_amdgcn_s_setprio(0);
  }
}

__global__ __launch_bounds__(256, 2) void gemm128p(
    const bf16* __restrict__ A, const bf16* __restrict__ Bt, int Kk,
    const float* __restrict__ bias, const bf16* __restrict__ resid,
    float* __restrict__ outf) {
  __shared__ __align__(16) bf16 lds[4][8192];    // A0,B0,A1,B1 (16KB each)
  const int cpx = gridDim.x >> 3;
  const int wg = (blockIdx.x & 7) * cpx + (blockIdx.x >> 3);
  const int bx = wg & 7, by = wg >> 3;           // nbx = 8 (N=1024)
  const int tid = threadIdx.x;
  const int lane = tid & 63, wave = tid >> 6;
  const int lr = lane & 15, lg = lane >> 4;
  const int wm = wave >> 1, wn = wave & 1;
  const int m0 = by * 128, n0 = bx * 128;

  const bf16* Ag = A + (size_t)m0 * Kk;
  const bf16* Bg = Bt + (size_t)n0 * Kk;
  bf16* LA0 = lds[0]; bf16* LB0 = lds[1];
  bf16* LA1 = lds[2]; bf16* LB1 = lds[3];

  f32x4 acc[4][4] = {};
  const int T = Kk >> 6;

  stage128(Ag, Bg, Kk, 0, LA0, LB0, tid);
  stage128(Ag, Bg, Kk, 1, LA1, LB1, tid);
  VMCNT8(); BAR(); SCH0();

  for (int t = 0; t + 3 < T; t += 2) {
    compute128(LA0, LB0, wm, wn, lr, lg, acc);
    BAR(); SCH0();
    stage128(Ag, Bg, Kk, t + 2, LA0, LB0, tid);
    VMCNT8(); BAR(); SCH0();
    compute128(LA1, LB1, wm, wn, lr, lg, acc);
    BAR(); SCH0();
    stage128(Ag, Bg, Kk, t + 3, LA1, LB1, tid);
    VMCNT8(); BAR(); SCH0();
  }
  compute128(LA0, LB0, wm, wn, lr, lg, acc);     // tile T-2
  VMCNT0(); BAR(); SCH0();                       // tile T-1 landed
  compute128(LA1, LB1, wm, wn, lr, lg, acc);     // tile T-1

#pragma unroll
  for (int m = 0; m < 4; ++m)
#pragma unroll
    for (int n = 0; n < 4; ++n)
#pragma unroll
      for (int r = 0; r < 4; ++r) {
        const int row = m0 + wm * 64 + m * 16 + lg * 4 + r;
        const int col = n0 + wn * 64 + n * 16 + lr;
        const float val = acc[m][n][r] + bias[col]
                        + (float)resid[(size_t)row * 1024 + col];
        outf[(size_t)row * 1024 + col] = val;
      }
}

// ------------------------- flash attention (per b,h) ------------------------
// grid: (S/128, B*H). block: 512 = 8 waves; wave w owns q-rows [128*bx+16w,+16)
// K in [bh][s][64]; V^T in [bh][64][s]. Reg-staged K/V double buffer.
// XOR-swizzled LDS (col8 ^= row&7), swapped QK^T, log2-domain softmax.
// NOTE: chunk loop MUST be unrolled by 2 (rule #20, round-3 lesson).
__global__ __launch_bounds__(512) void attn_kernel(const bf16* __restrict__ q,
                                                   const bf16* __restrict__ k,
                                                   const bf16* __restrict__ vt,
                                                   bf16* __restrict__ ctxo) {
  __shared__ __align__(16) bf16 Kl[64][64];
  __shared__ __align__(16) bf16 Vt[64][64];   // rows = hd, cols = key
  __shared__ __align__(16) bf16 Pl[8][16][64];
  const int tid = threadIdx.x;
  const int lane = tid & 63, w = tid >> 6;
  const int lr = lane & 15, lg = lane >> 4;
  const int swz = lr & 7;
  const int bh = blockIdx.y;
  const int q0 = blockIdx.x * 128;

  const bf16* qp = q + ((size_t)bh * 2048 + q0 + w * 16) * 64;
  bf16x8 qf0 = *(const bf16x8*)&qp[lr * 64 + lg * 8];
  bf16x8 qf1 = *(const bf16x8*)&qp[lr * 64 + lg * 8 + 32];
  const float qs = 0.18033688011112042f;      // (1/8)*log2(e)
#pragma unroll
  for (int j = 0; j < 8; ++j) {
    qf0[j] = (bf16)((float)qf0[j] * qs);
    qf1[j] = (bf16)((float)qf1[j] * qs);
  }
  bf16x8 ones8;
#pragma unroll
  for (int j = 0; j < 8; ++j) ones8[j] = (bf16)1.0f;

  const bf16* kbase = k + (size_t)bh * 2048 * 64;
  const bf16* vtb = vt + (size_t)bh * 64 * 2048;

  const int sr0 = tid >> 3;                       // 0..63: staging row
  const int c0 = (tid & 7) * 8;
  const int cs0 = c0 ^ ((sr0 & 7) << 3);

  f32x4 acc[4] = {};
  f32x4 accl = {};
  float mq = -1e30f;

  bf16x8 kr[2], vr[2];
  kr[0] = *(const bf16x8*)&kbase[(size_t)sr0 * 64 + c0];
  vr[0] = *(const bf16x8*)&vtb[(size_t)sr0 * 2048 + c0];

#pragma unroll 2
  for (int c = 0; c < 32; ++c) {
    const int pp = c & 1;
    *(bf16x8*)&Kl[sr0][cs0] = kr[pp];
    *(bf16x8*)&Vt[sr0][cs0] = vr[pp];
    if (c + 1 < 32) {
      const int key0n = (c + 1) * 64;
      kr[pp ^ 1] = *(const bf16x8*)&kbase[(size_t)(key0n + sr0) * 64 + c0];
      vr[pp ^ 1] = *(const bf16x8*)&vtb[(size_t)sr0 * 2048 + key0n + c0];
    }
    __syncthreads();

    f32x4 st[4];
    __builtin_amdgcn_s_setprio(1);
#pragma unroll
    for (int ks = 0; ks < 4; ++ks) {
      const bf16x8 kf0 = *(const bf16x8*)&Kl[ks * 16 + lr][(lg ^ swz) << 3];
      const bf16x8 kf1 = *(const bf16x8*)&Kl[ks * 16 + lr][((lg + 4) ^ swz) << 3];
      f32x4 sa = {};
      sa = MFMA16(kf0, qf0, sa);
      sa = MFMA16(kf1, qf1, sa);
      st[ks] = sa;
    }
    __builtin_amdgcn_s_setprio(0);

    float mx = st[0][0];
#pragma unroll
    for (int ks = 0; ks < 4; ++ks)
#pragma unroll
      for (int r = 0; r < 4; ++r) mx = fmaxf(mx, st[ks][r]);
    mx = fmaxf(mx, __shfl_xor(mx, 16));
    mx = fmaxf(mx, __shfl_xor(mx, 32));
    if (!__all(mx - mq <= 8.0f)) {                 // defer-max (T13)
      const float resc = exp2f(mq - mx);
      mq = mx;
      float rq[4];
#pragma unroll
      for (int r = 0; r < 4; ++r) rq[r] = __shfl(resc, lg * 4 + r);
#pragma unroll
      for (int r = 0; r < 4; ++r) {
        accl[r] *= rq[r];
#pragma unroll
        for (int jn = 0; jn < 4; ++jn) acc[jn][r] *= rq[r];
      }
    }
#pragma unroll
    for (int ks = 0; ks < 4; ++ks) {
      bf16x4 pk;
#pragma unroll
      for (int r = 0; r < 4; ++r) pk[r] = (bf16)exp2f(st[ks][r] - mq);
      const int col = (((ks * 2 + (lg >> 1)) ^ swz) << 3) + ((lg & 1) << 2);
      *(bf16x4*)&Pl[w][lr][col] = pk;
    }

    const bf16x8 pf0 = *(const bf16x8*)&Pl[w][lr][(lg ^ swz) << 3];
    const bf16x8 pf1 = *(const bf16x8*)&Pl[w][lr][((lg + 4) ^ swz) << 3];
    __builtin_amdgcn_s_setprio(1);
#pragma unroll
    for (int jn = 0; jn < 4; ++jn) {
      const bf16x8 vf0 = *(const bf16x8*)&Vt[jn * 16 + lr][(lg ^ swz) << 3];
      const bf16x8 vf1 = *(const bf16x8*)&Vt[jn * 16 + lr][((lg + 4) ^ swz) << 3];
      acc[jn] = MFMA16(pf0, vf0, acc[jn]);
      acc[jn] = MFMA16(pf1, vf1, acc[jn]);
    }
    accl = MFMA16(pf0, ones8, accl);
    accl = MFMA16(pf1, ones8, accl);
    __builtin_amdgcn_s_setprio(0);
    __syncthreads();
  }

  const int bb = bh >> 4, hh = bh & 15;
#pragma unroll
  for (int r = 0; r < 4; ++r) {
    const float inv = 1.f / accl[r];
    const size_t rowg = (size_t)bb * 2048 + q0 + w * 16 + lg * 4 + r;
#pragma unroll
    for (int jn = 0; jn < 4; ++jn)
      ctxo[rowg * 1024 + hh * 64 + jn * 16 + lr] = (bf16)(acc[jn][r] * inv);
  }
}

// ------------------------------ LayerNorm (fp32 y) --------------------------
__global__ __launch_bounds__(256) void ln_kernel(const float* __restrict__ y,
                                                 const float* __restrict__ g,
                                                 const float* __restrict__ be,
                                                 bf16* __restrict__ xo) {
  const int row = blockIdx.x, tid = threadIdx.x;
  const float4 v = ((const float4*)(y + (size_t)row * 1024))[tid];
  float s = v.x + v.y + v.z + v.w;
  float s2 = v.x * v.x + v.y * v.y + v.z * v.z + v.w * v.w;
#pragma unroll
  for (int o = 32; o > 0; o >>= 1) { s += __shfl_down(s, o); s2 += __shfl_down(s2, o); }
  __shared__ float red[8];
  if ((tid & 63) == 0) { red[tid >> 6] = s; red[4 + (tid >> 6)] = s2; }
  __syncthreads();
  s = red[0] + red[1] + red[2] + red[3];
  s2 = red[4] + red[5] + red[6] + red[7];
  const float mean = s * (1.f / 1024.f);
  const float var = s2 * (1.f / 1024.f) - mean * mean;
  const float rstd = rsqrtf(var + 1e-5f);
  const float4 gv = ((const float4*)g)[tid];
  const float4 bv = ((const float4*)be)[tid];
  bf16x4 o4;
  o4[0] = (bf16)((v.x - mean) * rstd * gv.x + bv.x);
  o4[1] = (bf16)((v.y - mean) * rstd * gv.y + bv.y);
  o4[2] = (bf16)((v.z - mean) * rstd * gv.z + bv.z);
  o4[3] = (bf16)((v.w - mean) * rstd * gv.w + bv.w);
  *(bf16x4*)&xo[(size_t)row * 1024 + tid * 4] = o4;
}

// ------------------------------ bf16 -> fp32 --------------------------------
__global__ __launch_bounds__(256) void to_f32_kernel(const bf16* __restrict__ x,
                                                     float* __restrict__ o) {
  const size_t i = ((size_t)blockIdx.x * 256 + threadIdx.x) * 4;
  const bf16x4 v = *(const bf16x4*)&x[i];
  float4 f;
  f.x = (float)v[0]; f.y = (float)v[1]; f.z = (float)v[2]; f.w = (float)v[3];
  *(float4*)&o[i] = f;
}

// ----------------------------------------------------------------------------
extern "C" void kernel_launch(void* const* d_in, const int* in_sizes, int n_in,
                              void* d_out, int out_size, void* d_ws, size_t ws_size,
                              hipStream_t stream) {
  const int* tokens = (const int*)d_in[0];
  const float* emb = (const float*)d_in[2];
  const float* Wq = (const float*)d_in[3];
  const float* bq = (const float*)d_in[4];
  const float* Wk = (const float*)d_in[5];
  const float* bk = (const float*)d_in[6];
  const float* Wv = (const float*)d_in[7];
  const float* bv = (const float*)d_in[8];
  const float* Wo = (const float*)d_in[9];
  const float* bo = (const float*)d_in[10];
  const float* W1 = (const float*)d_in[11];
  const float* b1 = (const float*)d_in[12];
  const float* W2 = (const float*)d_in[13];
  const float* b2 = (const float*)d_in[14];
  const float* g1 = (const float*)d_in[15];
  const float* be1 = (const float*)d_in[16];
  const float* g2 = (const float*)d_in[17];
  const float* be2 = (const float*)d_in[18];

  char* p = (char*)d_ws;
  auto carve = [&](size_t bytes) { char* r = p; p += (bytes + 255) & ~(size_t)255; return r; };
  bf16* wt_qkv = (bf16*)carve((size_t)3072 * 1024 * 2);
  bf16* wt_o   = (bf16*)carve((size_t)1024 * 1024 * 2);
  bf16* wt_1   = (bf16*)carve((size_t)4096 * 1024 * 2);
  bf16* wt_2   = (bf16*)carve((size_t)1024 * 4096 * 2);
  bf16* xb     = (bf16*)carve((size_t)4096 * 1024 * 2);
  bf16* qb     = (bf16*)carve((size_t)4096 * 1024 * 2);
  bf16* kb     = (bf16*)carve((size_t)4096 * 1024 * 2);
  bf16* vb     = (bf16*)carve((size_t)4096 * 1024 * 2);
  bf16* vtb    = (bf16*)carve((size_t)4096 * 1024 * 2);
  bf16* ctxb   = (bf16*)carve((size_t)4096 * 1024 * 2);
  float* yb    = (float*)carve((size_t)4096 * 1024 * 4);
  bf16* hb     = (bf16*)carve((size_t)4096 * 4096 * 2);

  embed_kernel<<<4096, 256, 0, stream>>>(tokens, emb, xb);

  for (int l = 0; l < 6; ++l) {
    TArgs ta;
    ta.j[0] = { Wq + (size_t)l * 1024 * 1024, wt_qkv,                  1024, 1024, 0 };
    ta.j[1] = { Wk + (size_t)l * 1024 * 1024, wt_qkv + 1024 * 1024,    1024, 1024, 1024 };
    ta.j[2] = { Wv + (size_t)l * 1024 * 1024, wt_qkv + 2 * 1024 * 1024,1024, 1024, 2048 };
    ta.j[3] = { Wo + (size_t)l * 1024 * 1024, wt_o,                    1024, 1024, 3072 };
    ta.j[4] = { W1 + (size_t)l * 1024 * 4096, wt_1,                    1024, 4096, 4096 };
    ta.j[5] = { W2 + (size_t)l * 4096 * 1024, wt_2,                    4096, 1024, 8192 };
    wtrans_kernel<<<12288, 256, 0, stream>>>(ta);

    // QKV: 256^2 tile, grid 16x12 = 192
    gemm256<0><<<192, 512, 0, stream>>>(xb, wt_qkv, 1024, 1024, 3072, 12,
        bq + (size_t)l * 1024, bk + (size_t)l * 1024, bv + (size_t)l * 1024,
        nullptr, qb, kb, vb);

    vtrans_kernel<<<dim3(32, 32), 256, 0, stream>>>(vb, vtb);

    attn_kernel<<<dim3(16, 32), 512, 0, stream>>>(qb, kb, vtb, ctxb);

    // O-proj: 128^2 pipeline, single-pass K=1024, grid 256
    gemm128p<<<256, 256, 0, stream>>>(ctxb, wt_o, 1024,
        bo + (size_t)l * 1024, xb, yb);
    ln_kernel<<<4096, 256, 0, stream>>>(yb, g1 + (size_t)l * 1024,
        be1 + (size_t)l * 1024, xb);

    // FFN1: 256^2 tile, grid 16x16 = 256
    gemm256<2><<<256, 512, 0, stream>>>(xb, wt_1, 1024, 1024, 4096, 16,
        b1 + (size_t)l * 4096, nullptr, nullptr, hb,
        nullptr, nullptr, nullptr);

    // FFN2: 128^2 pipeline, single-pass K=4096, grid 256
    gemm128p<<<256, 256, 0, stream>>>(hb, wt_2, 4096,
        b2 + (size_t)l * 1024, xb, yb);
    ln_kernel<<<4096, 256, 0, stream>>>(yb, g2 + (size_t)l * 1024,
        be2 + (size_t)l * 1024, xb);
  }

  to_f32_kernel<<<4096, 256, 0, stream>>>(xb, (float*)d_out);
}

// Round 11
// 1413.230 us; speedup vs baseline: 1.0932x; 1.0109x over previous
//
#include <hip/hip_runtime.h>
#include <hip/hip_bf16.h>
#include <cstdint>
#include <cstddef>

// ---------------------------------------------------------------------------
// Transformer encoder, 6 layers: B=2,S=2048,D=1024,H=16,HD=64,F=4096.
// QKV+FFN1: 256^2-tile 8-wave GEMM, counted-vmcnt double buffer (T2+T3+T4+T5).
// FFN2: gemm256 split-K=4 -> fp32 partials + fused LN. O-proj: 128^2 pipeline.
// Flash attention: 8-wave blocks (Q=128), XCD-swizzled grid, swapped QK^T,
// T2 swizzle, reg-staged K/V double buffer. fp32 LN.
// ---------------------------------------------------------------------------

typedef __bf16 bf16;
typedef __bf16 bf16x2 __attribute__((ext_vector_type(2)));
typedef __bf16 bf16x4 __attribute__((ext_vector_type(4)));
typedef __bf16 bf16x8 __attribute__((ext_vector_type(8)));
typedef float  f32x4  __attribute__((ext_vector_type(4)));

#define MFMA16(a, b, c) __builtin_amdgcn_mfma_f32_16x16x32_bf16((a), (b), (c), 0, 0, 0)

static __device__ __forceinline__ void load_lds16(const void* g, void* l) {
  __builtin_amdgcn_global_load_lds((const __attribute__((address_space(1))) void*)g,
                                   (__attribute__((address_space(3))) void*)l, 16, 0, 0);
}

#define BAR()   __builtin_amdgcn_s_barrier()
#define SCH0()  __builtin_amdgcn_sched_barrier(0)
#define VMCNT8() asm volatile("s_waitcnt vmcnt(8)" ::: "memory")
#define VMCNT0() asm volatile("s_waitcnt vmcnt(0)" ::: "memory")

// ---------------- embedding + positional encoding -> bf16 x ----------------
__global__ __launch_bounds__(256) void embed_kernel(const int* __restrict__ tok,
                                                    const float* __restrict__ emb,
                                                    bf16* __restrict__ xo) {
  const int row = blockIdx.x;          // b*2048 + s
  const int s = row & 2047;
  const int t = tok[row];
  const int d0 = threadIdx.x * 4;
  const float4 e = *(const float4*)&emb[(size_t)t * 1024 + d0];
  const float* ef = (const float*)&e;
  bf16x4 o4;
#pragma unroll
  for (int j = 0; j < 4; ++j) {
    const int d = d0 + j;
    const float div = __expf(-(float)(d & ~1) * 0.00899447301950864f); // ln(1e4)/1024
    const float arg = (float)s * div;
    const float pe = (d & 1) ? cosf(arg) : sinf(arg);
    o4[j] = (bf16)(ef[j] + pe);
  }
  *(bf16x4*)&xo[(size_t)row * 1024 + d0] = o4;
}

// ------------- weight transpose: fp32 [K][N] -> bf16 [N][K], batched --------
struct TJob { const float* src; bf16* dst; int K; int N; int t0; };
struct TArgs { TJob j[6]; };

__global__ __launch_bounds__(256) void wtrans_kernel(TArgs a) {
  __shared__ float t[32][33];
  const int blk = blockIdx.x;
  const float* src = a.j[0].src; bf16* dst = a.j[0].dst;
  int K = a.j[0].K, N = a.j[0].N, t0 = a.j[0].t0;
#pragma unroll
  for (int q = 1; q < 6; ++q)
    if (blk >= a.j[q].t0) { src = a.j[q].src; dst = a.j[q].dst; K = a.j[q].K; N = a.j[q].N; t0 = a.j[q].t0; }
  const int tj = blk - t0;
  const int tilesK = K >> 5;
  const int tk = (tj % tilesK) << 5;
  const int tn = (tj / tilesK) << 5;
  const int lx = threadIdx.x & 31, ly = threadIdx.x >> 5;
#pragma unroll
  for (int i = 0; i < 4; ++i)
    t[ly + 8 * i][lx] = src[(size_t)(tk + ly + 8 * i) * N + tn + lx];
  __syncthreads();
#pragma unroll
  for (int i = 0; i < 4; ++i)
    dst[(size_t)(tn + ly + 8 * i) * K + tk + lx] = (bf16)t[lx][ly + 8 * i];
}

// -------- V transpose per layer: [bh][s][64] bf16 -> [bh][64][s] bf16 -------
__global__ __launch_bounds__(256) void vtrans_kernel(const bf16* __restrict__ v,
                                                     bf16* __restrict__ vt) {
  __shared__ bf16 t[64][72];
  const int bh = blockIdx.y;
  const int s0 = blockIdx.x * 64;
  const int tid = threadIdx.x;
#pragma unroll
  for (int it = 0; it < 2; ++it) {
    const int idx = tid + it * 256;
    const int sr = idx >> 3, h8 = (idx & 7) * 8;
    *(bf16x8*)&t[sr][h8] = *(const bf16x8*)&v[((size_t)bh * 2048 + s0 + sr) * 64 + h8];
  }
  __syncthreads();
#pragma unroll
  for (int it = 0; it < 2; ++it) {
    const int idx = tid + it * 256;
    const int hd = idx >> 3, s8 = (idx & 7) * 8;
    bf16x8 o;
#pragma unroll
    for (int j = 0; j < 8; ++j) o[j] = t[s8 + j][hd];
    *(bf16x8*)&vt[((size_t)bh * 64 + hd) * 2048 + s0 + s8] = o;
  }
}

// ======================= shared GEMM building blocks ========================
static __device__ __forceinline__ bf16x8 ldsfrag(const bf16* base, int row, int colb) {
  int off = row * 128 + colb;
  off ^= ((off >> 7) & 7) << 4;
  return *(const bf16x8*)((const char*)base + off);
}

// ================= 256x256-tile 8-wave GEMM, counted-vmcnt =================
static __device__ __forceinline__ void stage_tile(const bf16* __restrict__ Ag,
    const bf16* __restrict__ Bg, int Kstr, int kt, bf16* lA, bf16* lB, int tid) {
  const char* wbaseA = (const char*)lA + ((tid >> 6) << 10);
  const char* wbaseB = (const char*)lB + ((tid >> 6) << 10);
#pragma unroll
  for (int s = 0; s < 4; ++s) {
    const int L = s * 8192 + tid * 16;
    const int off = L ^ (((L >> 7) & 7) << 4);
    load_lds16(Ag + (size_t)(off >> 7) * Kstr + kt * 64 + ((off & 127) >> 1),
               (void*)(wbaseA + s * 8192));
  }
#pragma unroll
  for (int s = 0; s < 4; ++s) {
    const int L = s * 8192 + tid * 16;
    const int off = L ^ (((L >> 7) & 7) << 4);
    load_lds16(Bg + (size_t)(off >> 7) * Kstr + kt * 64 + ((off & 127) >> 1),
               (void*)(wbaseB + s * 8192));
  }
}

static __device__ __forceinline__ void compute_tile(const bf16* lA, const bf16* lB,
    int wm, int wn, int lr, int lg, f32x4 (&acc)[8][4]) {
  bf16x8 bfr[4][2];
#pragma unroll
  for (int n = 0; n < 4; ++n)
#pragma unroll
    for (int kk = 0; kk < 2; ++kk)
      bfr[n][kk] = ldsfrag(lB, wn * 64 + n * 16 + lr, kk * 64 + lg * 16);
#pragma unroll
  for (int m = 0; m < 8; ++m) {
    const bf16x8 a0 = ldsfrag(lA, wm * 128 + m * 16 + lr, lg * 16);
    const bf16x8 a1 = ldsfrag(lA, wm * 128 + m * 16 + lr, 64 + lg * 16);
    __builtin_amdgcn_s_setprio(1);
#pragma unroll
    for (int n = 0; n < 4; ++n) {
      acc[m][n] = MFMA16(a0, bfr[n][0], acc[m][n]);
      acc[m][n] = MFMA16(a1, bfr[n][1], acc[m][n]);
    }
    __builtin_amdgcn_s_setprio(0);
  }
}

template <int EPI>   // 0: qkv scatter, 1: fp32 partial (split-K), 2: bias+relu
__global__ __launch_bounds__(512, 2) void gemm256(
    const bf16* __restrict__ A, const bf16* __restrict__ Bt,
    int Kstr, int Kloop, int Nn, int nbx,
    const float* __restrict__ bias0, const float* __restrict__ bias1,
    const float* __restrict__ bias2, bf16* __restrict__ outb,
    float* __restrict__ pout,
    bf16* __restrict__ q_out, bf16* __restrict__ k_out, bf16* __restrict__ v_out) {
  __shared__ __align__(16) bf16 lds[4][16384];   // A0,B0,A1,B1 (32KB each)
  const int bz = blockIdx.y;
  const bf16* Abase = A + (size_t)bz * Kloop;
  const bf16* Bbase = Bt + (size_t)bz * Kloop;
  const int cpx = gridDim.x >> 3;
  const int wg = (blockIdx.x & 7) * cpx + (blockIdx.x >> 3);
  const int bx = wg % nbx, by = wg / nbx;
  const int tid = threadIdx.x;
  const int lane = tid & 63, wave = tid >> 6;
  const int lr = lane & 15, lg = lane >> 4;
  const int wm = wave >> 2, wn = wave & 3;
  const int m0 = by * 256, n0 = bx * 256;

  const bf16* Ag = Abase + (size_t)m0 * Kstr;
  const bf16* Bg = Bbase + (size_t)n0 * Kstr;
  bf16* LA0 = lds[0]; bf16* LB0 = lds[1];
  bf16* LA1 = lds[2]; bf16* LB1 = lds[3];

  f32x4 acc[8][4] = {};
  const int T = Kloop >> 6;

  stage_tile(Ag, Bg, Kstr, 0, LA0, LB0, tid);
  stage_tile(Ag, Bg, Kstr, 1, LA1, LB1, tid);
  VMCNT8(); BAR(); SCH0();

  for (int t = 0; t + 3 < T; t += 2) {
    compute_tile(LA0, LB0, wm, wn, lr, lg, acc);
    BAR(); SCH0();
    stage_tile(Ag, Bg, Kstr, t + 2, LA0, LB0, tid);
    VMCNT8(); BAR(); SCH0();
    compute_tile(LA1, LB1, wm, wn, lr, lg, acc);
    BAR(); SCH0();
    stage_tile(Ag, Bg, Kstr, t + 3, LA1, LB1, tid);
    VMCNT8(); BAR(); SCH0();
  }
  compute_tile(LA0, LB0, wm, wn, lr, lg, acc);   // tile T-2
  VMCNT0(); BAR(); SCH0();                       // tile T-1 landed
  compute_tile(LA1, LB1, wm, wn, lr, lg, acc);   // tile T-1

#pragma unroll
  for (int m = 0; m < 8; ++m)
#pragma unroll
    for (int n = 0; n < 4; ++n)
#pragma unroll
      for (int r = 0; r < 4; ++r) {
        const int row = m0 + wm * 128 + m * 16 + lg * 4 + r;
        const int col = n0 + wn * 64 + n * 16 + lr;
        float val = acc[m][n][r];
        if (EPI == 0) {
          const int which = col >> 10, hc = col & 1023;
          const float* bs = (which == 0) ? bias0 : (which == 1) ? bias1 : bias2;
          bf16* dst = (which == 0) ? q_out : (which == 1) ? k_out : v_out;
          val += bs[hc];
          const int b = row >> 11, s = row & 2047;
          const int h = hc >> 6, hd = hc & 63;
          dst[(((size_t)b * 16 + h) * 2048 + s) * 64 + hd] = (bf16)val;
        } else if (EPI == 1) {
          pout[(size_t)bz * 4096 * 1024 + (size_t)row * 1024 + col] = val;
        } else {
          val += bias0[col];
          outb[(size_t)row * Nn + col] = (bf16)(val > 0.f ? val : 0.f);
        }
      }
}

// ========== 128x128-tile 4-wave GEMM, counted-vmcnt (O-proj K=1024) =========
static __device__ __forceinline__ void stage128(const bf16* __restrict__ Ag,
    const bf16* __restrict__ Bg, int Kstr, int kt, bf16* lA, bf16* lB, int tid) {
  const char* dA = (const char*)lA + ((tid >> 6) << 10);
  const char* dB = (const char*)lB + ((tid >> 6) << 10);
#pragma unroll
  for (int s = 0; s < 4; ++s) {
    const int L = s * 4096 + tid * 16;
    const int off = L ^ (((L >> 7) & 7) << 4);
    load_lds16(Ag + (size_t)(off >> 7) * Kstr + kt * 64 + ((off & 127) >> 1),
               (void*)(dA + s * 4096));
  }
#pragma unroll
  for (int s = 0; s < 4; ++s) {
    const int L = s * 4096 + tid * 16;
    const int off = L ^ (((L >> 7) & 7) << 4);
    load_lds16(Bg + (size_t)(off >> 7) * Kstr + kt * 64 + ((off & 127) >> 1),
               (void*)(dB + s * 4096));
  }
}

static __device__ __forceinline__ void compute128(const bf16* lA, const bf16* lB,
    int wm, int wn, int lr, int lg, f32x4 (&acc)[4][4]) {
  bf16x8 bfr[4][2];
#pragma unroll
  for (int n = 0; n < 4; ++n)
#pragma unroll
    for (int kk = 0; kk < 2; ++kk)
      bfr[n][kk] = ldsfrag(lB, wn * 64 + n * 16 + lr, kk * 64 + lg * 16);
#pragma unroll
  for (int m = 0; m < 4; ++m) {
    const bf16x8 a0 = ldsfrag(lA, wm * 64 + m * 16 + lr, lg * 16);
    const bf16x8 a1 = ldsfrag(lA, wm * 64 + m * 16 + lr, 64 + lg * 16);
    __builtin_amdgcn_s_setprio(1);
#pragma unroll
    for (int n = 0; n < 4; ++n) {
      acc[m][n] = MFMA16(a0, bfr[n][0], acc[m][n]);
      acc[m][n] = MFMA16(a1, bfr[n][1], acc[m][n]);
    }
    __builtin_amdgcn_s_setprio(0);
  }
}

__global__ __launch_bounds__(256, 2) void gemm128p(
    const bf16* __restrict__ A, const bf16* __restrict__ Bt, int Kk,
    const float* __restrict__ bias, const bf16* __restrict__ resid,
    float* __restrict__ outf) {
  __shared__ __align__(16) bf16 lds[4][8192];    // A0,B0,A1,B1 (16KB each)
  const int cpx = gridDim.x >> 3;
  const int wg = (blockIdx.x & 7) * cpx + (blockIdx.x >> 3);
  const int bx = wg & 7, by = wg >> 3;           // nbx = 8 (N=1024)
  const int tid = threadIdx.x;
  const int lane = tid & 63, wave = tid >> 6;
  const int lr = lane & 15, lg = lane >> 4;
  const int wm = wave >> 1, wn = wave & 1;
  const int m0 = by * 128, n0 = bx * 128;

  const bf16* Ag = A + (size_t)m0 * Kk;
  const bf16* Bg = Bt + (size_t)n0 * Kk;
  bf16* LA0 = lds[0]; bf16* LB0 = lds[1];
  bf16* LA1 = lds[2]; bf16* LB1 = lds[3];

  f32x4 acc[4][4] = {};
  const int T = Kk >> 6;

  stage128(Ag, Bg, Kk, 0, LA0, LB0, tid);
  stage128(Ag, Bg, Kk, 1, LA1, LB1, tid);
  VMCNT8(); BAR(); SCH0();

  for (int t = 0; t + 3 < T; t += 2) {
    compute128(LA0, LB0, wm, wn, lr, lg, acc);
    BAR(); SCH0();
    stage128(Ag, Bg, Kk, t + 2, LA0, LB0, tid);
    VMCNT8(); BAR(); SCH0();
    compute128(LA1, LB1, wm, wn, lr, lg, acc);
    BAR(); SCH0();
    stage128(Ag, Bg, Kk, t + 3, LA1, LB1, tid);
    VMCNT8(); BAR(); SCH0();
  }
  compute128(LA0, LB0, wm, wn, lr, lg, acc);     // tile T-2
  VMCNT0(); BAR(); SCH0();                       // tile T-1 landed
  compute128(LA1, LB1, wm, wn, lr, lg, acc);     // tile T-1

#pragma unroll
  for (int m = 0; m < 4; ++m)
#pragma unroll
    for (int n = 0; n < 4; ++n)
#pragma unroll
      for (int r = 0; r < 4; ++r) {
        const int row = m0 + wm * 64 + m * 16 + lg * 4 + r;
        const int col = n0 + wn * 64 + n * 16 + lr;
        const float val = acc[m][n][r] + bias[col]
                        + (float)resid[(size_t)row * 1024 + col];
        outf[(size_t)row * 1024 + col] = val;
      }
}

// ------------------------- flash attention (per b,h) ------------------------
// 1D grid 512, XCD-swizzled: wid = (bid&7)*64 + (bid>>3) -> each XCD owns 4
// consecutive bh (KV L2-resident). block: 512 = 8 waves; wave w owns q-rows
// [128*(wid&15) + 16w, +16). Reg-staged K/V double buffer, T2 swizzle,
// swapped QK^T, log2-domain softmax. Chunk loop MUST be unrolled by 2
// (rule #20, round-3 lesson).
__global__ __launch_bounds__(512) void attn_kernel(const bf16* __restrict__ q,
                                                   const bf16* __restrict__ k,
                                                   const bf16* __restrict__ vt,
                                                   bf16* __restrict__ ctxo) {
  __shared__ __align__(16) bf16 Kl[64][64];
  __shared__ __align__(16) bf16 Vt[64][64];   // rows = hd, cols = key
  __shared__ __align__(16) bf16 Pl[8][16][64];
  const int wid = ((blockIdx.x & 7) << 6) + (blockIdx.x >> 3);
  const int bh = wid >> 4;
  const int q0 = (wid & 15) * 128;
  const int tid = threadIdx.x;
  const int lane = tid & 63, w = tid >> 6;
  const int lr = lane & 15, lg = lane >> 4;
  const int swz = lr & 7;

  const bf16* qp = q + ((size_t)bh * 2048 + q0 + w * 16) * 64;
  bf16x8 qf0 = *(const bf16x8*)&qp[lr * 64 + lg * 8];
  bf16x8 qf1 = *(const bf16x8*)&qp[lr * 64 + lg * 8 + 32];
  const float qs = 0.18033688011112042f;      // (1/8)*log2(e)
#pragma unroll
  for (int j = 0; j < 8; ++j) {
    qf0[j] = (bf16)((float)qf0[j] * qs);
    qf1[j] = (bf16)((float)qf1[j] * qs);
  }
  bf16x8 ones8;
#pragma unroll
  for (int j = 0; j < 8; ++j) ones8[j] = (bf16)1.0f;

  const bf16* kbase = k + (size_t)bh * 2048 * 64;
  const bf16* vtb = vt + (size_t)bh * 64 * 2048;

  const int sr0 = tid >> 3;                       // 0..63: staging row
  const int c0 = (tid & 7) * 8;
  const int cs0 = c0 ^ ((sr0 & 7) << 3);

  f32x4 acc[4] = {};
  f32x4 accl = {};
  float mq = -1e30f;

  bf16x8 kr[2], vr[2];
  kr[0] = *(const bf16x8*)&kbase[(size_t)sr0 * 64 + c0];
  vr[0] = *(const bf16x8*)&vtb[(size_t)sr0 * 2048 + c0];

#pragma unroll 2
  for (int c = 0; c < 32; ++c) {
    const int pp = c & 1;
    *(bf16x8*)&Kl[sr0][cs0] = kr[pp];
    *(bf16x8*)&Vt[sr0][cs0] = vr[pp];
    if (c + 1 < 32) {
      const int key0n = (c + 1) * 64;
      kr[pp ^ 1] = *(const bf16x8*)&kbase[(size_t)(key0n + sr0) * 64 + c0];
      vr[pp ^ 1] = *(const bf16x8*)&vtb[(size_t)sr0 * 2048 + key0n + c0];
    }
    __syncthreads();

    f32x4 st[4];
    __builtin_amdgcn_s_setprio(1);
#pragma unroll
    for (int ks = 0; ks < 4; ++ks) {
      const bf16x8 kf0 = *(const bf16x8*)&Kl[ks * 16 + lr][(lg ^ swz) << 3];
      const bf16x8 kf1 = *(const bf16x8*)&Kl[ks * 16 + lr][((lg + 4) ^ swz) << 3];
      f32x4 sa = {};
      sa = MFMA16(kf0, qf0, sa);
      sa = MFMA16(kf1, qf1, sa);
      st[ks] = sa;
    }
    __builtin_amdgcn_s_setprio(0);

    float mx = st[0][0];
#pragma unroll
    for (int ks = 0; ks < 4; ++ks)
#pragma unroll
      for (int r = 0; r < 4; ++r) mx = fmaxf(mx, st[ks][r]);
    mx = fmaxf(mx, __shfl_xor(mx, 16));
    mx = fmaxf(mx, __shfl_xor(mx, 32));
    if (!__all(mx - mq <= 8.0f)) {                 // defer-max (T13)
      const float resc = exp2f(mq - mx);
      mq = mx;
      float rq[4];
#pragma unroll
      for (int r = 0; r < 4; ++r) rq[r] = __shfl(resc, lg * 4 + r);
#pragma unroll
      for (int r = 0; r < 4; ++r) {
        accl[r] *= rq[r];
#pragma unroll
        for (int jn = 0; jn < 4; ++jn) acc[jn][r] *= rq[r];
      }
    }
#pragma unroll
    for (int ks = 0; ks < 4; ++ks) {
      bf16x4 pk;
#pragma unroll
      for (int r = 0; r < 4; ++r) pk[r] = (bf16)exp2f(st[ks][r] - mq);
      const int col = (((ks * 2 + (lg >> 1)) ^ swz) << 3) + ((lg & 1) << 2);
      *(bf16x4*)&Pl[w][lr][col] = pk;
    }

    const bf16x8 pf0 = *(const bf16x8*)&Pl[w][lr][(lg ^ swz) << 3];
    const bf16x8 pf1 = *(const bf16x8*)&Pl[w][lr][((lg + 4) ^ swz) << 3];
    __builtin_amdgcn_s_setprio(1);
#pragma unroll
    for (int jn = 0; jn < 4; ++jn) {
      const bf16x8 vf0 = *(const bf16x8*)&Vt[jn * 16 + lr][(lg ^ swz) << 3];
      const bf16x8 vf1 = *(const bf16x8*)&Vt[jn * 16 + lr][((lg + 4) ^ swz) << 3];
      acc[jn] = MFMA16(pf0, vf0, acc[jn]);
      acc[jn] = MFMA16(pf1, vf1, acc[jn]);
    }
    accl = MFMA16(pf0, ones8, accl);
    accl = MFMA16(pf1, ones8, accl);
    __builtin_amdgcn_s_setprio(0);
    __syncthreads();
  }

  const int bb = bh >> 4, hh = bh & 15;
#pragma unroll
  for (int r = 0; r < 4; ++r) {
    const float inv = 1.f / accl[r];
    const size_t rowg = (size_t)bb * 2048 + q0 + w * 16 + lg * 4 + r;
#pragma unroll
    for (int jn = 0; jn < 4; ++jn)
      ctxo[rowg * 1024 + hh * 64 + jn * 16 + lr] = (bf16)(acc[jn][r] * inv);
  }
}

// ---------- fused split-K reduce + bias + residual + LayerNorm --------------
// fout != nullptr: write fp32 result directly (final layer -> d_out).
template <int NP>
__global__ __launch_bounds__(256) void ln2_kernel(const float* __restrict__ p,
                                                  const bf16* __restrict__ resid,
                                                  const float* __restrict__ bias,
                                                  const float* __restrict__ g,
                                                  const float* __restrict__ be,
                                                  bf16* __restrict__ xo,
                                                  float* __restrict__ fout) {
  const int row = blockIdx.x, tid = threadIdx.x;
  const bf16x4 rv = *(const bf16x4*)&resid[(size_t)row * 1024 + tid * 4];
  const float4 bb = ((const float4*)bias)[tid];
  float4 v;
  v.x = bb.x + (float)rv[0];
  v.y = bb.y + (float)rv[1];
  v.z = bb.z + (float)rv[2];
  v.w = bb.w + (float)rv[3];
#pragma unroll
  for (int pl = 0; pl < NP; ++pl) {
    const float4 a = ((const float4*)(p + (size_t)pl * 4096 * 1024 + (size_t)row * 1024))[tid];
    v.x += a.x; v.y += a.y; v.z += a.z; v.w += a.w;
  }
  float s = v.x + v.y + v.z + v.w;
  float s2 = v.x * v.x + v.y * v.y + v.z * v.z + v.w * v.w;
#pragma unroll
  for (int o = 32; o > 0; o >>= 1) { s += __shfl_down(s, o); s2 += __shfl_down(s2, o); }
  __shared__ float red[8];
  if ((tid & 63) == 0) { red[tid >> 6] = s; red[4 + (tid >> 6)] = s2; }
  __syncthreads();
  s = red[0] + red[1] + red[2] + red[3];
  s2 = red[4] + red[5] + red[6] + red[7];
  const float mean = s * (1.f / 1024.f);
  const float var = s2 * (1.f / 1024.f) - mean * mean;
  const float rstd = rsqrtf(var + 1e-5f);
  const float4 gv = ((const float4*)g)[tid];
  const float4 bv = ((const float4*)be)[tid];
  float4 of;
  of.x = (v.x - mean) * rstd * gv.x + bv.x;
  of.y = (v.y - mean) * rstd * gv.y + bv.y;
  of.z = (v.z - mean) * rstd * gv.z + bv.z;
  of.w = (v.w - mean) * rstd * gv.w + bv.w;
  if (fout) {
    ((float4*)(fout + (size_t)row * 1024))[tid] = of;
  } else {
    bf16x4 o4;
    o4[0] = (bf16)of.x; o4[1] = (bf16)of.y; o4[2] = (bf16)of.z; o4[3] = (bf16)of.w;
    *(bf16x4*)&xo[(size_t)row * 1024 + tid * 4] = o4;
  }
}

// ------------------------------ LayerNorm (fp32 y) --------------------------
__global__ __launch_bounds__(256) void ln_kernel(const float* __restrict__ y,
                                                 const float* __restrict__ g,
                                                 const float* __restrict__ be,
                                                 bf16* __restrict__ xo) {
  const int row = blockIdx.x, tid = threadIdx.x;
  const float4 v = ((const float4*)(y + (size_t)row * 1024))[tid];
  float s = v.x + v.y + v.z + v.w;
  float s2 = v.x * v.x + v.y * v.y + v.z * v.z + v.w * v.w;
#pragma unroll
  for (int o = 32; o > 0; o >>= 1) { s += __shfl_down(s, o); s2 += __shfl_down(s2, o); }
  __shared__ float red[8];
  if ((tid & 63) == 0) { red[tid >> 6] = s; red[4 + (tid >> 6)] = s2; }
  __syncthreads();
  s = red[0] + red[1] + red[2] + red[3];
  s2 = red[4] + red[5] + red[6] + red[7];
  const float mean = s * (1.f / 1024.f);
  const float var = s2 * (1.f / 1024.f) - mean * mean;
  const float rstd = rsqrtf(var + 1e-5f);
  const float4 gv = ((const float4*)g)[tid];
  const float4 bv = ((const float4*)be)[tid];
  bf16x4 o4;
  o4[0] = (bf16)((v.x - mean) * rstd * gv.x + bv.x);
  o4[1] = (bf16)((v.y - mean) * rstd * gv.y + bv.y);
  o4[2] = (bf16)((v.z - mean) * rstd * gv.z + bv.z);
  o4[3] = (bf16)((v.w - mean) * rstd * gv.w + bv.w);
  *(bf16x4*)&xo[(size_t)row * 1024 + tid * 4] = o4;
}

// ----------------------------------------------------------------------------
extern "C" void kernel_launch(void* const* d_in, const int* in_sizes, int n_in,
                              void* d_out, int out_size, void* d_ws, size_t ws_size,
                              hipStream_t stream) {
  const int* tokens = (const int*)d_in[0];
  const float* emb = (const float*)d_in[2];
  const float* Wq = (const float*)d_in[3];
  const float* bq = (const float*)d_in[4];
  const float* Wk = (const float*)d_in[5];
  const float* bk = (const float*)d_in[6];
  const float* Wv = (const float*)d_in[7];
  const float* bv = (const float*)d_in[8];
  const float* Wo = (const float*)d_in[9];
  const float* bo = (const float*)d_in[10];
  const float* W1 = (const float*)d_in[11];
  const float* b1 = (const float*)d_in[12];
  const float* W2 = (const float*)d_in[13];
  const float* b2 = (const float*)d_in[14];
  const float* g1 = (const float*)d_in[15];
  const float* be1 = (const float*)d_in[16];
  const float* g2 = (const float*)d_in[17];
  const float* be2 = (const float*)d_in[18];

  char* p = (char*)d_ws;
  auto carve = [&](size_t bytes) { char* r = p; p += (bytes + 255) & ~(size_t)255; return r; };
  bf16* wt_qkv = (bf16*)carve((size_t)3072 * 1024 * 2);
  bf16* wt_o   = (bf16*)carve((size_t)1024 * 1024 * 2);
  bf16* wt_1   = (bf16*)carve((size_t)4096 * 1024 * 2);
  bf16* wt_2   = (bf16*)carve((size_t)1024 * 4096 * 2);
  bf16* xb     = (bf16*)carve((size_t)4096 * 1024 * 2);
  bf16* qb     = (bf16*)carve((size_t)4096 * 1024 * 2);
  bf16* kb     = (bf16*)carve((size_t)4096 * 1024 * 2);
  bf16* vb     = (bf16*)carve((size_t)4096 * 1024 * 2);
  bf16* vtb    = (bf16*)carve((size_t)4096 * 1024 * 2);
  bf16* ctxb   = (bf16*)carve((size_t)4096 * 1024 * 2);
  float* yb    = (float*)carve((size_t)4096 * 1024 * 4);
  float* pb    = (float*)carve((size_t)4 * 4096 * 1024 * 4);   // split-K partials
  bf16* hb     = (bf16*)carve((size_t)4096 * 4096 * 2);

  embed_kernel<<<4096, 256, 0, stream>>>(tokens, emb, xb);

  for (int l = 0; l < 6; ++l) {
    TArgs ta;
    ta.j[0] = { Wq + (size_t)l * 1024 * 1024, wt_qkv,                  1024, 1024, 0 };
    ta.j[1] = { Wk + (size_t)l * 1024 * 1024, wt_qkv + 1024 * 1024,    1024, 1024, 1024 };
    ta.j[2] = { Wv + (size_t)l * 1024 * 1024, wt_qkv + 2 * 1024 * 1024,1024, 1024, 2048 };
    ta.j[3] = { Wo + (size_t)l * 1024 * 1024, wt_o,                    1024, 1024, 3072 };
    ta.j[4] = { W1 + (size_t)l * 1024 * 4096, wt_1,                    1024, 4096, 4096 };
    ta.j[5] = { W2 + (size_t)l * 4096 * 1024, wt_2,                    4096, 1024, 8192 };
    wtrans_kernel<<<12288, 256, 0, stream>>>(ta);

    // QKV: 256^2 tile, grid 16x12 = 192
    gemm256<0><<<192, 512, 0, stream>>>(xb, wt_qkv, 1024, 1024, 3072, 12,
        bq + (size_t)l * 1024, bk + (size_t)l * 1024, bv + (size_t)l * 1024,
        nullptr, nullptr, qb, kb, vb);

    vtrans_kernel<<<dim3(32, 32), 256, 0, stream>>>(vb, vtb);

    attn_kernel<<<512, 512, 0, stream>>>(qb, kb, vtb, ctxb);

    // O-proj: 128^2 pipeline, single-pass K=1024, grid 256
    gemm128p<<<256, 256, 0, stream>>>(ctxb, wt_o, 1024,
        bo + (size_t)l * 1024, xb, yb);
    ln_kernel<<<4096, 256, 0, stream>>>(yb, g1 + (size_t)l * 1024,
        be1 + (size_t)l * 1024, xb);

    // FFN1: 256^2 tile, grid 16x16 = 256
    gemm256<2><<<256, 512, 0, stream>>>(xb, wt_1, 1024, 1024, 4096, 16,
        b1 + (size_t)l * 4096, nullptr, nullptr, hb,
        nullptr, nullptr, nullptr, nullptr);

    // FFN2: 256^2 tile split-K=4 (K-slice 1024), grid (64,4) = 256 blocks
    gemm256<1><<<dim3(64, 4), 512, 0, stream>>>(hb, wt_2, 4096, 1024, 1024, 4,
        nullptr, nullptr, nullptr, nullptr, pb,
        nullptr, nullptr, nullptr);
    ln2_kernel<4><<<4096, 256, 0, stream>>>(pb, xb, b2 + (size_t)l * 1024,
        g2 + (size_t)l * 1024, be2 + (size_t)l * 1024, xb,
        (l == 5) ? (float*)d_out : nullptr);
  }
}

// Round 12
// 1398.922 us; speedup vs baseline: 1.1044x; 1.0102x over previous
//
#include <hip/hip_runtime.h>
#include <hip/hip_bf16.h>
#include <cstdint>
#include <cstddef>

// ---------------------------------------------------------------------------
// Transformer encoder, 6 layers: B=2,S=2048,D=1024,H=16,HD=64,F=4096.
// QKV+FFN1: 256^2-tile 8-wave GEMM, counted-vmcnt double buffer (T2+T3+T4+T5).
// FFN2: gemm256 split-K=4 -> fp32 partials + fused LN. O-proj: 128^2 pipeline.
// Flash attention: 8-wave blocks (Q=128), KVBLK=128 (2 barriers per 128 keys),
// XCD-swizzled grid, swapped QK^T, T2 swizzle, reg-staged K/V double buffer.
// ---------------------------------------------------------------------------

typedef __bf16 bf16;
typedef __bf16 bf16x2 __attribute__((ext_vector_type(2)));
typedef __bf16 bf16x4 __attribute__((ext_vector_type(4)));
typedef __bf16 bf16x8 __attribute__((ext_vector_type(8)));
typedef float  f32x4  __attribute__((ext_vector_type(4)));

#define MFMA16(a, b, c) __builtin_amdgcn_mfma_f32_16x16x32_bf16((a), (b), (c), 0, 0, 0)

static __device__ __forceinline__ void load_lds16(const void* g, void* l) {
  __builtin_amdgcn_global_load_lds((const __attribute__((address_space(1))) void*)g,
                                   (__attribute__((address_space(3))) void*)l, 16, 0, 0);
}

#define BAR()   __builtin_amdgcn_s_barrier()
#define SCH0()  __builtin_amdgcn_sched_barrier(0)
#define VMCNT8() asm volatile("s_waitcnt vmcnt(8)" ::: "memory")
#define VMCNT0() asm volatile("s_waitcnt vmcnt(0)" ::: "memory")

// ---------------- embedding + positional encoding -> bf16 x ----------------
__global__ __launch_bounds__(256) void embed_kernel(const int* __restrict__ tok,
                                                    const float* __restrict__ emb,
                                                    bf16* __restrict__ xo) {
  const int row = blockIdx.x;          // b*2048 + s
  const int s = row & 2047;
  const int t = tok[row];
  const int d0 = threadIdx.x * 4;
  const float4 e = *(const float4*)&emb[(size_t)t * 1024 + d0];
  const float* ef = (const float*)&e;
  bf16x4 o4;
#pragma unroll
  for (int j = 0; j < 4; ++j) {
    const int d = d0 + j;
    const float div = __expf(-(float)(d & ~1) * 0.00899447301950864f); // ln(1e4)/1024
    const float arg = (float)s * div;
    const float pe = (d & 1) ? cosf(arg) : sinf(arg);
    o4[j] = (bf16)(ef[j] + pe);
  }
  *(bf16x4*)&xo[(size_t)row * 1024 + d0] = o4;
}

// ------------- weight transpose: fp32 [K][N] -> bf16 [N][K], batched --------
struct TJob { const float* src; bf16* dst; int K; int N; int t0; };
struct TArgs { TJob j[6]; };

__global__ __launch_bounds__(256) void wtrans_kernel(TArgs a) {
  __shared__ float t[32][33];
  const int blk = blockIdx.x;
  const float* src = a.j[0].src; bf16* dst = a.j[0].dst;
  int K = a.j[0].K, N = a.j[0].N, t0 = a.j[0].t0;
#pragma unroll
  for (int q = 1; q < 6; ++q)
    if (blk >= a.j[q].t0) { src = a.j[q].src; dst = a.j[q].dst; K = a.j[q].K; N = a.j[q].N; t0 = a.j[q].t0; }
  const int tj = blk - t0;
  const int tilesK = K >> 5;
  const int tk = (tj % tilesK) << 5;
  const int tn = (tj / tilesK) << 5;
  const int lx = threadIdx.x & 31, ly = threadIdx.x >> 5;
#pragma unroll
  for (int i = 0; i < 4; ++i)
    t[ly + 8 * i][lx] = src[(size_t)(tk + ly + 8 * i) * N + tn + lx];
  __syncthreads();
#pragma unroll
  for (int i = 0; i < 4; ++i)
    dst[(size_t)(tn + ly + 8 * i) * K + tk + lx] = (bf16)t[lx][ly + 8 * i];
}

// -------- V transpose per layer: [bh][s][64] bf16 -> [bh][64][s] bf16 -------
__global__ __launch_bounds__(256) void vtrans_kernel(const bf16* __restrict__ v,
                                                     bf16* __restrict__ vt) {
  __shared__ bf16 t[64][72];
  const int bh = blockIdx.y;
  const int s0 = blockIdx.x * 64;
  const int tid = threadIdx.x;
#pragma unroll
  for (int it = 0; it < 2; ++it) {
    const int idx = tid + it * 256;
    const int sr = idx >> 3, h8 = (idx & 7) * 8;
    *(bf16x8*)&t[sr][h8] = *(const bf16x8*)&v[((size_t)bh * 2048 + s0 + sr) * 64 + h8];
  }
  __syncthreads();
#pragma unroll
  for (int it = 0; it < 2; ++it) {
    const int idx = tid + it * 256;
    const int hd = idx >> 3, s8 = (idx & 7) * 8;
    bf16x8 o;
#pragma unroll
    for (int j = 0; j < 8; ++j) o[j] = t[s8 + j][hd];
    *(bf16x8*)&vt[((size_t)bh * 64 + hd) * 2048 + s0 + s8] = o;
  }
}

// ======================= shared GEMM building blocks ========================
static __device__ __forceinline__ bf16x8 ldsfrag(const bf16* base, int row, int colb) {
  int off = row * 128 + colb;
  off ^= ((off >> 7) & 7) << 4;
  return *(const bf16x8*)((const char*)base + off);
}

// ================= 256x256-tile 8-wave GEMM, counted-vmcnt =================
static __device__ __forceinline__ void stage_tile(const bf16* __restrict__ Ag,
    const bf16* __restrict__ Bg, int Kstr, int kt, bf16* lA, bf16* lB, int tid) {
  const char* wbaseA = (const char*)lA + ((tid >> 6) << 10);
  const char* wbaseB = (const char*)lB + ((tid >> 6) << 10);
#pragma unroll
  for (int s = 0; s < 4; ++s) {
    const int L = s * 8192 + tid * 16;
    const int off = L ^ (((L >> 7) & 7) << 4);
    load_lds16(Ag + (size_t)(off >> 7) * Kstr + kt * 64 + ((off & 127) >> 1),
               (void*)(wbaseA + s * 8192));
  }
#pragma unroll
  for (int s = 0; s < 4; ++s) {
    const int L = s * 8192 + tid * 16;
    const int off = L ^ (((L >> 7) & 7) << 4);
    load_lds16(Bg + (size_t)(off >> 7) * Kstr + kt * 64 + ((off & 127) >> 1),
               (void*)(wbaseB + s * 8192));
  }
}

static __device__ __forceinline__ void compute_tile(const bf16* lA, const bf16* lB,
    int wm, int wn, int lr, int lg, f32x4 (&acc)[8][4]) {
  bf16x8 bfr[4][2];
#pragma unroll
  for (int n = 0; n < 4; ++n)
#pragma unroll
    for (int kk = 0; kk < 2; ++kk)
      bfr[n][kk] = ldsfrag(lB, wn * 64 + n * 16 + lr, kk * 64 + lg * 16);
#pragma unroll
  for (int m = 0; m < 8; ++m) {
    const bf16x8 a0 = ldsfrag(lA, wm * 128 + m * 16 + lr, lg * 16);
    const bf16x8 a1 = ldsfrag(lA, wm * 128 + m * 16 + lr, 64 + lg * 16);
    __builtin_amdgcn_s_setprio(1);
#pragma unroll
    for (int n = 0; n < 4; ++n) {
      acc[m][n] = MFMA16(a0, bfr[n][0], acc[m][n]);
      acc[m][n] = MFMA16(a1, bfr[n][1], acc[m][n]);
    }
    __builtin_amdgcn_s_setprio(0);
  }
}

template <int EPI>   // 0: qkv scatter, 1: fp32 partial (split-K), 2: bias+relu
__global__ __launch_bounds__(512, 2) void gemm256(
    const bf16* __restrict__ A, const bf16* __restrict__ Bt,
    int Kstr, int Kloop, int Nn, int nbx,
    const float* __restrict__ bias0, const float* __restrict__ bias1,
    const float* __restrict__ bias2, bf16* __restrict__ outb,
    float* __restrict__ pout,
    bf16* __restrict__ q_out, bf16* __restrict__ k_out, bf16* __restrict__ v_out) {
  __shared__ __align__(16) bf16 lds[4][16384];   // A0,B0,A1,B1 (32KB each)
  const int bz = blockIdx.y;
  const bf16* Abase = A + (size_t)bz * Kloop;
  const bf16* Bbase = Bt + (size_t)bz * Kloop;
  const int cpx = gridDim.x >> 3;
  const int wg = (blockIdx.x & 7) * cpx + (blockIdx.x >> 3);
  const int bx = wg % nbx, by = wg / nbx;
  const int tid = threadIdx.x;
  const int lane = tid & 63, wave = tid >> 6;
  const int lr = lane & 15, lg = lane >> 4;
  const int wm = wave >> 2, wn = wave & 3;
  const int m0 = by * 256, n0 = bx * 256;

  const bf16* Ag = Abase + (size_t)m0 * Kstr;
  const bf16* Bg = Bbase + (size_t)n0 * Kstr;
  bf16* LA0 = lds[0]; bf16* LB0 = lds[1];
  bf16* LA1 = lds[2]; bf16* LB1 = lds[3];

  f32x4 acc[8][4] = {};
  const int T = Kloop >> 6;

  stage_tile(Ag, Bg, Kstr, 0, LA0, LB0, tid);
  stage_tile(Ag, Bg, Kstr, 1, LA1, LB1, tid);
  VMCNT8(); BAR(); SCH0();

  for (int t = 0; t + 3 < T; t += 2) {
    compute_tile(LA0, LB0, wm, wn, lr, lg, acc);
    BAR(); SCH0();
    stage_tile(Ag, Bg, Kstr, t + 2, LA0, LB0, tid);
    VMCNT8(); BAR(); SCH0();
    compute_tile(LA1, LB1, wm, wn, lr, lg, acc);
    BAR(); SCH0();
    stage_tile(Ag, Bg, Kstr, t + 3, LA1, LB1, tid);
    VMCNT8(); BAR(); SCH0();
  }
  compute_tile(LA0, LB0, wm, wn, lr, lg, acc);   // tile T-2
  VMCNT0(); BAR(); SCH0();                       // tile T-1 landed
  compute_tile(LA1, LB1, wm, wn, lr, lg, acc);   // tile T-1

#pragma unroll
  for (int m = 0; m < 8; ++m)
#pragma unroll
    for (int n = 0; n < 4; ++n)
#pragma unroll
      for (int r = 0; r < 4; ++r) {
        const int row = m0 + wm * 128 + m * 16 + lg * 4 + r;
        const int col = n0 + wn * 64 + n * 16 + lr;
        float val = acc[m][n][r];
        if (EPI == 0) {
          const int which = col >> 10, hc = col & 1023;
          const float* bs = (which == 0) ? bias0 : (which == 1) ? bias1 : bias2;
          bf16* dst = (which == 0) ? q_out : (which == 1) ? k_out : v_out;
          val += bs[hc];
          const int b = row >> 11, s = row & 2047;
          const int h = hc >> 6, hd = hc & 63;
          dst[(((size_t)b * 16 + h) * 2048 + s) * 64 + hd] = (bf16)val;
        } else if (EPI == 1) {
          pout[(size_t)bz * 4096 * 1024 + (size_t)row * 1024 + col] = val;
        } else {
          val += bias0[col];
          outb[(size_t)row * Nn + col] = (bf16)(val > 0.f ? val : 0.f);
        }
      }
}

// ========== 128x128-tile 4-wave GEMM, counted-vmcnt (O-proj K=1024) =========
static __device__ __forceinline__ void stage128(const bf16* __restrict__ Ag,
    const bf16* __restrict__ Bg, int Kstr, int kt, bf16* lA, bf16* lB, int tid) {
  const char* dA = (const char*)lA + ((tid >> 6) << 10);
  const char* dB = (const char*)lB + ((tid >> 6) << 10);
#pragma unroll
  for (int s = 0; s < 4; ++s) {
    const int L = s * 4096 + tid * 16;
    const int off = L ^ (((L >> 7) & 7) << 4);
    load_lds16(Ag + (size_t)(off >> 7) * Kstr + kt * 64 + ((off & 127) >> 1),
               (void*)(dA + s * 4096));
  }
#pragma unroll
  for (int s = 0; s < 4; ++s) {
    const int L = s * 4096 + tid * 16;
    const int off = L ^ (((L >> 7) & 7) << 4);
    load_lds16(Bg + (size_t)(off >> 7) * Kstr + kt * 64 + ((off & 127) >> 1),
               (void*)(dB + s * 4096));
  }
}

static __device__ __forceinline__ void compute128(const bf16* lA, const bf16* lB,
    int wm, int wn, int lr, int lg, f32x4 (&acc)[4][4]) {
  bf16x8 bfr[4][2];
#pragma unroll
  for (int n = 0; n < 4; ++n)
#pragma unroll
    for (int kk = 0; kk < 2; ++kk)
      bfr[n][kk] = ldsfrag(lB, wn * 64 + n * 16 + lr, kk * 64 + lg * 16);
#pragma unroll
  for (int m = 0; m < 4; ++m) {
    const bf16x8 a0 = ldsfrag(lA, wm * 64 + m * 16 + lr, lg * 16);
    const bf16x8 a1 = ldsfrag(lA, wm * 64 + m * 16 + lr, 64 + lg * 16);
    __builtin_amdgcn_s_setprio(1);
#pragma unroll
    for (int n = 0; n < 4; ++n) {
      acc[m][n] = MFMA16(a0, bfr[n][0], acc[m][n]);
      acc[m][n] = MFMA16(a1, bfr[n][1], acc[m][n]);
    }
    __builtin_amdgcn_s_setprio(0);
  }
}

__global__ __launch_bounds__(256, 2) void gemm128p(
    const bf16* __restrict__ A, const bf16* __restrict__ Bt, int Kk,
    const float* __restrict__ bias, const bf16* __restrict__ resid,
    float* __restrict__ outf) {
  __shared__ __align__(16) bf16 lds[4][8192];    // A0,B0,A1,B1 (16KB each)
  const int cpx = gridDim.x >> 3;
  const int wg = (blockIdx.x & 7) * cpx + (blockIdx.x >> 3);
  const int bx = wg & 7, by = wg >> 3;           // nbx = 8 (N=1024)
  const int tid = threadIdx.x;
  const int lane = tid & 63, wave = tid >> 6;
  const int lr = lane & 15, lg = lane >> 4;
  const int wm = wave >> 1, wn = wave & 1;
  const int m0 = by * 128, n0 = bx * 128;

  const bf16* Ag = A + (size_t)m0 * Kk;
  const bf16* Bg = Bt + (size_t)n0 * Kk;
  bf16* LA0 = lds[0]; bf16* LB0 = lds[1];
  bf16* LA1 = lds[2]; bf16* LB1 = lds[3];

  f32x4 acc[4][4] = {};
  const int T = Kk >> 6;

  stage128(Ag, Bg, Kk, 0, LA0, LB0, tid);
  stage128(Ag, Bg, Kk, 1, LA1, LB1, tid);
  VMCNT8(); BAR(); SCH0();

  for (int t = 0; t + 3 < T; t += 2) {
    compute128(LA0, LB0, wm, wn, lr, lg, acc);
    BAR(); SCH0();
    stage128(Ag, Bg, Kk, t + 2, LA0, LB0, tid);
    VMCNT8(); BAR(); SCH0();
    compute128(LA1, LB1, wm, wn, lr, lg, acc);
    BAR(); SCH0();
    stage128(Ag, Bg, Kk, t + 3, LA1, LB1, tid);
    VMCNT8(); BAR(); SCH0();
  }
  compute128(LA0, LB0, wm, wn, lr, lg, acc);     // tile T-2
  VMCNT0(); BAR(); SCH0();                       // tile T-1 landed
  compute128(LA1, LB1, wm, wn, lr, lg, acc);     // tile T-1

#pragma unroll
  for (int m = 0; m < 4; ++m)
#pragma unroll
    for (int n = 0; n < 4; ++n)
#pragma unroll
      for (int r = 0; r < 4; ++r) {
        const int row = m0 + wm * 64 + m * 16 + lg * 4 + r;
        const int col = n0 + wn * 64 + n * 16 + lr;
        const float val = acc[m][n][r] + bias[col]
                        + (float)resid[(size_t)row * 1024 + col];
        outf[(size_t)row * 1024 + col] = val;
      }
}

// ------------------------- flash attention (per b,h) ------------------------
// 1D grid 512, XCD-swizzled: wid = (bid&7)*64 + (bid>>3). block: 512 = 8
// waves; wave w owns q-rows [128*(wid&15) + 16w, +16). KVBLK=128: one
// barrier-pair per 128-key chunk, processed as two 64-key halves with NO
// barrier between (P is per-wave; K/V LDS read-only during compute).
// Reg-staged K/V double buffer, slot-XOR swizzle (slot ^= row&7, low-3-bit
// involution for both 8-slot K rows and 16-slot V rows), swapped QK^T,
// log2-domain softmax with defer-max. Chunk loop MUST be unrolled by 2
// (rule #20: runtime-indexed ext_vector arrays go to scratch; round 3).
__global__ __launch_bounds__(512) void attn_kernel(const bf16* __restrict__ q,
                                                   const bf16* __restrict__ k,
                                                   const bf16* __restrict__ vt,
                                                   bf16* __restrict__ ctxo) {
  __shared__ __align__(16) bf16 Kl[128][64];  // rows = key, 8 slots of 16B
  __shared__ __align__(16) bf16 Vt[64][128];  // rows = hd, 16 slots of 16B
  __shared__ __align__(16) bf16 Pl[8][16][64];
  const int wid = ((blockIdx.x & 7) << 6) + (blockIdx.x >> 3);
  const int bh = wid >> 4;
  const int q0 = (wid & 15) * 128;
  const int tid = threadIdx.x;
  const int lane = tid & 63, w = tid >> 6;
  const int lr = lane & 15, lg = lane >> 4;
  const int swz = lr & 7;

  const bf16* qp = q + ((size_t)bh * 2048 + q0 + w * 16) * 64;
  bf16x8 qf0 = *(const bf16x8*)&qp[lr * 64 + lg * 8];
  bf16x8 qf1 = *(const bf16x8*)&qp[lr * 64 + lg * 8 + 32];
  const float qs = 0.18033688011112042f;      // (1/8)*log2(e)
#pragma unroll
  for (int j = 0; j < 8; ++j) {
    qf0[j] = (bf16)((float)qf0[j] * qs);
    qf1[j] = (bf16)((float)qf1[j] * qs);
  }
  bf16x8 ones8;
#pragma unroll
  for (int j = 0; j < 8; ++j) ones8[j] = (bf16)1.0f;

  const bf16* kbase = k + (size_t)bh * 2048 * 64;
  const bf16* vtb = vt + (size_t)bh * 64 * 2048;

  // K staging: thread t covers key rows (t>>3) and (t>>3)+64, col (t&7)*8
  const int skr = tid >> 3;
  const int skc = (tid & 7) * 8;
  const int skcs = skc ^ ((skr & 7) << 3);      // (+64 rows: same low-3 bits)
  // V staging: thread t covers hd rows (t>>4) and (t>>4)+32, slot (t&15)
  const int svr = tid >> 4;
  const int svslot = tid & 15;
  const int svs = (svslot ^ (svr & 7)) * 8;     // (+32 rows: same low-3 bits)

  f32x4 acc[4] = {};
  f32x4 accl = {};
  float mq = -1e30f;

  bf16x8 kr[2][2], vr[2][2];
  kr[0][0] = *(const bf16x8*)&kbase[(size_t)skr * 64 + skc];
  kr[0][1] = *(const bf16x8*)&kbase[(size_t)(skr + 64) * 64 + skc];
  vr[0][0] = *(const bf16x8*)&vtb[(size_t)svr * 2048 + svslot * 8];
  vr[0][1] = *(const bf16x8*)&vtb[(size_t)(svr + 32) * 2048 + svslot * 8];

#pragma unroll 2
  for (int c = 0; c < 16; ++c) {
    const int pp = c & 1;
    *(bf16x8*)&Kl[skr][skcs]      = kr[pp][0];
    *(bf16x8*)&Kl[skr + 64][skcs] = kr[pp][1];
    *(bf16x8*)&Vt[svr][svs]       = vr[pp][0];
    *(bf16x8*)&Vt[svr + 32][svs]  = vr[pp][1];
    if (c + 1 < 16) {
      const int key0n = (c + 1) * 128;
      kr[pp ^ 1][0] = *(const bf16x8*)&kbase[(size_t)(key0n + skr) * 64 + skc];
      kr[pp ^ 1][1] = *(const bf16x8*)&kbase[(size_t)(key0n + skr + 64) * 64 + skc];
      vr[pp ^ 1][0] = *(const bf16x8*)&vtb[(size_t)svr * 2048 + key0n + svslot * 8];
      vr[pp ^ 1][1] = *(const bf16x8*)&vtb[(size_t)(svr + 32) * 2048 + key0n + svslot * 8];
    }
    __syncthreads();

#pragma unroll
    for (int hf = 0; hf < 2; ++hf) {
      // --- swapped QK^T: st[ks][r], key = hf*64 + ks*16 + lg*4 + r ---
      f32x4 st[4];
      __builtin_amdgcn_s_setprio(1);
#pragma unroll
      for (int ks = 0; ks < 4; ++ks) {
        const bf16x8 kf0 = *(const bf16x8*)&Kl[hf * 64 + ks * 16 + lr][(lg ^ swz) << 3];
        const bf16x8 kf1 = *(const bf16x8*)&Kl[hf * 64 + ks * 16 + lr][((lg + 4) ^ swz) << 3];
        f32x4 sa = {};
        sa = MFMA16(kf0, qf0, sa);
        sa = MFMA16(kf1, qf1, sa);
        st[ks] = sa;
      }
      __builtin_amdgcn_s_setprio(0);

      // --- in-lane online softmax (log2 domain) ---
      float mx = st[0][0];
#pragma unroll
      for (int ks = 0; ks < 4; ++ks)
#pragma unroll
        for (int r = 0; r < 4; ++r) mx = fmaxf(mx, st[ks][r]);
      mx = fmaxf(mx, __shfl_xor(mx, 16));
      mx = fmaxf(mx, __shfl_xor(mx, 32));
      if (!__all(mx - mq <= 8.0f)) {               // defer-max (T13)
        const float resc = exp2f(mq - mx);
        mq = mx;
        float rq[4];
#pragma unroll
        for (int r = 0; r < 4; ++r) rq[r] = __shfl(resc, lg * 4 + r);
#pragma unroll
        for (int r = 0; r < 4; ++r) {
          accl[r] *= rq[r];
#pragma unroll
          for (int jn = 0; jn < 4; ++jn) acc[jn][r] *= rq[r];
        }
      }
#pragma unroll
      for (int ks = 0; ks < 4; ++ks) {             // P pack + vectorized store
        bf16x4 pk;
#pragma unroll
        for (int r = 0; r < 4; ++r) pk[r] = (bf16)exp2f(st[ks][r] - mq);
        const int col = (((ks * 2 + (lg >> 1)) ^ swz) << 3) + ((lg & 1) << 2);
        *(bf16x4*)&Pl[w][lr][col] = pk;
      }

      // --- PV + denominators ---
      const bf16x8 pf0 = *(const bf16x8*)&Pl[w][lr][(lg ^ swz) << 3];
      const bf16x8 pf1 = *(const bf16x8*)&Pl[w][lr][((lg + 4) ^ swz) << 3];
      __builtin_amdgcn_s_setprio(1);
#pragma unroll
      for (int jn = 0; jn < 4; ++jn) {
        const bf16x8 vf0 = *(const bf16x8*)&Vt[jn * 16 + lr][hf * 64 + ((lg ^ swz) << 3)];
        const bf16x8 vf1 = *(const bf16x8*)&Vt[jn * 16 + lr][hf * 64 + (((lg + 4) ^ swz) << 3)];
        acc[jn] = MFMA16(pf0, vf0, acc[jn]);
        acc[jn] = MFMA16(pf1, vf1, acc[jn]);
      }
      accl = MFMA16(pf0, ones8, accl);
      accl = MFMA16(pf1, ones8, accl);
      __builtin_amdgcn_s_setprio(0);
    }
    __syncthreads();
  }

  const int bb = bh >> 4, hh = bh & 15;
#pragma unroll
  for (int r = 0; r < 4; ++r) {
    const float inv = 1.f / accl[r];
    const size_t rowg = (size_t)bb * 2048 + q0 + w * 16 + lg * 4 + r;
#pragma unroll
    for (int jn = 0; jn < 4; ++jn)
      ctxo[rowg * 1024 + hh * 64 + jn * 16 + lr] = (bf16)(acc[jn][r] * inv);
  }
}

// ---------- fused split-K reduce + bias + residual + LayerNorm --------------
// fout != nullptr: write fp32 result directly (final layer -> d_out).
template <int NP>
__global__ __launch_bounds__(256) void ln2_kernel(const float* __restrict__ p,
                                                  const bf16* __restrict__ resid,
                                                  const float* __restrict__ bias,
                                                  const float* __restrict__ g,
                                                  const float* __restrict__ be,
                                                  bf16* __restrict__ xo,
                                                  float* __restrict__ fout) {
  const int row = blockIdx.x, tid = threadIdx.x;
  const bf16x4 rv = *(const bf16x4*)&resid[(size_t)row * 1024 + tid * 4];
  const float4 bb = ((const float4*)bias)[tid];
  float4 v;
  v.x = bb.x + (float)rv[0];
  v.y = bb.y + (float)rv[1];
  v.z = bb.z + (float)rv[2];
  v.w = bb.w + (float)rv[3];
#pragma unroll
  for (int pl = 0; pl < NP; ++pl) {
    const float4 a = ((const float4*)(p + (size_t)pl * 4096 * 1024 + (size_t)row * 1024))[tid];
    v.x += a.x; v.y += a.y; v.z += a.z; v.w += a.w;
  }
  float s = v.x + v.y + v.z + v.w;
  float s2 = v.x * v.x + v.y * v.y + v.z * v.z + v.w * v.w;
#pragma unroll
  for (int o = 32; o > 0; o >>= 1) { s += __shfl_down(s, o); s2 += __shfl_down(s2, o); }
  __shared__ float red[8];
  if ((tid & 63) == 0) { red[tid >> 6] = s; red[4 + (tid >> 6)] = s2; }
  __syncthreads();
  s = red[0] + red[1] + red[2] + red[3];
  s2 = red[4] + red[5] + red[6] + red[7];
  const float mean = s * (1.f / 1024.f);
  const float var = s2 * (1.f / 1024.f) - mean * mean;
  const float rstd = rsqrtf(var + 1e-5f);
  const float4 gv = ((const float4*)g)[tid];
  const float4 bv = ((const float4*)be)[tid];
  float4 of;
  of.x = (v.x - mean) * rstd * gv.x + bv.x;
  of.y = (v.y - mean) * rstd * gv.y + bv.y;
  of.z = (v.z - mean) * rstd * gv.z + bv.z;
  of.w = (v.w - mean) * rstd * gv.w + bv.w;
  if (fout) {
    ((float4*)(fout + (size_t)row * 1024))[tid] = of;
  } else {
    bf16x4 o4;
    o4[0] = (bf16)of.x; o4[1] = (bf16)of.y; o4[2] = (bf16)of.z; o4[3] = (bf16)of.w;
    *(bf16x4*)&xo[(size_t)row * 1024 + tid * 4] = o4;
  }
}

// ------------------------------ LayerNorm (fp32 y) --------------------------
__global__ __launch_bounds__(256) void ln_kernel(const float* __restrict__ y,
                                                 const float* __restrict__ g,
                                                 const float* __restrict__ be,
                                                 bf16* __restrict__ xo) {
  const int row = blockIdx.x, tid = threadIdx.x;
  const float4 v = ((const float4*)(y + (size_t)row * 1024))[tid];
  float s = v.x + v.y + v.z + v.w;
  float s2 = v.x * v.x + v.y * v.y + v.z * v.z + v.w * v.w;
#pragma unroll
  for (int o = 32; o > 0; o >>= 1) { s += __shfl_down(s, o); s2 += __shfl_down(s2, o); }
  __shared__ float red[8];
  if ((tid & 63) == 0) { red[tid >> 6] = s; red[4 + (tid >> 6)] = s2; }
  __syncthreads();
  s = red[0] + red[1] + red[2] + red[3];
  s2 = red[4] + red[5] + red[6] + red[7];
  const float mean = s * (1.f / 1024.f);
  const float var = s2 * (1.f / 1024.f) - mean * mean;
  const float rstd = rsqrtf(var + 1e-5f);
  const float4 gv = ((const float4*)g)[tid];
  const float4 bv = ((const float4*)be)[tid];
  bf16x4 o4;
  o4[0] = (bf16)((v.x - mean) * rstd * gv.x + bv.x);
  o4[1] = (bf16)((v.y - mean) * rstd * gv.y + bv.y);
  o4[2] = (bf16)((v.z - mean) * rstd * gv.z + bv.z);
  o4[3] = (bf16)((v.w - mean) * rstd * gv.w + bv.w);
  *(bf16x4*)&xo[(size_t)row * 1024 + tid * 4] = o4;
}

// ----------------------------------------------------------------------------
extern "C" void kernel_launch(void* const* d_in, const int* in_sizes, int n_in,
                              void* d_out, int out_size, void* d_ws, size_t ws_size,
                              hipStream_t stream) {
  const int* tokens = (const int*)d_in[0];
  const float* emb = (const float*)d_in[2];
  const float* Wq = (const float*)d_in[3];
  const float* bq = (const float*)d_in[4];
  const float* Wk = (const float*)d_in[5];
  const float* bk = (const float*)d_in[6];
  const float* Wv = (const float*)d_in[7];
  const float* bv = (const float*)d_in[8];
  const float* Wo = (const float*)d_in[9];
  const float* bo = (const float*)d_in[10];
  const float* W1 = (const float*)d_in[11];
  const float* b1 = (const float*)d_in[12];
  const float* W2 = (const float*)d_in[13];
  const float* b2 = (const float*)d_in[14];
  const float* g1 = (const float*)d_in[15];
  const float* be1 = (const float*)d_in[16];
  const float* g2 = (const float*)d_in[17];
  const float* be2 = (const float*)d_in[18];

  char* p = (char*)d_ws;
  auto carve = [&](size_t bytes) { char* r = p; p += (bytes + 255) & ~(size_t)255; return r; };
  bf16* wt_qkv = (bf16*)carve((size_t)3072 * 1024 * 2);
  bf16* wt_o   = (bf16*)carve((size_t)1024 * 1024 * 2);
  bf16* wt_1   = (bf16*)carve((size_t)4096 * 1024 * 2);
  bf16* wt_2   = (bf16*)carve((size_t)1024 * 4096 * 2);
  bf16* xb     = (bf16*)carve((size_t)4096 * 1024 * 2);
  bf16* qb     = (bf16*)carve((size_t)4096 * 1024 * 2);
  bf16* kb     = (bf16*)carve((size_t)4096 * 1024 * 2);
  bf16* vb     = (bf16*)carve((size_t)4096 * 1024 * 2);
  bf16* vtb    = (bf16*)carve((size_t)4096 * 1024 * 2);
  bf16* ctxb   = (bf16*)carve((size_t)4096 * 1024 * 2);
  float* yb    = (float*)carve((size_t)4096 * 1024 * 4);
  float* pb    = (float*)carve((size_t)4 * 4096 * 1024 * 4);   // split-K partials
  bf16* hb     = (bf16*)carve((size_t)4096 * 4096 * 2);

  embed_kernel<<<4096, 256, 0, stream>>>(tokens, emb, xb);

  for (int l = 0; l < 6; ++l) {
    TArgs ta;
    ta.j[0] = { Wq + (size_t)l * 1024 * 1024, wt_qkv,                  1024, 1024, 0 };
    ta.j[1] = { Wk + (size_t)l * 1024 * 1024, wt_qkv + 1024 * 1024,    1024, 1024, 1024 };
    ta.j[2] = { Wv + (size_t)l * 1024 * 1024, wt_qkv + 2 * 1024 * 1024,1024, 1024, 2048 };
    ta.j[3] = { Wo + (size_t)l * 1024 * 1024, wt_o,                    1024, 1024, 3072 };
    ta.j[4] = { W1 + (size_t)l * 1024 * 4096, wt_1,                    1024, 4096, 4096 };
    ta.j[5] = { W2 + (size_t)l * 4096 * 1024, wt_2,                    4096, 1024, 8192 };
    wtrans_kernel<<<12288, 256, 0, stream>>>(ta);

    // QKV: 256^2 tile, grid 16x12 = 192
    gemm256<0><<<192, 512, 0, stream>>>(xb, wt_qkv, 1024, 1024, 3072, 12,
        bq + (size_t)l * 1024, bk + (size_t)l * 1024, bv + (size_t)l * 1024,
        nullptr, nullptr, qb, kb, vb);

    vtrans_kernel<<<dim3(32, 32), 256, 0, stream>>>(vb, vtb);

    attn_kernel<<<512, 512, 0, stream>>>(qb, kb, vtb, ctxb);

    // O-proj: 128^2 pipeline, single-pass K=1024, grid 256
    gemm128p<<<256, 256, 0, stream>>>(ctxb, wt_o, 1024,
        bo + (size_t)l * 1024, xb, yb);
    ln_kernel<<<4096, 256, 0, stream>>>(yb, g1 + (size_t)l * 1024,
        be1 + (size_t)l * 1024, xb);

    // FFN1: 256^2 tile, grid 16x16 = 256
    gemm256<2><<<256, 512, 0, stream>>>(xb, wt_1, 1024, 1024, 4096, 16,
        b1 + (size_t)l * 4096, nullptr, nullptr, hb,
        nullptr, nullptr, nullptr, nullptr);

    // FFN2: 256^2 tile split-K=4 (K-slice 1024), grid (64,4) = 256 blocks
    gemm256<1><<<dim3(64, 4), 512, 0, stream>>>(hb, wt_2, 4096, 1024, 1024, 4,
        nullptr, nullptr, nullptr, nullptr, pb,
        nullptr, nullptr, nullptr);
    ln2_kernel<4><<<4096, 256, 0, stream>>>(pb, xb, b2 + (size_t)l * 1024,
        g2 + (size_t)l * 1024, be2 + (size_t)l * 1024, xb,
        (l == 5) ? (float*)d_out : nullptr);
  }
}

// Round 13
// 1380.808 us; speedup vs baseline: 1.1189x; 1.0131x over previous
//
#include <hip/hip_runtime.h>
#include <hip/hip_bf16.h>
#include <cstdint>
#include <cstddef>

// ---------------------------------------------------------------------------
// Transformer encoder, 6 layers: B=2,S=2048,D=1024,H=16,HD=64,F=4096.
// QKV+FFN1: 256^2-tile 8-wave GEMM, counted-vmcnt double buffer (T2+T3+T4+T5).
// FFN2: gemm256 split-K=4 -> fp32 partials + fused LN. O-proj: 128^2 pipeline.
// Flash attention: 8-wave blocks (Q=128), KVBLK=128, XCD-swizzled grid,
// swapped QK^T, T2 swizzle, reg-staged K/V double buffer.
// wtrans: 64x64 tiles, float4 reads + bf16x4 writes (transaction-efficient).
// ---------------------------------------------------------------------------

typedef __bf16 bf16;
typedef __bf16 bf16x2 __attribute__((ext_vector_type(2)));
typedef __bf16 bf16x4 __attribute__((ext_vector_type(4)));
typedef __bf16 bf16x8 __attribute__((ext_vector_type(8)));
typedef float  f32x4  __attribute__((ext_vector_type(4)));

#define MFMA16(a, b, c) __builtin_amdgcn_mfma_f32_16x16x32_bf16((a), (b), (c), 0, 0, 0)

static __device__ __forceinline__ void load_lds16(const void* g, void* l) {
  __builtin_amdgcn_global_load_lds((const __attribute__((address_space(1))) void*)g,
                                   (__attribute__((address_space(3))) void*)l, 16, 0, 0);
}

#define BAR()   __builtin_amdgcn_s_barrier()
#define SCH0()  __builtin_amdgcn_sched_barrier(0)
#define VMCNT8() asm volatile("s_waitcnt vmcnt(8)" ::: "memory")
#define VMCNT0() asm volatile("s_waitcnt vmcnt(0)" ::: "memory")

// ---------------- embedding + positional encoding -> bf16 x ----------------
__global__ __launch_bounds__(256) void embed_kernel(const int* __restrict__ tok,
                                                    const float* __restrict__ emb,
                                                    bf16* __restrict__ xo) {
  const int row = blockIdx.x;          // b*2048 + s
  const int s = row & 2047;
  const int t = tok[row];
  const int d0 = threadIdx.x * 4;
  const float4 e = *(const float4*)&emb[(size_t)t * 1024 + d0];
  const float* ef = (const float*)&e;
  bf16x4 o4;
#pragma unroll
  for (int j = 0; j < 4; ++j) {
    const int d = d0 + j;
    const float div = __expf(-(float)(d & ~1) * 0.00899447301950864f); // ln(1e4)/1024
    const float arg = (float)s * div;
    const float pe = (d & 1) ? cosf(arg) : sinf(arg);
    o4[j] = (bf16)(ef[j] + pe);
  }
  *(bf16x4*)&xo[(size_t)row * 1024 + d0] = o4;
}

// ------------- weight transpose: fp32 [K][N] -> bf16 [N][K], batched --------
// 64x64 tiles: float4 reads (256B/16 lanes), LDS [64][65] (2-way = free),
// bf16x4 writes along K (128B contiguous per 16 lanes).
struct TJob { const float* src; bf16* dst; int K; int N; int t0; };
struct TArgs { TJob j[6]; };

__global__ __launch_bounds__(256) void wtrans_kernel(TArgs a) {
  __shared__ float t[64][65];
  const int blk = blockIdx.x;
  const float* src = a.j[0].src; bf16* dst = a.j[0].dst;
  int K = a.j[0].K, N = a.j[0].N, t0 = a.j[0].t0;
#pragma unroll
  for (int q = 1; q < 6; ++q)
    if (blk >= a.j[q].t0) { src = a.j[q].src; dst = a.j[q].dst; K = a.j[q].K; N = a.j[q].N; t0 = a.j[q].t0; }
  const int tj = blk - t0;
  const int tilesK = K >> 6;
  const int tk = (tj % tilesK) << 6;
  const int tn = (tj / tilesK) << 6;
  const int tid = threadIdx.x;
  const int rr = tid >> 4;            // 0..15
  const int c4 = (tid & 15) * 4;
#pragma unroll
  for (int i = 0; i < 4; ++i) {
    const float4 v = *(const float4*)&src[(size_t)(tk + rr + 16 * i) * N + tn + c4];
    t[rr + 16 * i][c4 + 0] = v.x;
    t[rr + 16 * i][c4 + 1] = v.y;
    t[rr + 16 * i][c4 + 2] = v.z;
    t[rr + 16 * i][c4 + 3] = v.w;
  }
  __syncthreads();
  const int k0 = (tid & 15) * 4;
#pragma unroll
  for (int i = 0; i < 4; ++i) {
    const int n = rr + 16 * i;
    bf16x4 o;
#pragma unroll
    for (int j = 0; j < 4; ++j) o[j] = (bf16)t[k0 + j][n];
    *(bf16x4*)&dst[(size_t)(tn + n) * K + tk + k0] = o;
  }
}

// -------- V transpose per layer: [bh][s][64] bf16 -> [bh][64][s] bf16 -------
__global__ __launch_bounds__(256) void vtrans_kernel(const bf16* __restrict__ v,
                                                     bf16* __restrict__ vt) {
  __shared__ bf16 t[64][72];
  const int bh = blockIdx.y;
  const int s0 = blockIdx.x * 64;
  const int tid = threadIdx.x;
#pragma unroll
  for (int it = 0; it < 2; ++it) {
    const int idx = tid + it * 256;
    const int sr = idx >> 3, h8 = (idx & 7) * 8;
    *(bf16x8*)&t[sr][h8] = *(const bf16x8*)&v[((size_t)bh * 2048 + s0 + sr) * 64 + h8];
  }
  __syncthreads();
#pragma unroll
  for (int it = 0; it < 2; ++it) {
    const int idx = tid + it * 256;
    const int hd = idx >> 3, s8 = (idx & 7) * 8;
    bf16x8 o;
#pragma unroll
    for (int j = 0; j < 8; ++j) o[j] = t[s8 + j][hd];
    *(bf16x8*)&vt[((size_t)bh * 64 + hd) * 2048 + s0 + s8] = o;
  }
}

// ======================= shared GEMM building blocks ========================
static __device__ __forceinline__ bf16x8 ldsfrag(const bf16* base, int row, int colb) {
  int off = row * 128 + colb;
  off ^= ((off >> 7) & 7) << 4;
  return *(const bf16x8*)((const char*)base + off);
}

// ================= 256x256-tile 8-wave GEMM, counted-vmcnt =================
static __device__ __forceinline__ void stage_tile(const bf16* __restrict__ Ag,
    const bf16* __restrict__ Bg, int Kstr, int kt, bf16* lA, bf16* lB, int tid) {
  const char* wbaseA = (const char*)lA + ((tid >> 6) << 10);
  const char* wbaseB = (const char*)lB + ((tid >> 6) << 10);
#pragma unroll
  for (int s = 0; s < 4; ++s) {
    const int L = s * 8192 + tid * 16;
    const int off = L ^ (((L >> 7) & 7) << 4);
    load_lds16(Ag + (size_t)(off >> 7) * Kstr + kt * 64 + ((off & 127) >> 1),
               (void*)(wbaseA + s * 8192));
  }
#pragma unroll
  for (int s = 0; s < 4; ++s) {
    const int L = s * 8192 + tid * 16;
    const int off = L ^ (((L >> 7) & 7) << 4);
    load_lds16(Bg + (size_t)(off >> 7) * Kstr + kt * 64 + ((off & 127) >> 1),
               (void*)(wbaseB + s * 8192));
  }
}

static __device__ __forceinline__ void compute_tile(const bf16* lA, const bf16* lB,
    int wm, int wn, int lr, int lg, f32x4 (&acc)[8][4]) {
  bf16x8 bfr[4][2];
#pragma unroll
  for (int n = 0; n < 4; ++n)
#pragma unroll
    for (int kk = 0; kk < 2; ++kk)
      bfr[n][kk] = ldsfrag(lB, wn * 64 + n * 16 + lr, kk * 64 + lg * 16);
#pragma unroll
  for (int m = 0; m < 8; ++m) {
    const bf16x8 a0 = ldsfrag(lA, wm * 128 + m * 16 + lr, lg * 16);
    const bf16x8 a1 = ldsfrag(lA, wm * 128 + m * 16 + lr, 64 + lg * 16);
    __builtin_amdgcn_s_setprio(1);
#pragma unroll
    for (int n = 0; n < 4; ++n) {
      acc[m][n] = MFMA16(a0, bfr[n][0], acc[m][n]);
      acc[m][n] = MFMA16(a1, bfr[n][1], acc[m][n]);
    }
    __builtin_amdgcn_s_setprio(0);
  }
}

template <int EPI>   // 0: qkv scatter, 1: fp32 partial (split-K), 2: bias+relu
__global__ __launch_bounds__(512, 2) void gemm256(
    const bf16* __restrict__ A, const bf16* __restrict__ Bt,
    int Kstr, int Kloop, int Nn, int nbx,
    const float* __restrict__ bias0, const float* __restrict__ bias1,
    const float* __restrict__ bias2, bf16* __restrict__ outb,
    float* __restrict__ pout,
    bf16* __restrict__ q_out, bf16* __restrict__ k_out, bf16* __restrict__ v_out) {
  __shared__ __align__(16) bf16 lds[4][16384];   // A0,B0,A1,B1 (32KB each)
  const int bz = blockIdx.y;
  const bf16* Abase = A + (size_t)bz * Kloop;
  const bf16* Bbase = Bt + (size_t)bz * Kloop;
  const int cpx = gridDim.x >> 3;
  const int wg = (blockIdx.x & 7) * cpx + (blockIdx.x >> 3);
  const int bx = wg % nbx, by = wg / nbx;
  const int tid = threadIdx.x;
  const int lane = tid & 63, wave = tid >> 6;
  const int lr = lane & 15, lg = lane >> 4;
  const int wm = wave >> 2, wn = wave & 3;
  const int m0 = by * 256, n0 = bx * 256;

  const bf16* Ag = Abase + (size_t)m0 * Kstr;
  const bf16* Bg = Bbase + (size_t)n0 * Kstr;
  bf16* LA0 = lds[0]; bf16* LB0 = lds[1];
  bf16* LA1 = lds[2]; bf16* LB1 = lds[3];

  f32x4 acc[8][4] = {};
  const int T = Kloop >> 6;

  stage_tile(Ag, Bg, Kstr, 0, LA0, LB0, tid);
  stage_tile(Ag, Bg, Kstr, 1, LA1, LB1, tid);
  VMCNT8(); BAR(); SCH0();

  for (int t = 0; t + 3 < T; t += 2) {
    compute_tile(LA0, LB0, wm, wn, lr, lg, acc);
    BAR(); SCH0();
    stage_tile(Ag, Bg, Kstr, t + 2, LA0, LB0, tid);
    VMCNT8(); BAR(); SCH0();
    compute_tile(LA1, LB1, wm, wn, lr, lg, acc);
    BAR(); SCH0();
    stage_tile(Ag, Bg, Kstr, t + 3, LA1, LB1, tid);
    VMCNT8(); BAR(); SCH0();
  }
  compute_tile(LA0, LB0, wm, wn, lr, lg, acc);   // tile T-2
  VMCNT0(); BAR(); SCH0();                       // tile T-1 landed
  compute_tile(LA1, LB1, wm, wn, lr, lg, acc);   // tile T-1

#pragma unroll
  for (int m = 0; m < 8; ++m)
#pragma unroll
    for (int n = 0; n < 4; ++n)
#pragma unroll
      for (int r = 0; r < 4; ++r) {
        const int row = m0 + wm * 128 + m * 16 + lg * 4 + r;
        const int col = n0 + wn * 64 + n * 16 + lr;
        float val = acc[m][n][r];
        if (EPI == 0) {
          const int which = col >> 10, hc = col & 1023;
          const float* bs = (which == 0) ? bias0 : (which == 1) ? bias1 : bias2;
          bf16* dst = (which == 0) ? q_out : (which == 1) ? k_out : v_out;
          val += bs[hc];
          const int b = row >> 11, s = row & 2047;
          const int h = hc >> 6, hd = hc & 63;
          dst[(((size_t)b * 16 + h) * 2048 + s) * 64 + hd] = (bf16)val;
        } else if (EPI == 1) {
          pout[(size_t)bz * 4096 * 1024 + (size_t)row * 1024 + col] = val;
        } else {
          val += bias0[col];
          outb[(size_t)row * Nn + col] = (bf16)(val > 0.f ? val : 0.f);
        }
      }
}

// ========== 128x128-tile 4-wave GEMM, counted-vmcnt (O-proj K=1024) =========
static __device__ __forceinline__ void stage128(const bf16* __restrict__ Ag,
    const bf16* __restrict__ Bg, int Kstr, int kt, bf16* lA, bf16* lB, int tid) {
  const char* dA = (const char*)lA + ((tid >> 6) << 10);
  const char* dB = (const char*)lB + ((tid >> 6) << 10);
#pragma unroll
  for (int s = 0; s < 4; ++s) {
    const int L = s * 4096 + tid * 16;
    const int off = L ^ (((L >> 7) & 7) << 4);
    load_lds16(Ag + (size_t)(off >> 7) * Kstr + kt * 64 + ((off & 127) >> 1),
               (void*)(dA + s * 4096));
  }
#pragma unroll
  for (int s = 0; s < 4; ++s) {
    const int L = s * 4096 + tid * 16;
    const int off = L ^ (((L >> 7) & 7) << 4);
    load_lds16(Bg + (size_t)(off >> 7) * Kstr + kt * 64 + ((off & 127) >> 1),
               (void*)(dB + s * 4096));
  }
}

static __device__ __forceinline__ void compute128(const bf16* lA, const bf16* lB,
    int wm, int wn, int lr, int lg, f32x4 (&acc)[4][4]) {
  bf16x8 bfr[4][2];
#pragma unroll
  for (int n = 0; n < 4; ++n)
#pragma unroll
    for (int kk = 0; kk < 2; ++kk)
      bfr[n][kk] = ldsfrag(lB, wn * 64 + n * 16 + lr, kk * 64 + lg * 16);
#pragma unroll
  for (int m = 0; m < 4; ++m) {
    const bf16x8 a0 = ldsfrag(lA, wm * 64 + m * 16 + lr, lg * 16);
    const bf16x8 a1 = ldsfrag(lA, wm * 64 + m * 16 + lr, 64 + lg * 16);
    __builtin_amdgcn_s_setprio(1);
#pragma unroll
    for (int n = 0; n < 4; ++n) {
      acc[m][n] = MFMA16(a0, bfr[n][0], acc[m][n]);
      acc[m][n] = MFMA16(a1, bfr[n][1], acc[m][n]);
    }
    __builtin_amdgcn_s_setprio(0);
  }
}

__global__ __launch_bounds__(256, 2) void gemm128p(
    const bf16* __restrict__ A, const bf16* __restrict__ Bt, int Kk,
    const float* __restrict__ bias, const bf16* __restrict__ resid,
    float* __restrict__ outf) {
  __shared__ __align__(16) bf16 lds[4][8192];    // A0,B0,A1,B1 (16KB each)
  const int cpx = gridDim.x >> 3;
  const int wg = (blockIdx.x & 7) * cpx + (blockIdx.x >> 3);
  const int bx = wg & 7, by = wg >> 3;           // nbx = 8 (N=1024)
  const int tid = threadIdx.x;
  const int lane = tid & 63, wave = tid >> 6;
  const int lr = lane & 15, lg = lane >> 4;
  const int wm = wave >> 1, wn = wave & 1;
  const int m0 = by * 128, n0 = bx * 128;

  const bf16* Ag = A + (size_t)m0 * Kk;
  const bf16* Bg = Bt + (size_t)n0 * Kk;
  bf16* LA0 = lds[0]; bf16* LB0 = lds[1];
  bf16* LA1 = lds[2]; bf16* LB1 = lds[3];

  f32x4 acc[4][4] = {};
  const int T = Kk >> 6;

  stage128(Ag, Bg, Kk, 0, LA0, LB0, tid);
  stage128(Ag, Bg, Kk, 1, LA1, LB1, tid);
  VMCNT8(); BAR(); SCH0();

  for (int t = 0; t + 3 < T; t += 2) {
    compute128(LA0, LB0, wm, wn, lr, lg, acc);
    BAR(); SCH0();
    stage128(Ag, Bg, Kk, t + 2, LA0, LB0, tid);
    VMCNT8(); BAR(); SCH0();
    compute128(LA1, LB1, wm, wn, lr, lg, acc);
    BAR(); SCH0();
    stage128(Ag, Bg, Kk, t + 3, LA1, LB1, tid);
    VMCNT8(); BAR(); SCH0();
  }
  compute128(LA0, LB0, wm, wn, lr, lg, acc);     // tile T-2
  VMCNT0(); BAR(); SCH0();                       // tile T-1 landed
  compute128(LA1, LB1, wm, wn, lr, lg, acc);     // tile T-1

#pragma unroll
  for (int m = 0; m < 4; ++m)
#pragma unroll
    for (int n = 0; n < 4; ++n)
#pragma unroll
      for (int r = 0; r < 4; ++r) {
        const int row = m0 + wm * 64 + m * 16 + lg * 4 + r;
        const int col = n0 + wn * 64 + n * 16 + lr;
        const float val = acc[m][n][r] + bias[col]
                        + (float)resid[(size_t)row * 1024 + col];
        outf[(size_t)row * 1024 + col] = val;
      }
}

// ------------------------- flash attention (per b,h) ------------------------
// 1D grid 512, XCD-swizzled. block: 512 = 8 waves; wave w owns q-rows
// [128*(wid&15) + 16w, +16). KVBLK=128: one barrier-pair per 128-key chunk,
// two 64-key halves with NO barrier between. Reg-staged K/V double buffer,
// slot-XOR swizzle, swapped QK^T, log2-domain softmax with defer-max.
// Chunk loop MUST be unrolled by 2 (rule #20, round-3 lesson).
__global__ __launch_bounds__(512) void attn_kernel(const bf16* __restrict__ q,
                                                   const bf16* __restrict__ k,
                                                   const bf16* __restrict__ vt,
                                                   bf16* __restrict__ ctxo) {
  __shared__ __align__(16) bf16 Kl[128][64];  // rows = key, 8 slots of 16B
  __shared__ __align__(16) bf16 Vt[64][128];  // rows = hd, 16 slots of 16B
  __shared__ __align__(16) bf16 Pl[8][16][64];
  const int wid = ((blockIdx.x & 7) << 6) + (blockIdx.x >> 3);
  const int bh = wid >> 4;
  const int q0 = (wid & 15) * 128;
  const int tid = threadIdx.x;
  const int lane = tid & 63, w = tid >> 6;
  const int lr = lane & 15, lg = lane >> 4;
  const int swz = lr & 7;

  const bf16* qp = q + ((size_t)bh * 2048 + q0 + w * 16) * 64;
  bf16x8 qf0 = *(const bf16x8*)&qp[lr * 64 + lg * 8];
  bf16x8 qf1 = *(const bf16x8*)&qp[lr * 64 + lg * 8 + 32];
  const float qs = 0.18033688011112042f;      // (1/8)*log2(e)
#pragma unroll
  for (int j = 0; j < 8; ++j) {
    qf0[j] = (bf16)((float)qf0[j] * qs);
    qf1[j] = (bf16)((float)qf1[j] * qs);
  }
  bf16x8 ones8;
#pragma unroll
  for (int j = 0; j < 8; ++j) ones8[j] = (bf16)1.0f;

  const bf16* kbase = k + (size_t)bh * 2048 * 64;
  const bf16* vtb = vt + (size_t)bh * 64 * 2048;

  const int skr = tid >> 3;
  const int skc = (tid & 7) * 8;
  const int skcs = skc ^ ((skr & 7) << 3);
  const int svr = tid >> 4;
  const int svslot = tid & 15;
  const int svs = (svslot ^ (svr & 7)) * 8;

  f32x4 acc[4] = {};
  f32x4 accl = {};
  float mq = -1e30f;

  bf16x8 kr[2][2], vr[2][2];
  kr[0][0] = *(const bf16x8*)&kbase[(size_t)skr * 64 + skc];
  kr[0][1] = *(const bf16x8*)&kbase[(size_t)(skr + 64) * 64 + skc];
  vr[0][0] = *(const bf16x8*)&vtb[(size_t)svr * 2048 + svslot * 8];
  vr[0][1] = *(const bf16x8*)&vtb[(size_t)(svr + 32) * 2048 + svslot * 8];

#pragma unroll 2
  for (int c = 0; c < 16; ++c) {
    const int pp = c & 1;
    *(bf16x8*)&Kl[skr][skcs]      = kr[pp][0];
    *(bf16x8*)&Kl[skr + 64][skcs] = kr[pp][1];
    *(bf16x8*)&Vt[svr][svs]       = vr[pp][0];
    *(bf16x8*)&Vt[svr + 32][svs]  = vr[pp][1];
    if (c + 1 < 16) {
      const int key0n = (c + 1) * 128;
      kr[pp ^ 1][0] = *(const bf16x8*)&kbase[(size_t)(key0n + skr) * 64 + skc];
      kr[pp ^ 1][1] = *(const bf16x8*)&kbase[(size_t)(key0n + skr + 64) * 64 + skc];
      vr[pp ^ 1][0] = *(const bf16x8*)&vtb[(size_t)svr * 2048 + key0n + svslot * 8];
      vr[pp ^ 1][1] = *(const bf16x8*)&vtb[(size_t)(svr + 32) * 2048 + key0n + svslot * 8];
    }
    __syncthreads();

#pragma unroll
    for (int hf = 0; hf < 2; ++hf) {
      f32x4 st[4];
      __builtin_amdgcn_s_setprio(1);
#pragma unroll
      for (int ks = 0; ks < 4; ++ks) {
        const bf16x8 kf0 = *(const bf16x8*)&Kl[hf * 64 + ks * 16 + lr][(lg ^ swz) << 3];
        const bf16x8 kf1 = *(const bf16x8*)&Kl[hf * 64 + ks * 16 + lr][((lg + 4) ^ swz) << 3];
        f32x4 sa = {};
        sa = MFMA16(kf0, qf0, sa);
        sa = MFMA16(kf1, qf1, sa);
        st[ks] = sa;
      }
      __builtin_amdgcn_s_setprio(0);

      float mx = st[0][0];
#pragma unroll
      for (int ks = 0; ks < 4; ++ks)
#pragma unroll
        for (int r = 0; r < 4; ++r) mx = fmaxf(mx, st[ks][r]);
      mx = fmaxf(mx, __shfl_xor(mx, 16));
      mx = fmaxf(mx, __shfl_xor(mx, 32));
      if (!__all(mx - mq <= 8.0f)) {               // defer-max (T13)
        const float resc = exp2f(mq - mx);
        mq = mx;
        float rq[4];
#pragma unroll
        for (int r = 0; r < 4; ++r) rq[r] = __shfl(resc, lg * 4 + r);
#pragma unroll
        for (int r = 0; r < 4; ++r) {
          accl[r] *= rq[r];
#pragma unroll
          for (int jn = 0; jn < 4; ++jn) acc[jn][r] *= rq[r];
        }
      }
#pragma unroll
      for (int ks = 0; ks < 4; ++ks) {             // P pack + vectorized store
        bf16x4 pk;
#pragma unroll
        for (int r = 0; r < 4; ++r) pk[r] = (bf16)exp2f(st[ks][r] - mq);
        const int col = (((ks * 2 + (lg >> 1)) ^ swz) << 3) + ((lg & 1) << 2);
        *(bf16x4*)&Pl[w][lr][col] = pk;
      }

      const bf16x8 pf0 = *(const bf16x8*)&Pl[w][lr][(lg ^ swz) << 3];
      const bf16x8 pf1 = *(const bf16x8*)&Pl[w][lr][((lg + 4) ^ swz) << 3];
      __builtin_amdgcn_s_setprio(1);
#pragma unroll
      for (int jn = 0; jn < 4; ++jn) {
        const bf16x8 vf0 = *(const bf16x8*)&Vt[jn * 16 + lr][hf * 64 + ((lg ^ swz) << 3)];
        const bf16x8 vf1 = *(const bf16x8*)&Vt[jn * 16 + lr][hf * 64 + (((lg + 4) ^ swz) << 3)];
        acc[jn] = MFMA16(pf0, vf0, acc[jn]);
        acc[jn] = MFMA16(pf1, vf1, acc[jn]);
      }
      accl = MFMA16(pf0, ones8, accl);
      accl = MFMA16(pf1, ones8, accl);
      __builtin_amdgcn_s_setprio(0);
    }
    __syncthreads();
  }

  const int bb = bh >> 4, hh = bh & 15;
#pragma unroll
  for (int r = 0; r < 4; ++r) {
    const float inv = 1.f / accl[r];
    const size_t rowg = (size_t)bb * 2048 + q0 + w * 16 + lg * 4 + r;
#pragma unroll
    for (int jn = 0; jn < 4; ++jn)
      ctxo[rowg * 1024 + hh * 64 + jn * 16 + lr] = (bf16)(acc[jn][r] * inv);
  }
}

// ---------- fused split-K reduce + bias + residual + LayerNorm --------------
template <int NP>
__global__ __launch_bounds__(256) void ln2_kernel(const float* __restrict__ p,
                                                  const bf16* __restrict__ resid,
                                                  const float* __restrict__ bias,
                                                  const float* __restrict__ g,
                                                  const float* __restrict__ be,
                                                  bf16* __restrict__ xo,
                                                  float* __restrict__ fout) {
  const int row = blockIdx.x, tid = threadIdx.x;
  const bf16x4 rv = *(const bf16x4*)&resid[(size_t)row * 1024 + tid * 4];
  const float4 bb = ((const float4*)bias)[tid];
  float4 v;
  v.x = bb.x + (float)rv[0];
  v.y = bb.y + (float)rv[1];
  v.z = bb.z + (float)rv[2];
  v.w = bb.w + (float)rv[3];
#pragma unroll
  for (int pl = 0; pl < NP; ++pl) {
    const float4 a = ((const float4*)(p + (size_t)pl * 4096 * 1024 + (size_t)row * 1024))[tid];
    v.x += a.x; v.y += a.y; v.z += a.z; v.w += a.w;
  }
  float s = v.x + v.y + v.z + v.w;
  float s2 = v.x * v.x + v.y * v.y + v.z * v.z + v.w * v.w;
#pragma unroll
  for (int o = 32; o > 0; o >>= 1) { s += __shfl_down(s, o); s2 += __shfl_down(s2, o); }
  __shared__ float red[8];
  if ((tid & 63) == 0) { red[tid >> 6] = s; red[4 + (tid >> 6)] = s2; }
  __syncthreads();
  s = red[0] + red[1] + red[2] + red[3];
  s2 = red[4] + red[5] + red[6] + red[7];
  const float mean = s * (1.f / 1024.f);
  const float var = s2 * (1.f / 1024.f) - mean * mean;
  const float rstd = rsqrtf(var + 1e-5f);
  const float4 gv = ((const float4*)g)[tid];
  const float4 bv = ((const float4*)be)[tid];
  float4 of;
  of.x = (v.x - mean) * rstd * gv.x + bv.x;
  of.y = (v.y - mean) * rstd * gv.y + bv.y;
  of.z = (v.z - mean) * rstd * gv.z + bv.z;
  of.w = (v.w - mean) * rstd * gv.w + bv.w;
  if (fout) {
    ((float4*)(fout + (size_t)row * 1024))[tid] = of;
  } else {
    bf16x4 o4;
    o4[0] = (bf16)of.x; o4[1] = (bf16)of.y; o4[2] = (bf16)of.z; o4[3] = (bf16)of.w;
    *(bf16x4*)&xo[(size_t)row * 1024 + tid * 4] = o4;
  }
}

// ------------------------------ LayerNorm (fp32 y) --------------------------
__global__ __launch_bounds__(256) void ln_kernel(const float* __restrict__ y,
                                                 const float* __restrict__ g,
                                                 const float* __restrict__ be,
                                                 bf16* __restrict__ xo) {
  const int row = blockIdx.x, tid = threadIdx.x;
  const float4 v = ((const float4*)(y + (size_t)row * 1024))[tid];
  float s = v.x + v.y + v.z + v.w;
  float s2 = v.x * v.x + v.y * v.y + v.z * v.z + v.w * v.w;
#pragma unroll
  for (int o = 32; o > 0; o >>= 1) { s += __shfl_down(s, o); s2 += __shfl_down(s2, o); }
  __shared__ float red[8];
  if ((tid & 63) == 0) { red[tid >> 6] = s; red[4 + (tid >> 6)] = s2; }
  __syncthreads();
  s = red[0] + red[1] + red[2] + red[3];
  s2 = red[4] + red[5] + red[6] + red[7];
  const float mean = s * (1.f / 1024.f);
  const float var = s2 * (1.f / 1024.f) - mean * mean;
  const float rstd = rsqrtf(var + 1e-5f);
  const float4 gv = ((const float4*)g)[tid];
  const float4 bv = ((const float4*)be)[tid];
  bf16x4 o4;
  o4[0] = (bf16)((v.x - mean) * rstd * gv.x + bv.x);
  o4[1] = (bf16)((v.y - mean) * rstd * gv.y + bv.y);
  o4[2] = (bf16)((v.z - mean) * rstd * gv.z + bv.z);
  o4[3] = (bf16)((v.w - mean) * rstd * gv.w + bv.w);
  *(bf16x4*)&xo[(size_t)row * 1024 + tid * 4] = o4;
}

// ----------------------------------------------------------------------------
extern "C" void kernel_launch(void* const* d_in, const int* in_sizes, int n_in,
                              void* d_out, int out_size, void* d_ws, size_t ws_size,
                              hipStream_t stream) {
  const int* tokens = (const int*)d_in[0];
  const float* emb = (const float*)d_in[2];
  const float* Wq = (const float*)d_in[3];
  const float* bq = (const float*)d_in[4];
  const float* Wk = (const float*)d_in[5];
  const float* bk = (const float*)d_in[6];
  const float* Wv = (const float*)d_in[7];
  const float* bv = (const float*)d_in[8];
  const float* Wo = (const float*)d_in[9];
  const float* bo = (const float*)d_in[10];
  const float* W1 = (const float*)d_in[11];
  const float* b1 = (const float*)d_in[12];
  const float* W2 = (const float*)d_in[13];
  const float* b2 = (const float*)d_in[14];
  const float* g1 = (const float*)d_in[15];
  const float* be1 = (const float*)d_in[16];
  const float* g2 = (const float*)d_in[17];
  const float* be2 = (const float*)d_in[18];

  char* p = (char*)d_ws;
  auto carve = [&](size_t bytes) { char* r = p; p += (bytes + 255) & ~(size_t)255; return r; };
  bf16* wt_qkv = (bf16*)carve((size_t)3072 * 1024 * 2);
  bf16* wt_o   = (bf16*)carve((size_t)1024 * 1024 * 2);
  bf16* wt_1   = (bf16*)carve((size_t)4096 * 1024 * 2);
  bf16* wt_2   = (bf16*)carve((size_t)1024 * 4096 * 2);
  bf16* xb     = (bf16*)carve((size_t)4096 * 1024 * 2);
  bf16* qb     = (bf16*)carve((size_t)4096 * 1024 * 2);
  bf16* kb     = (bf16*)carve((size_t)4096 * 1024 * 2);
  bf16* vb     = (bf16*)carve((size_t)4096 * 1024 * 2);
  bf16* vtb    = (bf16*)carve((size_t)4096 * 1024 * 2);
  bf16* ctxb   = (bf16*)carve((size_t)4096 * 1024 * 2);
  float* yb    = (float*)carve((size_t)4096 * 1024 * 4);
  float* pb    = (float*)carve((size_t)4 * 4096 * 1024 * 4);   // split-K partials
  bf16* hb     = (bf16*)carve((size_t)4096 * 4096 * 2);

  embed_kernel<<<4096, 256, 0, stream>>>(tokens, emb, xb);

  for (int l = 0; l < 6; ++l) {
    // 64x64 tiles: jobs sized (K/64)*(N/64)
    TArgs ta;
    ta.j[0] = { Wq + (size_t)l * 1024 * 1024, wt_qkv,                  1024, 1024, 0 };
    ta.j[1] = { Wk + (size_t)l * 1024 * 1024, wt_qkv + 1024 * 1024,    1024, 1024, 256 };
    ta.j[2] = { Wv + (size_t)l * 1024 * 1024, wt_qkv + 2 * 1024 * 1024,1024, 1024, 512 };
    ta.j[3] = { Wo + (size_t)l * 1024 * 1024, wt_o,                    1024, 1024, 768 };
    ta.j[4] = { W1 + (size_t)l * 1024 * 4096, wt_1,                    1024, 4096, 1024 };
    ta.j[5] = { W2 + (size_t)l * 4096 * 1024, wt_2,                    4096, 1024, 2048 };
    wtrans_kernel<<<3072, 256, 0, stream>>>(ta);

    // QKV: 256^2 tile, grid 16x12 = 192
    gemm256<0><<<192, 512, 0, stream>>>(xb, wt_qkv, 1024, 1024, 3072, 12,
        bq + (size_t)l * 1024, bk + (size_t)l * 1024, bv + (size_t)l * 1024,
        nullptr, nullptr, qb, kb, vb);

    vtrans_kernel<<<dim3(32, 32), 256, 0, stream>>>(vb, vtb);

    attn_kernel<<<512, 512, 0, stream>>>(qb, kb, vtb, ctxb);

    // O-proj: 128^2 pipeline, single-pass K=1024, grid 256
    gemm128p<<<256, 256, 0, stream>>>(ctxb, wt_o, 1024,
        bo + (size_t)l * 1024, xb, yb);
    ln_kernel<<<4096, 256, 0, stream>>>(yb, g1 + (size_t)l * 1024,
        be1 + (size_t)l * 1024, xb);

    // FFN1: 256^2 tile, grid 16x16 = 256
    gemm256<2><<<256, 512, 0, stream>>>(xb, wt_1, 1024, 1024, 4096, 16,
        b1 + (size_t)l * 4096, nullptr, nullptr, hb,
        nullptr, nullptr, nullptr, nullptr);

    // FFN2: 256^2 tile split-K=4 (K-slice 1024), grid (64,4) = 256 blocks
    gemm256<1><<<dim3(64, 4), 512, 0, stream>>>(hb, wt_2, 4096, 1024, 1024, 4,
        nullptr, nullptr, nullptr, nullptr, pb,
        nullptr, nullptr, nullptr);
    ln2_kernel<4><<<4096, 256, 0, stream>>>(pb, xb, b2 + (size_t)l * 1024,
        g2 + (size_t)l * 1024, be2 + (size_t)l * 1024, xb,
        (l == 5) ? (float*)d_out : nullptr);
  }
}

// Round 14
// 1368.649 us; speedup vs baseline: 1.1288x; 1.0089x over previous
//
#include <hip/hip_runtime.h>
#include <hip/hip_bf16.h>
#include <cstdint>
#include <cstddef>

// ---------------------------------------------------------------------------
// Transformer encoder, 6 layers: B=2,S=2048,D=1024,H=16,HD=64,F=4096.
// QKV: 256x192-tile (grid 256 = 1/CU). FFN1: 256^2. Both: 8-wave counted-vmcnt
// double buffer (T2+T3+T4+T5). FFN2: gemm256 split-K=4 + fused LN.
// O-proj: 128^2 pipeline. Flash attention: 8-wave blocks (Q=128), KVBLK=128,
// XCD-swizzled grid, swapped QK^T, T2 swizzle, reg-staged K/V double buffer.
// ---------------------------------------------------------------------------

typedef __bf16 bf16;
typedef __bf16 bf16x2 __attribute__((ext_vector_type(2)));
typedef __bf16 bf16x4 __attribute__((ext_vector_type(4)));
typedef __bf16 bf16x8 __attribute__((ext_vector_type(8)));
typedef float  f32x4  __attribute__((ext_vector_type(4)));

#define MFMA16(a, b, c) __builtin_amdgcn_mfma_f32_16x16x32_bf16((a), (b), (c), 0, 0, 0)

static __device__ __forceinline__ void load_lds16(const void* g, void* l) {
  __builtin_amdgcn_global_load_lds((const __attribute__((address_space(1))) void*)g,
                                   (__attribute__((address_space(3))) void*)l, 16, 0, 0);
}

#define BAR()   __builtin_amdgcn_s_barrier()
#define SCH0()  __builtin_amdgcn_sched_barrier(0)
#define VMCNT8() asm volatile("s_waitcnt vmcnt(8)" ::: "memory")
#define VMCNT7() asm volatile("s_waitcnt vmcnt(7)" ::: "memory")
#define VMCNT0() asm volatile("s_waitcnt vmcnt(0)" ::: "memory")

// ---------------- embedding + positional encoding -> bf16 x ----------------
__global__ __launch_bounds__(256) void embed_kernel(const int* __restrict__ tok,
                                                    const float* __restrict__ emb,
                                                    bf16* __restrict__ xo) {
  const int row = blockIdx.x;          // b*2048 + s
  const int s = row & 2047;
  const int t = tok[row];
  const int d0 = threadIdx.x * 4;
  const float4 e = *(const float4*)&emb[(size_t)t * 1024 + d0];
  const float* ef = (const float*)&e;
  bf16x4 o4;
#pragma unroll
  for (int j = 0; j < 4; ++j) {
    const int d = d0 + j;
    const float div = __expf(-(float)(d & ~1) * 0.00899447301950864f); // ln(1e4)/1024
    const float arg = (float)s * div;
    const float pe = (d & 1) ? cosf(arg) : sinf(arg);
    o4[j] = (bf16)(ef[j] + pe);
  }
  *(bf16x4*)&xo[(size_t)row * 1024 + d0] = o4;
}

// ------------- weight transpose: fp32 [K][N] -> bf16 [N][K], batched --------
struct TJob { const float* src; bf16* dst; int K; int N; int t0; };
struct TArgs { TJob j[6]; };

__global__ __launch_bounds__(256) void wtrans_kernel(TArgs a) {
  __shared__ float t[64][65];
  const int blk = blockIdx.x;
  const float* src = a.j[0].src; bf16* dst = a.j[0].dst;
  int K = a.j[0].K, N = a.j[0].N, t0 = a.j[0].t0;
#pragma unroll
  for (int q = 1; q < 6; ++q)
    if (blk >= a.j[q].t0) { src = a.j[q].src; dst = a.j[q].dst; K = a.j[q].K; N = a.j[q].N; t0 = a.j[q].t0; }
  const int tj = blk - t0;
  const int tilesK = K >> 6;
  const int tk = (tj % tilesK) << 6;
  const int tn = (tj / tilesK) << 6;
  const int tid = threadIdx.x;
  const int rr = tid >> 4;            // 0..15
  const int c4 = (tid & 15) * 4;
#pragma unroll
  for (int i = 0; i < 4; ++i) {
    const float4 v = *(const float4*)&src[(size_t)(tk + rr + 16 * i) * N + tn + c4];
    t[rr + 16 * i][c4 + 0] = v.x;
    t[rr + 16 * i][c4 + 1] = v.y;
    t[rr + 16 * i][c4 + 2] = v.z;
    t[rr + 16 * i][c4 + 3] = v.w;
  }
  __syncthreads();
  const int k0 = (tid & 15) * 4;
#pragma unroll
  for (int i = 0; i < 4; ++i) {
    const int n = rr + 16 * i;
    bf16x4 o;
#pragma unroll
    for (int j = 0; j < 4; ++j) o[j] = (bf16)t[k0 + j][n];
    *(bf16x4*)&dst[(size_t)(tn + n) * K + tk + k0] = o;
  }
}

// -------- V transpose per layer: [bh][s][64] bf16 -> [bh][64][s] bf16 -------
__global__ __launch_bounds__(256) void vtrans_kernel(const bf16* __restrict__ v,
                                                     bf16* __restrict__ vt) {
  __shared__ bf16 t[64][72];
  const int bh = blockIdx.y;
  const int s0 = blockIdx.x * 64;
  const int tid = threadIdx.x;
#pragma unroll
  for (int it = 0; it < 2; ++it) {
    const int idx = tid + it * 256;
    const int sr = idx >> 3, h8 = (idx & 7) * 8;
    *(bf16x8*)&t[sr][h8] = *(const bf16x8*)&v[((size_t)bh * 2048 + s0 + sr) * 64 + h8];
  }
  __syncthreads();
#pragma unroll
  for (int it = 0; it < 2; ++it) {
    const int idx = tid + it * 256;
    const int hd = idx >> 3, s8 = (idx & 7) * 8;
    bf16x8 o;
#pragma unroll
    for (int j = 0; j < 8; ++j) o[j] = t[s8 + j][hd];
    *(bf16x8*)&vt[((size_t)bh * 64 + hd) * 2048 + s0 + s8] = o;
  }
}

// ======================= shared GEMM building blocks ========================
static __device__ __forceinline__ bf16x8 ldsfrag(const bf16* base, int row, int colb) {
  int off = row * 128 + colb;
  off ^= ((off >> 7) & 7) << 4;
  return *(const bf16x8*)((const char*)base + off);
}

// ====== 256xBN-tile 8-wave GEMM, counted-vmcnt (BN = 64*BNF, BNF=3|4) ======
template <int BNF>
static __device__ __forceinline__ void stage_tileT(const bf16* __restrict__ Ag,
    const bf16* __restrict__ Bg, int Kstr, int kt, bf16* lA, bf16* lB, int tid) {
  const char* wbaseA = (const char*)lA + ((tid >> 6) << 10);
  const char* wbaseB = (const char*)lB + ((tid >> 6) << 10);
#pragma unroll
  for (int s = 0; s < 4; ++s) {
    const int L = s * 8192 + tid * 16;
    const int off = L ^ (((L >> 7) & 7) << 4);
    load_lds16(Ag + (size_t)(off >> 7) * Kstr + kt * 64 + ((off & 127) >> 1),
               (void*)(wbaseA + s * 8192));
  }
#pragma unroll
  for (int s = 0; s < BNF; ++s) {
    const int L = s * 8192 + tid * 16;
    const int off = L ^ (((L >> 7) & 7) << 4);
    load_lds16(Bg + (size_t)(off >> 7) * Kstr + kt * 64 + ((off & 127) >> 1),
               (void*)(wbaseB + s * 8192));
  }
}

template <int BNF>
static __device__ __forceinline__ void compute_tileT(const bf16* lA, const bf16* lB,
    int wm, int wn, int lr, int lg, f32x4 (&acc)[8][BNF]) {
  bf16x8 bfr[BNF][2];
#pragma unroll
  for (int n = 0; n < BNF; ++n)
#pragma unroll
    for (int kk = 0; kk < 2; ++kk)
      bfr[n][kk] = ldsfrag(lB, wn * (16 * BNF) + n * 16 + lr, kk * 64 + lg * 16);
#pragma unroll
  for (int m = 0; m < 8; ++m) {
    const bf16x8 a0 = ldsfrag(lA, wm * 128 + m * 16 + lr, lg * 16);
    const bf16x8 a1 = ldsfrag(lA, wm * 128 + m * 16 + lr, 64 + lg * 16);
    __builtin_amdgcn_s_setprio(1);
#pragma unroll
    for (int n = 0; n < BNF; ++n) {
      acc[m][n] = MFMA16(a0, bfr[n][0], acc[m][n]);
      acc[m][n] = MFMA16(a1, bfr[n][1], acc[m][n]);
    }
    __builtin_amdgcn_s_setprio(0);
  }
}

template <int BNF>
static __device__ __forceinline__ void waitK() {
  if constexpr (BNF == 3) { VMCNT7(); } else { VMCNT8(); }
}

template <int EPI, int BNF>  // EPI 0: qkv scatter, 1: fp32 partial, 2: bias+relu
__global__ __launch_bounds__(512, 2) void gemm256(
    const bf16* __restrict__ A, const bf16* __restrict__ Bt,
    int Kstr, int Kloop, int Nn, int nbx,
    const float* __restrict__ bias0, const float* __restrict__ bias1,
    const float* __restrict__ bias2, bf16* __restrict__ outb,
    float* __restrict__ pout,
    bf16* __restrict__ q_out, bf16* __restrict__ k_out, bf16* __restrict__ v_out) {
  __shared__ __align__(16) bf16 ldsA[2][16384];       // 32KB each
  __shared__ __align__(16) bf16 ldsB[2][BNF * 4096];  // BNF*8KB each
  const int bz = blockIdx.y;
  const bf16* Abase = A + (size_t)bz * Kloop;
  const bf16* Bbase = Bt + (size_t)bz * Kloop;
  const int cpx = gridDim.x >> 3;
  const int wg = (blockIdx.x & 7) * cpx + (blockIdx.x >> 3);
  const int bx = wg % nbx, by = wg / nbx;
  const int tid = threadIdx.x;
  const int lane = tid & 63, wave = tid >> 6;
  const int lr = lane & 15, lg = lane >> 4;
  const int wm = wave >> 2, wn = wave & 3;
  const int m0 = by * 256, n0 = bx * (64 * BNF);

  const bf16* Ag = Abase + (size_t)m0 * Kstr;
  const bf16* Bg = Bbase + (size_t)n0 * Kstr;

  f32x4 acc[8][BNF] = {};
  const int T = Kloop >> 6;

  stage_tileT<BNF>(Ag, Bg, Kstr, 0, ldsA[0], ldsB[0], tid);
  stage_tileT<BNF>(Ag, Bg, Kstr, 1, ldsA[1], ldsB[1], tid);
  waitK<BNF>(); BAR(); SCH0();

  for (int t = 0; t + 3 < T; t += 2) {
    compute_tileT<BNF>(ldsA[0], ldsB[0], wm, wn, lr, lg, acc);
    BAR(); SCH0();
    stage_tileT<BNF>(Ag, Bg, Kstr, t + 2, ldsA[0], ldsB[0], tid);
    waitK<BNF>(); BAR(); SCH0();
    compute_tileT<BNF>(ldsA[1], ldsB[1], wm, wn, lr, lg, acc);
    BAR(); SCH0();
    stage_tileT<BNF>(Ag, Bg, Kstr, t + 3, ldsA[1], ldsB[1], tid);
    waitK<BNF>(); BAR(); SCH0();
  }
  compute_tileT<BNF>(ldsA[0], ldsB[0], wm, wn, lr, lg, acc);  // tile T-2
  VMCNT0(); BAR(); SCH0();                                    // tile T-1 landed
  compute_tileT<BNF>(ldsA[1], ldsB[1], wm, wn, lr, lg, acc);  // tile T-1

#pragma unroll
  for (int m = 0; m < 8; ++m)
#pragma unroll
    for (int n = 0; n < BNF; ++n)
#pragma unroll
      for (int r = 0; r < 4; ++r) {
        const int row = m0 + wm * 128 + m * 16 + lg * 4 + r;
        const int col = n0 + wn * (16 * BNF) + n * 16 + lr;
        float val = acc[m][n][r];
        if (EPI == 0) {
          const int which = col >> 10, hc = col & 1023;
          const float* bs = (which == 0) ? bias0 : (which == 1) ? bias1 : bias2;
          bf16* dst = (which == 0) ? q_out : (which == 1) ? k_out : v_out;
          val += bs[hc];
          const int b = row >> 11, s = row & 2047;
          const int h = hc >> 6, hd = hc & 63;
          dst[(((size_t)b * 16 + h) * 2048 + s) * 64 + hd] = (bf16)val;
        } else if (EPI == 1) {
          pout[(size_t)bz * 4096 * 1024 + (size_t)row * 1024 + col] = val;
        } else {
          val += bias0[col];
          outb[(size_t)row * Nn + col] = (bf16)(val > 0.f ? val : 0.f);
        }
      }
}

// ========== 128x128-tile 4-wave GEMM, counted-vmcnt (O-proj K=1024) =========
static __device__ __forceinline__ void stage128(const bf16* __restrict__ Ag,
    const bf16* __restrict__ Bg, int Kstr, int kt, bf16* lA, bf16* lB, int tid) {
  const char* dA = (const char*)lA + ((tid >> 6) << 10);
  const char* dB = (const char*)lB + ((tid >> 6) << 10);
#pragma unroll
  for (int s = 0; s < 4; ++s) {
    const int L = s * 4096 + tid * 16;
    const int off = L ^ (((L >> 7) & 7) << 4);
    load_lds16(Ag + (size_t)(off >> 7) * Kstr + kt * 64 + ((off & 127) >> 1),
               (void*)(dA + s * 4096));
  }
#pragma unroll
  for (int s = 0; s < 4; ++s) {
    const int L = s * 4096 + tid * 16;
    const int off = L ^ (((L >> 7) & 7) << 4);
    load_lds16(Bg + (size_t)(off >> 7) * Kstr + kt * 64 + ((off & 127) >> 1),
               (void*)(dB + s * 4096));
  }
}

static __device__ __forceinline__ void compute128(const bf16* lA, const bf16* lB,
    int wm, int wn, int lr, int lg, f32x4 (&acc)[4][4]) {
  bf16x8 bfr[4][2];
#pragma unroll
  for (int n = 0; n < 4; ++n)
#pragma unroll
    for (int kk = 0; kk < 2; ++kk)
      bfr[n][kk] = ldsfrag(lB, wn * 64 + n * 16 + lr, kk * 64 + lg * 16);
#pragma unroll
  for (int m = 0; m < 4; ++m) {
    const bf16x8 a0 = ldsfrag(lA, wm * 64 + m * 16 + lr, lg * 16);
    const bf16x8 a1 = ldsfrag(lA, wm * 64 + m * 16 + lr, 64 + lg * 16);
    __builtin_amdgcn_s_setprio(1);
#pragma unroll
    for (int n = 0; n < 4; ++n) {
      acc[m][n] = MFMA16(a0, bfr[n][0], acc[m][n]);
      acc[m][n] = MFMA16(a1, bfr[n][1], acc[m][n]);
    }
    __builtin_amdgcn_s_setprio(0);
  }
}

__global__ __launch_bounds__(256, 2) void gemm128p(
    const bf16* __restrict__ A, const bf16* __restrict__ Bt, int Kk,
    const float* __restrict__ bias, const bf16* __restrict__ resid,
    float* __restrict__ outf) {
  __shared__ __align__(16) bf16 lds[4][8192];    // A0,B0,A1,B1 (16KB each)
  const int cpx = gridDim.x >> 3;
  const int wg = (blockIdx.x & 7) * cpx + (blockIdx.x >> 3);
  const int bx = wg & 7, by = wg >> 3;           // nbx = 8 (N=1024)
  const int tid = threadIdx.x;
  const int lane = tid & 63, wave = tid >> 6;
  const int lr = lane & 15, lg = lane >> 4;
  const int wm = wave >> 1, wn = wave & 1;
  const int m0 = by * 128, n0 = bx * 128;

  const bf16* Ag = A + (size_t)m0 * Kk;
  const bf16* Bg = Bt + (size_t)n0 * Kk;
  bf16* LA0 = lds[0]; bf16* LB0 = lds[1];
  bf16* LA1 = lds[2]; bf16* LB1 = lds[3];

  f32x4 acc[4][4] = {};
  const int T = Kk >> 6;

  stage128(Ag, Bg, Kk, 0, LA0, LB0, tid);
  stage128(Ag, Bg, Kk, 1, LA1, LB1, tid);
  VMCNT8(); BAR(); SCH0();

  for (int t = 0; t + 3 < T; t += 2) {
    compute128(LA0, LB0, wm, wn, lr, lg, acc);
    BAR(); SCH0();
    stage128(Ag, Bg, Kk, t + 2, LA0, LB0, tid);
    VMCNT8(); BAR(); SCH0();
    compute128(LA1, LB1, wm, wn, lr, lg, acc);
    BAR(); SCH0();
    stage128(Ag, Bg, Kk, t + 3, LA1, LB1, tid);
    VMCNT8(); BAR(); SCH0();
  }
  compute128(LA0, LB0, wm, wn, lr, lg, acc);     // tile T-2
  VMCNT0(); BAR(); SCH0();                       // tile T-1 landed
  compute128(LA1, LB1, wm, wn, lr, lg, acc);     // tile T-1

#pragma unroll
  for (int m = 0; m < 4; ++m)
#pragma unroll
    for (int n = 0; n < 4; ++n)
#pragma unroll
      for (int r = 0; r < 4; ++r) {
        const int row = m0 + wm * 64 + m * 16 + lg * 4 + r;
        const int col = n0 + wn * 64 + n * 16 + lr;
        const float val = acc[m][n][r] + bias[col]
                        + (float)resid[(size_t)row * 1024 + col];
        outf[(size_t)row * 1024 + col] = val;
      }
}

// ------------------------- flash attention (per b,h) ------------------------
// 1D grid 512, XCD-swizzled. block: 512 = 8 waves; wave w owns q-rows
// [128*(wid&15) + 16w, +16). KVBLK=128: one barrier-pair per 128-key chunk,
// two 64-key halves with NO barrier between. Reg-staged K/V double buffer,
// slot-XOR swizzle, swapped QK^T, log2-domain softmax with defer-max.
// Chunk loop MUST be unrolled by 2 (rule #20, round-3 lesson).
__global__ __launch_bounds__(512) void attn_kernel(const bf16* __restrict__ q,
                                                   const bf16* __restrict__ k,
                                                   const bf16* __restrict__ vt,
                                                   bf16* __restrict__ ctxo) {
  __shared__ __align__(16) bf16 Kl[128][64];  // rows = key, 8 slots of 16B
  __shared__ __align__(16) bf16 Vt[64][128];  // rows = hd, 16 slots of 16B
  __shared__ __align__(16) bf16 Pl[8][16][64];
  const int wid = ((blockIdx.x & 7) << 6) + (blockIdx.x >> 3);
  const int bh = wid >> 4;
  const int q0 = (wid & 15) * 128;
  const int tid = threadIdx.x;
  const int lane = tid & 63, w = tid >> 6;
  const int lr = lane & 15, lg = lane >> 4;
  const int swz = lr & 7;

  const bf16* qp = q + ((size_t)bh * 2048 + q0 + w * 16) * 64;
  bf16x8 qf0 = *(const bf16x8*)&qp[lr * 64 + lg * 8];
  bf16x8 qf1 = *(const bf16x8*)&qp[lr * 64 + lg * 8 + 32];
  const float qs = 0.18033688011112042f;      // (1/8)*log2(e)
#pragma unroll
  for (int j = 0; j < 8; ++j) {
    qf0[j] = (bf16)((float)qf0[j] * qs);
    qf1[j] = (bf16)((float)qf1[j] * qs);
  }
  bf16x8 ones8;
#pragma unroll
  for (int j = 0; j < 8; ++j) ones8[j] = (bf16)1.0f;

  const bf16* kbase = k + (size_t)bh * 2048 * 64;
  const bf16* vtb = vt + (size_t)bh * 64 * 2048;

  const int skr = tid >> 3;
  const int skc = (tid & 7) * 8;
  const int skcs = skc ^ ((skr & 7) << 3);
  const int svr = tid >> 4;
  const int svslot = tid & 15;
  const int svs = (svslot ^ (svr & 7)) * 8;

  f32x4 acc[4] = {};
  f32x4 accl = {};
  float mq = -1e30f;

  bf16x8 kr[2][2], vr[2][2];
  kr[0][0] = *(const bf16x8*)&kbase[(size_t)skr * 64 + skc];
  kr[0][1] = *(const bf16x8*)&kbase[(size_t)(skr + 64) * 64 + skc];
  vr[0][0] = *(const bf16x8*)&vtb[(size_t)svr * 2048 + svslot * 8];
  vr[0][1] = *(const bf16x8*)&vtb[(size_t)(svr + 32) * 2048 + svslot * 8];

#pragma unroll 2
  for (int c = 0; c < 16; ++c) {
    const int pp = c & 1;
    *(bf16x8*)&Kl[skr][skcs]      = kr[pp][0];
    *(bf16x8*)&Kl[skr + 64][skcs] = kr[pp][1];
    *(bf16x8*)&Vt[svr][svs]       = vr[pp][0];
    *(bf16x8*)&Vt[svr + 32][svs]  = vr[pp][1];
    if (c + 1 < 16) {
      const int key0n = (c + 1) * 128;
      kr[pp ^ 1][0] = *(const bf16x8*)&kbase[(size_t)(key0n + skr) * 64 + skc];
      kr[pp ^ 1][1] = *(const bf16x8*)&kbase[(size_t)(key0n + skr + 64) * 64 + skc];
      vr[pp ^ 1][0] = *(const bf16x8*)&vtb[(size_t)svr * 2048 + key0n + svslot * 8];
      vr[pp ^ 1][1] = *(const bf16x8*)&vtb[(size_t)(svr + 32) * 2048 + key0n + svslot * 8];
    }
    __syncthreads();

#pragma unroll
    for (int hf = 0; hf < 2; ++hf) {
      f32x4 st[4];
      __builtin_amdgcn_s_setprio(1);
#pragma unroll
      for (int ks = 0; ks < 4; ++ks) {
        const bf16x8 kf0 = *(const bf16x8*)&Kl[hf * 64 + ks * 16 + lr][(lg ^ swz) << 3];
        const bf16x8 kf1 = *(const bf16x8*)&Kl[hf * 64 + ks * 16 + lr][((lg + 4) ^ swz) << 3];
        f32x4 sa = {};
        sa = MFMA16(kf0, qf0, sa);
        sa = MFMA16(kf1, qf1, sa);
        st[ks] = sa;
      }
      __builtin_amdgcn_s_setprio(0);

      float mx = st[0][0];
#pragma unroll
      for (int ks = 0; ks < 4; ++ks)
#pragma unroll
        for (int r = 0; r < 4; ++r) mx = fmaxf(mx, st[ks][r]);
      mx = fmaxf(mx, __shfl_xor(mx, 16));
      mx = fmaxf(mx, __shfl_xor(mx, 32));
      if (!__all(mx - mq <= 8.0f)) {               // defer-max (T13)
        const float resc = exp2f(mq - mx);
        mq = mx;
        float rq[4];
#pragma unroll
        for (int r = 0; r < 4; ++r) rq[r] = __shfl(resc, lg * 4 + r);
#pragma unroll
        for (int r = 0; r < 4; ++r) {
          accl[r] *= rq[r];
#pragma unroll
          for (int jn = 0; jn < 4; ++jn) acc[jn][r] *= rq[r];
        }
      }
#pragma unroll
      for (int ks = 0; ks < 4; ++ks) {             // P pack + vectorized store
        bf16x4 pk;
#pragma unroll
        for (int r = 0; r < 4; ++r) pk[r] = (bf16)exp2f(st[ks][r] - mq);
        const int col = (((ks * 2 + (lg >> 1)) ^ swz) << 3) + ((lg & 1) << 2);
        *(bf16x4*)&Pl[w][lr][col] = pk;
      }

      const bf16x8 pf0 = *(const bf16x8*)&Pl[w][lr][(lg ^ swz) << 3];
      const bf16x8 pf1 = *(const bf16x8*)&Pl[w][lr][((lg + 4) ^ swz) << 3];
      __builtin_amdgcn_s_setprio(1);
#pragma unroll
      for (int jn = 0; jn < 4; ++jn) {
        const bf16x8 vf0 = *(const bf16x8*)&Vt[jn * 16 + lr][hf * 64 + ((lg ^ swz) << 3)];
        const bf16x8 vf1 = *(const bf16x8*)&Vt[jn * 16 + lr][hf * 64 + (((lg + 4) ^ swz) << 3)];
        acc[jn] = MFMA16(pf0, vf0, acc[jn]);
        acc[jn] = MFMA16(pf1, vf1, acc[jn]);
      }
      accl = MFMA16(pf0, ones8, accl);
      accl = MFMA16(pf1, ones8, accl);
      __builtin_amdgcn_s_setprio(0);
    }
    __syncthreads();
  }

  const int bb = bh >> 4, hh = bh & 15;
#pragma unroll
  for (int r = 0; r < 4; ++r) {
    const float inv = 1.f / accl[r];
    const size_t rowg = (size_t)bb * 2048 + q0 + w * 16 + lg * 4 + r;
#pragma unroll
    for (int jn = 0; jn < 4; ++jn)
      ctxo[rowg * 1024 + hh * 64 + jn * 16 + lr] = (bf16)(acc[jn][r] * inv);
  }
}

// ---------- fused split-K reduce + bias + residual + LayerNorm --------------
template <int NP>
__global__ __launch_bounds__(256) void ln2_kernel(const float* __restrict__ p,
                                                  const bf16* __restrict__ resid,
                                                  const float* __restrict__ bias,
                                                  const float* __restrict__ g,
                                                  const float* __restrict__ be,
                                                  bf16* __restrict__ xo,
                                                  float* __restrict__ fout) {
  const int row = blockIdx.x, tid = threadIdx.x;
  const bf16x4 rv = *(const bf16x4*)&resid[(size_t)row * 1024 + tid * 4];
  const float4 bb = ((const float4*)bias)[tid];
  float4 v;
  v.x = bb.x + (float)rv[0];
  v.y = bb.y + (float)rv[1];
  v.z = bb.z + (float)rv[2];
  v.w = bb.w + (float)rv[3];
#pragma unroll
  for (int pl = 0; pl < NP; ++pl) {
    const float4 a = ((const float4*)(p + (size_t)pl * 4096 * 1024 + (size_t)row * 1024))[tid];
    v.x += a.x; v.y += a.y; v.z += a.z; v.w += a.w;
  }
  float s = v.x + v.y + v.z + v.w;
  float s2 = v.x * v.x + v.y * v.y + v.z * v.z + v.w * v.w;
#pragma unroll
  for (int o = 32; o > 0; o >>= 1) { s += __shfl_down(s, o); s2 += __shfl_down(s2, o); }
  __shared__ float red[8];
  if ((tid & 63) == 0) { red[tid >> 6] = s; red[4 + (tid >> 6)] = s2; }
  __syncthreads();
  s = red[0] + red[1] + red[2] + red[3];
  s2 = red[4] + red[5] + red[6] + red[7];
  const float mean = s * (1.f / 1024.f);
  const float var = s2 * (1.f / 1024.f) - mean * mean;
  const float rstd = rsqrtf(var + 1e-5f);
  const float4 gv = ((const float4*)g)[tid];
  const float4 bv = ((const float4*)be)[tid];
  float4 of;
  of.x = (v.x - mean) * rstd * gv.x + bv.x;
  of.y = (v.y - mean) * rstd * gv.y + bv.y;
  of.z = (v.z - mean) * rstd * gv.z + bv.z;
  of.w = (v.w - mean) * rstd * gv.w + bv.w;
  if (fout) {
    ((float4*)(fout + (size_t)row * 1024))[tid] = of;
  } else {
    bf16x4 o4;
    o4[0] = (bf16)of.x; o4[1] = (bf16)of.y; o4[2] = (bf16)of.z; o4[3] = (bf16)of.w;
    *(bf16x4*)&xo[(size_t)row * 1024 + tid * 4] = o4;
  }
}

// ------------------------------ LayerNorm (fp32 y) --------------------------
__global__ __launch_bounds__(256) void ln_kernel(const float* __restrict__ y,
                                                 const float* __restrict__ g,
                                                 const float* __restrict__ be,
                                                 bf16* __restrict__ xo) {
  const int row = blockIdx.x, tid = threadIdx.x;
  const float4 v = ((const float4*)(y + (size_t)row * 1024))[tid];
  float s = v.x + v.y + v.z + v.w;
  float s2 = v.x * v.x + v.y * v.y + v.z * v.z + v.w * v.w;
#pragma unroll
  for (int o = 32; o > 0; o >>= 1) { s += __shfl_down(s, o); s2 += __shfl_down(s2, o); }
  __shared__ float red[8];
  if ((tid & 63) == 0) { red[tid >> 6] = s; red[4 + (tid >> 6)] = s2; }
  __syncthreads();
  s = red[0] + red[1] + red[2] + red[3];
  s2 = red[4] + red[5] + red[6] + red[7];
  const float mean = s * (1.f / 1024.f);
  const float var = s2 * (1.f / 1024.f) - mean * mean;
  const float rstd = rsqrtf(var + 1e-5f);
  const float4 gv = ((const float4*)g)[tid];
  const float4 bv = ((const float4*)be)[tid];
  bf16x4 o4;
  o4[0] = (bf16)((v.x - mean) * rstd * gv.x + bv.x);
  o4[1] = (bf16)((v.y - mean) * rstd * gv.y + bv.y);
  o4[2] = (bf16)((v.z - mean) * rstd * gv.z + bv.z);
  o4[3] = (bf16)((v.w - mean) * rstd * gv.w + bv.w);
  *(bf16x4*)&xo[(size_t)row * 1024 + tid * 4] = o4;
}

// ----------------------------------------------------------------------------
extern "C" void kernel_launch(void* const* d_in, const int* in_sizes, int n_in,
                              void* d_out, int out_size, void* d_ws, size_t ws_size,
                              hipStream_t stream) {
  const int* tokens = (const int*)d_in[0];
  const float* emb = (const float*)d_in[2];
  const float* Wq = (const float*)d_in[3];
  const float* bq = (const float*)d_in[4];
  const float* Wk = (const float*)d_in[5];
  const float* bk = (const float*)d_in[6];
  const float* Wv = (const float*)d_in[7];
  const float* bv = (const float*)d_in[8];
  const float* Wo = (const float*)d_in[9];
  const float* bo = (const float*)d_in[10];
  const float* W1 = (const float*)d_in[11];
  const float* b1 = (const float*)d_in[12];
  const float* W2 = (const float*)d_in[13];
  const float* b2 = (const float*)d_in[14];
  const float* g1 = (const float*)d_in[15];
  const float* be1 = (const float*)d_in[16];
  const float* g2 = (const float*)d_in[17];
  const float* be2 = (const float*)d_in[18];

  char* p = (char*)d_ws;
  auto carve = [&](size_t bytes) { char* r = p; p += (bytes + 255) & ~(size_t)255; return r; };
  bf16* wt_qkv = (bf16*)carve((size_t)3072 * 1024 * 2);
  bf16* wt_o   = (bf16*)carve((size_t)1024 * 1024 * 2);
  bf16* wt_1   = (bf16*)carve((size_t)4096 * 1024 * 2);
  bf16* wt_2   = (bf16*)carve((size_t)1024 * 4096 * 2);
  bf16* xb     = (bf16*)carve((size_t)4096 * 1024 * 2);
  bf16* qb     = (bf16*)carve((size_t)4096 * 1024 * 2);
  bf16* kb     = (bf16*)carve((size_t)4096 * 1024 * 2);
  bf16* vb     = (bf16*)carve((size_t)4096 * 1024 * 2);
  bf16* vtb    = (bf16*)carve((size_t)4096 * 1024 * 2);
  bf16* ctxb   = (bf16*)carve((size_t)4096 * 1024 * 2);
  float* yb    = (float*)carve((size_t)4096 * 1024 * 4);
  float* pb    = (float*)carve((size_t)4 * 4096 * 1024 * 4);   // split-K partials
  bf16* hb     = (bf16*)carve((size_t)4096 * 4096 * 2);

  embed_kernel<<<4096, 256, 0, stream>>>(tokens, emb, xb);

  for (int l = 0; l < 6; ++l) {
    // 64x64 tiles: jobs sized (K/64)*(N/64)
    TArgs ta;
    ta.j[0] = { Wq + (size_t)l * 1024 * 1024, wt_qkv,                  1024, 1024, 0 };
    ta.j[1] = { Wk + (size_t)l * 1024 * 1024, wt_qkv + 1024 * 1024,    1024, 1024, 256 };
    ta.j[2] = { Wv + (size_t)l * 1024 * 1024, wt_qkv + 2 * 1024 * 1024,1024, 1024, 512 };
    ta.j[3] = { Wo + (size_t)l * 1024 * 1024, wt_o,                    1024, 1024, 768 };
    ta.j[4] = { W1 + (size_t)l * 1024 * 4096, wt_1,                    1024, 4096, 1024 };
    ta.j[5] = { W2 + (size_t)l * 4096 * 1024, wt_2,                    4096, 1024, 2048 };
    wtrans_kernel<<<3072, 256, 0, stream>>>(ta);

    // QKV: 256x192 tile, nbx = 3072/192 = 16 -> grid 256 = 1 block/CU
    gemm256<0, 3><<<256, 512, 0, stream>>>(xb, wt_qkv, 1024, 1024, 3072, 16,
        bq + (size_t)l * 1024, bk + (size_t)l * 1024, bv + (size_t)l * 1024,
        nullptr, nullptr, qb, kb, vb);

    vtrans_kernel<<<dim3(32, 32), 256, 0, stream>>>(vb, vtb);

    attn_kernel<<<512, 512, 0, stream>>>(qb, kb, vtb, ctxb);

    // O-proj: 128^2 pipeline, single-pass K=1024, grid 256
    gemm128p<<<256, 256, 0, stream>>>(ctxb, wt_o, 1024,
        bo + (size_t)l * 1024, xb, yb);
    ln_kernel<<<4096, 256, 0, stream>>>(yb, g1 + (size_t)l * 1024,
        be1 + (size_t)l * 1024, xb);

    // FFN1: 256^2 tile, grid 16x16 = 256
    gemm256<2, 4><<<256, 512, 0, stream>>>(xb, wt_1, 1024, 1024, 4096, 16,
        b1 + (size_t)l * 4096, nullptr, nullptr, hb,
        nullptr, nullptr, nullptr, nullptr);

    // FFN2: 256^2 tile split-K=4 (K-slice 1024), grid (64,4) = 256 blocks
    gemm256<1, 4><<<dim3(64, 4), 512, 0, stream>>>(hb, wt_2, 4096, 1024, 1024, 4,
        nullptr, nullptr, nullptr, nullptr, pb,
        nullptr, nullptr, nullptr);
    ln2_kernel<4><<<4096, 256, 0, stream>>>(pb, xb, b2 + (size_t)l * 1024,
        g2 + (size_t)l * 1024, be2 + (size_t)l * 1024, xb,
        (l == 5) ? (float*)d_out : nullptr);
  }
}

// Round 15
// 1364.128 us; speedup vs baseline: 1.1325x; 1.0033x over previous
//
#include <hip/hip_runtime.h>
#include <hip/hip_bf16.h>
#include <cstdint>
#include <cstddef>

// ---------------------------------------------------------------------------
// Transformer encoder, 6 layers: B=2,S=2048,D=1024,H=16,HD=64,F=4096.
// QKV: 256x192-tile (grid 256 = 1/CU), V written directly transposed
// (vtrans fused into epilogue). FFN1: 256^2. Both: 8-wave counted-vmcnt
// double buffer (T2+T3+T4+T5). FFN2: gemm256 split-K=4 + fused LN.
// O-proj: 128^2 pipeline. Flash attention: 8-wave blocks (Q=128), KVBLK=128,
// XCD-swizzled grid, swapped QK^T, T2 swizzle, reg-staged K/V double buffer.
// ---------------------------------------------------------------------------

typedef __bf16 bf16;
typedef __bf16 bf16x2 __attribute__((ext_vector_type(2)));
typedef __bf16 bf16x4 __attribute__((ext_vector_type(4)));
typedef __bf16 bf16x8 __attribute__((ext_vector_type(8)));
typedef float  f32x4  __attribute__((ext_vector_type(4)));

#define MFMA16(a, b, c) __builtin_amdgcn_mfma_f32_16x16x32_bf16((a), (b), (c), 0, 0, 0)

static __device__ __forceinline__ void load_lds16(const void* g, void* l) {
  __builtin_amdgcn_global_load_lds((const __attribute__((address_space(1))) void*)g,
                                   (__attribute__((address_space(3))) void*)l, 16, 0, 0);
}

#define BAR()   __builtin_amdgcn_s_barrier()
#define SCH0()  __builtin_amdgcn_sched_barrier(0)
#define VMCNT8() asm volatile("s_waitcnt vmcnt(8)" ::: "memory")
#define VMCNT7() asm volatile("s_waitcnt vmcnt(7)" ::: "memory")
#define VMCNT0() asm volatile("s_waitcnt vmcnt(0)" ::: "memory")

// ---------------- embedding + positional encoding -> bf16 x ----------------
__global__ __launch_bounds__(256) void embed_kernel(const int* __restrict__ tok,
                                                    const float* __restrict__ emb,
                                                    bf16* __restrict__ xo) {
  const int row = blockIdx.x;          // b*2048 + s
  const int s = row & 2047;
  const int t = tok[row];
  const int d0 = threadIdx.x * 4;
  const float4 e = *(const float4*)&emb[(size_t)t * 1024 + d0];
  const float* ef = (const float*)&e;
  bf16x4 o4;
#pragma unroll
  for (int j = 0; j < 4; ++j) {
    const int d = d0 + j;
    const float div = __expf(-(float)(d & ~1) * 0.00899447301950864f); // ln(1e4)/1024
    const float arg = (float)s * div;
    const float pe = (d & 1) ? cosf(arg) : sinf(arg);
    o4[j] = (bf16)(ef[j] + pe);
  }
  *(bf16x4*)&xo[(size_t)row * 1024 + d0] = o4;
}

// ------------- weight transpose: fp32 [K][N] -> bf16 [N][K], batched --------
struct TJob { const float* src; bf16* dst; int K; int N; int t0; };
struct TArgs { TJob j[6]; };

__global__ __launch_bounds__(256) void wtrans_kernel(TArgs a) {
  __shared__ float t[64][65];
  const int blk = blockIdx.x;
  const float* src = a.j[0].src; bf16* dst = a.j[0].dst;
  int K = a.j[0].K, N = a.j[0].N, t0 = a.j[0].t0;
#pragma unroll
  for (int q = 1; q < 6; ++q)
    if (blk >= a.j[q].t0) { src = a.j[q].src; dst = a.j[q].dst; K = a.j[q].K; N = a.j[q].N; t0 = a.j[q].t0; }
  const int tj = blk - t0;
  const int tilesK = K >> 6;
  const int tk = (tj % tilesK) << 6;
  const int tn = (tj / tilesK) << 6;
  const int tid = threadIdx.x;
  const int rr = tid >> 4;            // 0..15
  const int c4 = (tid & 15) * 4;
#pragma unroll
  for (int i = 0; i < 4; ++i) {
    const float4 v = *(const float4*)&src[(size_t)(tk + rr + 16 * i) * N + tn + c4];
    t[rr + 16 * i][c4 + 0] = v.x;
    t[rr + 16 * i][c4 + 1] = v.y;
    t[rr + 16 * i][c4 + 2] = v.z;
    t[rr + 16 * i][c4 + 3] = v.w;
  }
  __syncthreads();
  const int k0 = (tid & 15) * 4;
#pragma unroll
  for (int i = 0; i < 4; ++i) {
    const int n = rr + 16 * i;
    bf16x4 o;
#pragma unroll
    for (int j = 0; j < 4; ++j) o[j] = (bf16)t[k0 + j][n];
    *(bf16x4*)&dst[(size_t)(tn + n) * K + tk + k0] = o;
  }
}

// ======================= shared GEMM building blocks ========================
static __device__ __forceinline__ bf16x8 ldsfrag(const bf16* base, int row, int colb) {
  int off = row * 128 + colb;
  off ^= ((off >> 7) & 7) << 4;
  return *(const bf16x8*)((const char*)base + off);
}

// ====== 256xBN-tile 8-wave GEMM, counted-vmcnt (BN = 64*BNF, BNF=3|4) ======
template <int BNF>
static __device__ __forceinline__ void stage_tileT(const bf16* __restrict__ Ag,
    const bf16* __restrict__ Bg, int Kstr, int kt, bf16* lA, bf16* lB, int tid) {
  const char* wbaseA = (const char*)lA + ((tid >> 6) << 10);
  const char* wbaseB = (const char*)lB + ((tid >> 6) << 10);
#pragma unroll
  for (int s = 0; s < 4; ++s) {
    const int L = s * 8192 + tid * 16;
    const int off = L ^ (((L >> 7) & 7) << 4);
    load_lds16(Ag + (size_t)(off >> 7) * Kstr + kt * 64 + ((off & 127) >> 1),
               (void*)(wbaseA + s * 8192));
  }
#pragma unroll
  for (int s = 0; s < BNF; ++s) {
    const int L = s * 8192 + tid * 16;
    const int off = L ^ (((L >> 7) & 7) << 4);
    load_lds16(Bg + (size_t)(off >> 7) * Kstr + kt * 64 + ((off & 127) >> 1),
               (void*)(wbaseB + s * 8192));
  }
}

template <int BNF>
static __device__ __forceinline__ void compute_tileT(const bf16* lA, const bf16* lB,
    int wm, int wn, int lr, int lg, f32x4 (&acc)[8][BNF]) {
  bf16x8 bfr[BNF][2];
#pragma unroll
  for (int n = 0; n < BNF; ++n)
#pragma unroll
    for (int kk = 0; kk < 2; ++kk)
      bfr[n][kk] = ldsfrag(lB, wn * (16 * BNF) + n * 16 + lr, kk * 64 + lg * 16);
#pragma unroll
  for (int m = 0; m < 8; ++m) {
    const bf16x8 a0 = ldsfrag(lA, wm * 128 + m * 16 + lr, lg * 16);
    const bf16x8 a1 = ldsfrag(lA, wm * 128 + m * 16 + lr, 64 + lg * 16);
    __builtin_amdgcn_s_setprio(1);
#pragma unroll
    for (int n = 0; n < BNF; ++n) {
      acc[m][n] = MFMA16(a0, bfr[n][0], acc[m][n]);
      acc[m][n] = MFMA16(a1, bfr[n][1], acc[m][n]);
    }
    __builtin_amdgcn_s_setprio(0);
  }
}

template <int BNF>
static __device__ __forceinline__ void waitK() {
  if constexpr (BNF == 3) { VMCNT7(); } else { VMCNT8(); }
}

template <int EPI, int BNF>  // EPI 0: qkv scatter (V transposed), 1: fp32 partial, 2: bias+relu
__global__ __launch_bounds__(512, 2) void gemm256(
    const bf16* __restrict__ A, const bf16* __restrict__ Bt,
    int Kstr, int Kloop, int Nn, int nbx,
    const float* __restrict__ bias0, const float* __restrict__ bias1,
    const float* __restrict__ bias2, bf16* __restrict__ outb,
    float* __restrict__ pout,
    bf16* __restrict__ q_out, bf16* __restrict__ k_out, bf16* __restrict__ vt_out) {
  __shared__ __align__(16) bf16 ldsA[2][16384];       // 32KB each
  __shared__ __align__(16) bf16 ldsB[2][BNF * 4096];  // BNF*8KB each
  const int bz = blockIdx.y;
  const bf16* Abase = A + (size_t)bz * Kloop;
  const bf16* Bbase = Bt + (size_t)bz * Kloop;
  const int cpx = gridDim.x >> 3;
  const int wg = (blockIdx.x & 7) * cpx + (blockIdx.x >> 3);
  const int bx = wg % nbx, by = wg / nbx;
  const int tid = threadIdx.x;
  const int lane = tid & 63, wave = tid >> 6;
  const int lr = lane & 15, lg = lane >> 4;
  const int wm = wave >> 2, wn = wave & 3;
  const int m0 = by * 256, n0 = bx * (64 * BNF);

  const bf16* Ag = Abase + (size_t)m0 * Kstr;
  const bf16* Bg = Bbase + (size_t)n0 * Kstr;

  f32x4 acc[8][BNF] = {};
  const int T = Kloop >> 6;

  stage_tileT<BNF>(Ag, Bg, Kstr, 0, ldsA[0], ldsB[0], tid);
  stage_tileT<BNF>(Ag, Bg, Kstr, 1, ldsA[1], ldsB[1], tid);
  waitK<BNF>(); BAR(); SCH0();

  for (int t = 0; t + 3 < T; t += 2) {
    compute_tileT<BNF>(ldsA[0], ldsB[0], wm, wn, lr, lg, acc);
    BAR(); SCH0();
    stage_tileT<BNF>(Ag, Bg, Kstr, t + 2, ldsA[0], ldsB[0], tid);
    waitK<BNF>(); BAR(); SCH0();
    compute_tileT<BNF>(ldsA[1], ldsB[1], wm, wn, lr, lg, acc);
    BAR(); SCH0();
    stage_tileT<BNF>(Ag, Bg, Kstr, t + 3, ldsA[1], ldsB[1], tid);
    waitK<BNF>(); BAR(); SCH0();
  }
  compute_tileT<BNF>(ldsA[0], ldsB[0], wm, wn, lr, lg, acc);  // tile T-2
  VMCNT0(); BAR(); SCH0();                                    // tile T-1 landed
  compute_tileT<BNF>(ldsA[1], ldsB[1], wm, wn, lr, lg, acc);  // tile T-1

#pragma unroll
  for (int m = 0; m < 8; ++m)
#pragma unroll
    for (int n = 0; n < BNF; ++n) {
      if (EPI == 0) {
        // col range of this fragment is 16-aligned -> segment-uniform
        const int col = n0 + wn * (16 * BNF) + n * 16 + lr;
        const int which = col >> 10, hc = col & 1023;
        const int h = hc >> 6, hd = hc & 63;
        const int row0 = m0 + wm * 128 + m * 16 + lg * 4;
        const int b = row0 >> 11, s0 = row0 & 2047;
        if (which == 2) {
          // V: 4 consecutive s at fixed hd -> one bf16x4 in [bh][hd][s] layout
          bf16x4 o;
#pragma unroll
          for (int r = 0; r < 4; ++r) o[r] = (bf16)(acc[m][n][r] + bias2[hc]);
          *(bf16x4*)&vt_out[(((size_t)b * 16 + h) * 64 + hd) * 2048 + s0] = o;
        } else {
          const float* bs = (which == 0) ? bias0 : bias1;
          bf16* dst = (which == 0) ? q_out : k_out;
#pragma unroll
          for (int r = 0; r < 4; ++r)
            dst[(((size_t)b * 16 + h) * 2048 + s0 + r) * 64 + hd] =
                (bf16)(acc[m][n][r] + bs[hc]);
        }
      } else {
#pragma unroll
        for (int r = 0; r < 4; ++r) {
          const int row = m0 + wm * 128 + m * 16 + lg * 4 + r;
          const int col = n0 + wn * (16 * BNF) + n * 16 + lr;
          float val = acc[m][n][r];
          if (EPI == 1) {
            pout[(size_t)bz * 4096 * 1024 + (size_t)row * 1024 + col] = val;
          } else {
            val += bias0[col];
            outb[(size_t)row * Nn + col] = (bf16)(val > 0.f ? val : 0.f);
          }
        }
      }
    }
}

// ========== 128x128-tile 4-wave GEMM, counted-vmcnt (O-proj K=1024) =========
static __device__ __forceinline__ void stage128(const bf16* __restrict__ Ag,
    const bf16* __restrict__ Bg, int Kstr, int kt, bf16* lA, bf16* lB, int tid) {
  const char* dA = (const char*)lA + ((tid >> 6) << 10);
  const char* dB = (const char*)lB + ((tid >> 6) << 10);
#pragma unroll
  for (int s = 0; s < 4; ++s) {
    const int L = s * 4096 + tid * 16;
    const int off = L ^ (((L >> 7) & 7) << 4);
    load_lds16(Ag + (size_t)(off >> 7) * Kstr + kt * 64 + ((off & 127) >> 1),
               (void*)(dA + s * 4096));
  }
#pragma unroll
  for (int s = 0; s < 4; ++s) {
    const int L = s * 4096 + tid * 16;
    const int off = L ^ (((L >> 7) & 7) << 4);
    load_lds16(Bg + (size_t)(off >> 7) * Kstr + kt * 64 + ((off & 127) >> 1),
               (void*)(dB + s * 4096));
  }
}

static __device__ __forceinline__ void compute128(const bf16* lA, const bf16* lB,
    int wm, int wn, int lr, int lg, f32x4 (&acc)[4][4]) {
  bf16x8 bfr[4][2];
#pragma unroll
  for (int n = 0; n < 4; ++n)
#pragma unroll
    for (int kk = 0; kk < 2; ++kk)
      bfr[n][kk] = ldsfrag(lB, wn * 64 + n * 16 + lr, kk * 64 + lg * 16);
#pragma unroll
  for (int m = 0; m < 4; ++m) {
    const bf16x8 a0 = ldsfrag(lA, wm * 64 + m * 16 + lr, lg * 16);
    const bf16x8 a1 = ldsfrag(lA, wm * 64 + m * 16 + lr, 64 + lg * 16);
    __builtin_amdgcn_s_setprio(1);
#pragma unroll
    for (int n = 0; n < 4; ++n) {
      acc[m][n] = MFMA16(a0, bfr[n][0], acc[m][n]);
      acc[m][n] = MFMA16(a1, bfr[n][1], acc[m][n]);
    }
    __builtin_amdgcn_s_setprio(0);
  }
}

__global__ __launch_bounds__(256, 2) void gemm128p(
    const bf16* __restrict__ A, const bf16* __restrict__ Bt, int Kk,
    const float* __restrict__ bias, const bf16* __restrict__ resid,
    float* __restrict__ outf) {
  __shared__ __align__(16) bf16 lds[4][8192];    // A0,B0,A1,B1 (16KB each)
  const int cpx = gridDim.x >> 3;
  const int wg = (blockIdx.x & 7) * cpx + (blockIdx.x >> 3);
  const int bx = wg & 7, by = wg >> 3;           // nbx = 8 (N=1024)
  const int tid = threadIdx.x;
  const int lane = tid & 63, wave = tid >> 6;
  const int lr = lane & 15, lg = lane >> 4;
  const int wm = wave >> 1, wn = wave & 1;
  const int m0 = by * 128, n0 = bx * 128;

  const bf16* Ag = A + (size_t)m0 * Kk;
  const bf16* Bg = Bt + (size_t)n0 * Kk;
  bf16* LA0 = lds[0]; bf16* LB0 = lds[1];
  bf16* LA1 = lds[2]; bf16* LB1 = lds[3];

  f32x4 acc[4][4] = {};
  const int T = Kk >> 6;

  stage128(Ag, Bg, Kk, 0, LA0, LB0, tid);
  stage128(Ag, Bg, Kk, 1, LA1, LB1, tid);
  VMCNT8(); BAR(); SCH0();

  for (int t = 0; t + 3 < T; t += 2) {
    compute128(LA0, LB0, wm, wn, lr, lg, acc);
    BAR(); SCH0();
    stage128(Ag, Bg, Kk, t + 2, LA0, LB0, tid);
    VMCNT8(); BAR(); SCH0();
    compute128(LA1, LB1, wm, wn, lr, lg, acc);
    BAR(); SCH0();
    stage128(Ag, Bg, Kk, t + 3, LA1, LB1, tid);
    VMCNT8(); BAR(); SCH0();
  }
  compute128(LA0, LB0, wm, wn, lr, lg, acc);     // tile T-2
  VMCNT0(); BAR(); SCH0();                       // tile T-1 landed
  compute128(LA1, LB1, wm, wn, lr, lg, acc);     // tile T-1

#pragma unroll
  for (int m = 0; m < 4; ++m)
#pragma unroll
    for (int n = 0; n < 4; ++n)
#pragma unroll
      for (int r = 0; r < 4; ++r) {
        const int row = m0 + wm * 64 + m * 16 + lg * 4 + r;
        const int col = n0 + wn * 64 + n * 16 + lr;
        const float val = acc[m][n][r] + bias[col]
                        + (float)resid[(size_t)row * 1024 + col];
        outf[(size_t)row * 1024 + col] = val;
      }
}

// ------------------------- flash attention (per b,h) ------------------------
// 1D grid 512, XCD-swizzled. block: 512 = 8 waves; wave w owns q-rows
// [128*(wid&15) + 16w, +16). KVBLK=128: one barrier-pair per 128-key chunk,
// two 64-key halves with NO barrier between. Reg-staged K/V double buffer,
// slot-XOR swizzle, swapped QK^T, log2-domain softmax with defer-max.
// Chunk loop MUST be unrolled by 2 (rule #20, round-3 lesson).
__global__ __launch_bounds__(512) void attn_kernel(const bf16* __restrict__ q,
                                                   const bf16* __restrict__ k,
                                                   const bf16* __restrict__ vt,
                                                   bf16* __restrict__ ctxo) {
  __shared__ __align__(16) bf16 Kl[128][64];  // rows = key, 8 slots of 16B
  __shared__ __align__(16) bf16 Vt[64][128];  // rows = hd, 16 slots of 16B
  __shared__ __align__(16) bf16 Pl[8][16][64];
  const int wid = ((blockIdx.x & 7) << 6) + (blockIdx.x >> 3);
  const int bh = wid >> 4;
  const int q0 = (wid & 15) * 128;
  const int tid = threadIdx.x;
  const int lane = tid & 63, w = tid >> 6;
  const int lr = lane & 15, lg = lane >> 4;
  const int swz = lr & 7;

  const bf16* qp = q + ((size_t)bh * 2048 + q0 + w * 16) * 64;
  bf16x8 qf0 = *(const bf16x8*)&qp[lr * 64 + lg * 8];
  bf16x8 qf1 = *(const bf16x8*)&qp[lr * 64 + lg * 8 + 32];
  const float qs = 0.18033688011112042f;      // (1/8)*log2(e)
#pragma unroll
  for (int j = 0; j < 8; ++j) {
    qf0[j] = (bf16)((float)qf0[j] * qs);
    qf1[j] = (bf16)((float)qf1[j] * qs);
  }
  bf16x8 ones8;
#pragma unroll
  for (int j = 0; j < 8; ++j) ones8[j] = (bf16)1.0f;

  const bf16* kbase = k + (size_t)bh * 2048 * 64;
  const bf16* vtb = vt + (size_t)bh * 64 * 2048;

  const int skr = tid >> 3;
  const int skc = (tid & 7) * 8;
  const int skcs = skc ^ ((skr & 7) << 3);
  const int svr = tid >> 4;
  const int svslot = tid & 15;
  const int svs = (svslot ^ (svr & 7)) * 8;

  f32x4 acc[4] = {};
  f32x4 accl = {};
  float mq = -1e30f;

  bf16x8 kr[2][2], vr[2][2];
  kr[0][0] = *(const bf16x8*)&kbase[(size_t)skr * 64 + skc];
  kr[0][1] = *(const bf16x8*)&kbase[(size_t)(skr + 64) * 64 + skc];
  vr[0][0] = *(const bf16x8*)&vtb[(size_t)svr * 2048 + svslot * 8];
  vr[0][1] = *(const bf16x8*)&vtb[(size_t)(svr + 32) * 2048 + svslot * 8];

#pragma unroll 2
  for (int c = 0; c < 16; ++c) {
    const int pp = c & 1;
    *(bf16x8*)&Kl[skr][skcs]      = kr[pp][0];
    *(bf16x8*)&Kl[skr + 64][skcs] = kr[pp][1];
    *(bf16x8*)&Vt[svr][svs]       = vr[pp][0];
    *(bf16x8*)&Vt[svr + 32][svs]  = vr[pp][1];
    if (c + 1 < 16) {
      const int key0n = (c + 1) * 128;
      kr[pp ^ 1][0] = *(const bf16x8*)&kbase[(size_t)(key0n + skr) * 64 + skc];
      kr[pp ^ 1][1] = *(const bf16x8*)&kbase[(size_t)(key0n + skr + 64) * 64 + skc];
      vr[pp ^ 1][0] = *(const bf16x8*)&vtb[(size_t)svr * 2048 + key0n + svslot * 8];
      vr[pp ^ 1][1] = *(const bf16x8*)&vtb[(size_t)(svr + 32) * 2048 + key0n + svslot * 8];
    }
    __syncthreads();

#pragma unroll
    for (int hf = 0; hf < 2; ++hf) {
      f32x4 st[4];
      __builtin_amdgcn_s_setprio(1);
#pragma unroll
      for (int ks = 0; ks < 4; ++ks) {
        const bf16x8 kf0 = *(const bf16x8*)&Kl[hf * 64 + ks * 16 + lr][(lg ^ swz) << 3];
        const bf16x8 kf1 = *(const bf16x8*)&Kl[hf * 64 + ks * 16 + lr][((lg + 4) ^ swz) << 3];
        f32x4 sa = {};
        sa = MFMA16(kf0, qf0, sa);
        sa = MFMA16(kf1, qf1, sa);
        st[ks] = sa;
      }
      __builtin_amdgcn_s_setprio(0);

      float mx = st[0][0];
#pragma unroll
      for (int ks = 0; ks < 4; ++ks)
#pragma unroll
        for (int r = 0; r < 4; ++r) mx = fmaxf(mx, st[ks][r]);
      mx = fmaxf(mx, __shfl_xor(mx, 16));
      mx = fmaxf(mx, __shfl_xor(mx, 32));
      if (!__all(mx - mq <= 8.0f)) {               // defer-max (T13)
        const float resc = exp2f(mq - mx);
        mq = mx;
        float rq[4];
#pragma unroll
        for (int r = 0; r < 4; ++r) rq[r] = __shfl(resc, lg * 4 + r);
#pragma unroll
        for (int r = 0; r < 4; ++r) {
          accl[r] *= rq[r];
#pragma unroll
          for (int jn = 0; jn < 4; ++jn) acc[jn][r] *= rq[r];
        }
      }
#pragma unroll
      for (int ks = 0; ks < 4; ++ks) {             // P pack + vectorized store
        bf16x4 pk;
#pragma unroll
        for (int r = 0; r < 4; ++r) pk[r] = (bf16)exp2f(st[ks][r] - mq);
        const int col = (((ks * 2 + (lg >> 1)) ^ swz) << 3) + ((lg & 1) << 2);
        *(bf16x4*)&Pl[w][lr][col] = pk;
      }

      const bf16x8 pf0 = *(const bf16x8*)&Pl[w][lr][(lg ^ swz) << 3];
      const bf16x8 pf1 = *(const bf16x8*)&Pl[w][lr][((lg + 4) ^ swz) << 3];
      __builtin_amdgcn_s_setprio(1);
#pragma unroll
      for (int jn = 0; jn < 4; ++jn) {
        const bf16x8 vf0 = *(const bf16x8*)&Vt[jn * 16 + lr][hf * 64 + ((lg ^ swz) << 3)];
        const bf16x8 vf1 = *(const bf16x8*)&Vt[jn * 16 + lr][hf * 64 + (((lg + 4) ^ swz) << 3)];
        acc[jn] = MFMA16(pf0, vf0, acc[jn]);
        acc[jn] = MFMA16(pf1, vf1, acc[jn]);
      }
      accl = MFMA16(pf0, ones8, accl);
      accl = MFMA16(pf1, ones8, accl);
      __builtin_amdgcn_s_setprio(0);
    }
    __syncthreads();
  }

  const int bb = bh >> 4, hh = bh & 15;
#pragma unroll
  for (int r = 0; r < 4; ++r) {
    const float inv = 1.f / accl[r];
    const size_t rowg = (size_t)bb * 2048 + q0 + w * 16 + lg * 4 + r;
#pragma unroll
    for (int jn = 0; jn < 4; ++jn)
      ctxo[rowg * 1024 + hh * 64 + jn * 16 + lr] = (bf16)(acc[jn][r] * inv);
  }
}

// ---------- fused split-K reduce + bias + residual + LayerNorm --------------
template <int NP>
__global__ __launch_bounds__(256) void ln2_kernel(const float* __restrict__ p,
                                                  const bf16* __restrict__ resid,
                                                  const float* __restrict__ bias,
                                                  const float* __restrict__ g,
                                                  const float* __restrict__ be,
                                                  bf16* __restrict__ xo,
                                                  float* __restrict__ fout) {
  const int row = blockIdx.x, tid = threadIdx.x;
  const bf16x4 rv = *(const bf16x4*)&resid[(size_t)row * 1024 + tid * 4];
  const float4 bb = ((const float4*)bias)[tid];
  float4 v;
  v.x = bb.x + (float)rv[0];
  v.y = bb.y + (float)rv[1];
  v.z = bb.z + (float)rv[2];
  v.w = bb.w + (float)rv[3];
#pragma unroll
  for (int pl = 0; pl < NP; ++pl) {
    const float4 a = ((const float4*)(p + (size_t)pl * 4096 * 1024 + (size_t)row * 1024))[tid];
    v.x += a.x; v.y += a.y; v.z += a.z; v.w += a.w;
  }
  float s = v.x + v.y + v.z + v.w;
  float s2 = v.x * v.x + v.y * v.y + v.z * v.z + v.w * v.w;
#pragma unroll
  for (int o = 32; o > 0; o >>= 1) { s += __shfl_down(s, o); s2 += __shfl_down(s2, o); }
  __shared__ float red[8];
  if ((tid & 63) == 0) { red[tid >> 6] = s; red[4 + (tid >> 6)] = s2; }
  __syncthreads();
  s = red[0] + red[1] + red[2] + red[3];
  s2 = red[4] + red[5] + red[6] + red[7];
  const float mean = s * (1.f / 1024.f);
  const float var = s2 * (1.f / 1024.f) - mean * mean;
  const float rstd = rsqrtf(var + 1e-5f);
  const float4 gv = ((const float4*)g)[tid];
  const float4 bv = ((const float4*)be)[tid];
  float4 of;
  of.x = (v.x - mean) * rstd * gv.x + bv.x;
  of.y = (v.y - mean) * rstd * gv.y + bv.y;
  of.z = (v.z - mean) * rstd * gv.z + bv.z;
  of.w = (v.w - mean) * rstd * gv.w + bv.w;
  if (fout) {
    ((float4*)(fout + (size_t)row * 1024))[tid] = of;
  } else {
    bf16x4 o4;
    o4[0] = (bf16)of.x; o4[1] = (bf16)of.y; o4[2] = (bf16)of.z; o4[3] = (bf16)of.w;
    *(bf16x4*)&xo[(size_t)row * 1024 + tid * 4] = o4;
  }
}

// ------------------------------ LayerNorm (fp32 y) --------------------------
__global__ __launch_bounds__(256) void ln_kernel(const float* __restrict__ y,
                                                 const float* __restrict__ g,
                                                 const float* __restrict__ be,
                                                 bf16* __restrict__ xo) {
  const int row = blockIdx.x, tid = threadIdx.x;
  const float4 v = ((const float4*)(y + (size_t)row * 1024))[tid];
  float s = v.x + v.y + v.z + v.w;
  float s2 = v.x * v.x + v.y * v.y + v.z * v.z + v.w * v.w;
#pragma unroll
  for (int o = 32; o > 0; o >>= 1) { s += __shfl_down(s, o); s2 += __shfl_down(s2, o); }
  __shared__ float red[8];
  if ((tid & 63) == 0) { red[tid >> 6] = s; red[4 + (tid >> 6)] = s2; }
  __syncthreads();
  s = red[0] + red[1] + red[2] + red[3];
  s2 = red[4] + red[5] + red[6] + red[7];
  const float mean = s * (1.f / 1024.f);
  const float var = s2 * (1.f / 1024.f) - mean * mean;
  const float rstd = rsqrtf(var + 1e-5f);
  const float4 gv = ((const float4*)g)[tid];
  const float4 bv = ((const float4*)be)[tid];
  bf16x4 o4;
  o4[0] = (bf16)((v.x - mean) * rstd * gv.x + bv.x);
  o4[1] = (bf16)((v.y - mean) * rstd * gv.y + bv.y);
  o4[2] = (bf16)((v.z - mean) * rstd * gv.z + bv.z);
  o4[3] = (bf16)((v.w - mean) * rstd * gv.w + bv.w);
  *(bf16x4*)&xo[(size_t)row * 1024 + tid * 4] = o4;
}

// ----------------------------------------------------------------------------
extern "C" void kernel_launch(void* const* d_in, const int* in_sizes, int n_in,
                              void* d_out, int out_size, void* d_ws, size_t ws_size,
                              hipStream_t stream) {
  const int* tokens = (const int*)d_in[0];
  const float* emb = (const float*)d_in[2];
  const float* Wq = (const float*)d_in[3];
  const float* bq = (const float*)d_in[4];
  const float* Wk = (const float*)d_in[5];
  const float* bk = (const float*)d_in[6];
  const float* Wv = (const float*)d_in[7];
  const float* bv = (const float*)d_in[8];
  const float* Wo = (const float*)d_in[9];
  const float* bo = (const float*)d_in[10];
  const float* W1 = (const float*)d_in[11];
  const float* b1 = (const float*)d_in[12];
  const float* W2 = (const float*)d_in[13];
  const float* b2 = (const float*)d_in[14];
  const float* g1 = (const float*)d_in[15];
  const float* be1 = (const float*)d_in[16];
  const float* g2 = (const float*)d_in[17];
  const float* be2 = (const float*)d_in[18];

  char* p = (char*)d_ws;
  auto carve = [&](size_t bytes) { char* r = p; p += (bytes + 255) & ~(size_t)255; return r; };
  bf16* wt_qkv = (bf16*)carve((size_t)3072 * 1024 * 2);
  bf16* wt_o   = (bf16*)carve((size_t)1024 * 1024 * 2);
  bf16* wt_1   = (bf16*)carve((size_t)4096 * 1024 * 2);
  bf16* wt_2   = (bf16*)carve((size_t)1024 * 4096 * 2);
  bf16* xb     = (bf16*)carve((size_t)4096 * 1024 * 2);
  bf16* qb     = (bf16*)carve((size_t)4096 * 1024 * 2);
  bf16* kb     = (bf16*)carve((size_t)4096 * 1024 * 2);
  bf16* vtb    = (bf16*)carve((size_t)4096 * 1024 * 2);
  bf16* ctxb   = (bf16*)carve((size_t)4096 * 1024 * 2);
  float* yb    = (float*)carve((size_t)4096 * 1024 * 4);
  float* pb    = (float*)carve((size_t)4 * 4096 * 1024 * 4);   // split-K partials
  bf16* hb     = (bf16*)carve((size_t)4096 * 4096 * 2);

  embed_kernel<<<4096, 256, 0, stream>>>(tokens, emb, xb);

  for (int l = 0; l < 6; ++l) {
    // 64x64 tiles: jobs sized (K/64)*(N/64)
    TArgs ta;
    ta.j[0] = { Wq + (size_t)l * 1024 * 1024, wt_qkv,                  1024, 1024, 0 };
    ta.j[1] = { Wk + (size_t)l * 1024 * 1024, wt_qkv + 1024 * 1024,    1024, 1024, 256 };
    ta.j[2] = { Wv + (size_t)l * 1024 * 1024, wt_qkv + 2 * 1024 * 1024,1024, 1024, 512 };
    ta.j[3] = { Wo + (size_t)l * 1024 * 1024, wt_o,                    1024, 1024, 768 };
    ta.j[4] = { W1 + (size_t)l * 1024 * 4096, wt_1,                    1024, 4096, 1024 };
    ta.j[5] = { W2 + (size_t)l * 4096 * 1024, wt_2,                    4096, 1024, 2048 };
    wtrans_kernel<<<3072, 256, 0, stream>>>(ta);

    // QKV: 256x192 tile, nbx = 16 -> grid 256 = 1 block/CU. V written
    // directly transposed into vtb (vtrans fused).
    gemm256<0, 3><<<256, 512, 0, stream>>>(xb, wt_qkv, 1024, 1024, 3072, 16,
        bq + (size_t)l * 1024, bk + (size_t)l * 1024, bv + (size_t)l * 1024,
        nullptr, nullptr, qb, kb, vtb);

    attn_kernel<<<512, 512, 0, stream>>>(qb, kb, vtb, ctxb);

    // O-proj: 128^2 pipeline, single-pass K=1024, grid 256
    gemm128p<<<256, 256, 0, stream>>>(ctxb, wt_o, 1024,
        bo + (size_t)l * 1024, xb, yb);
    ln_kernel<<<4096, 256, 0, stream>>>(yb, g1 + (size_t)l * 1024,
        be1 + (size_t)l * 1024, xb);

    // FFN1: 256^2 tile, grid 16x16 = 256
    gemm256<2, 4><<<256, 512, 0, stream>>>(xb, wt_1, 1024, 1024, 4096, 16,
        b1 + (size_t)l * 4096, nullptr, nullptr, hb,
        nullptr, nullptr, nullptr, nullptr);

    // FFN2: 256^2 tile split-K=4 (K-slice 1024), grid (64,4) = 256 blocks
    gemm256<1, 4><<<dim3(64, 4), 512, 0, stream>>>(hb, wt_2, 4096, 1024, 1024, 4,
        nullptr, nullptr, nullptr, nullptr, pb,
        nullptr, nullptr, nullptr);
    ln2_kernel<4><<<4096, 256, 0, stream>>>(pb, xb, b2 + (size_t)l * 1024,
        g2 + (size_t)l * 1024, be2 + (size_t)l * 1024, xb,
        (l == 5) ? (float*)d_out : nullptr);
  }
}

// Round 16
// 1353.065 us; speedup vs baseline: 1.1418x; 1.0082x over previous
//
#include <hip/hip_runtime.h>
#include <hip/hip_bf16.h>
#include <cstdint>
#include <cstddef>

// ---------------------------------------------------------------------------
// Transformer encoder, 6 layers: B=2,S=2048,D=1024,H=16,HD=64,F=4096.
// QKV: 256x192-tile (grid 256 = 1/CU), V written directly transposed.
// FFN1: 256^2. Both: 8-wave counted-vmcnt double buffer (T2+T3+T4+T5).
// FFN2: gemm256 split-K=4 + fused LN. O-proj: 128^2 pipeline.
// Flash attention: 16-wave blocks (Q=256), KVBLK=128, XCD-swizzled grid,
// swapped QK^T, T2 swizzle, reg-staged K/V double buffer.
// ---------------------------------------------------------------------------

typedef __bf16 bf16;
typedef __bf16 bf16x2 __attribute__((ext_vector_type(2)));
typedef __bf16 bf16x4 __attribute__((ext_vector_type(4)));
typedef __bf16 bf16x8 __attribute__((ext_vector_type(8)));
typedef float  f32x4  __attribute__((ext_vector_type(4)));

#define MFMA16(a, b, c) __builtin_amdgcn_mfma_f32_16x16x32_bf16((a), (b), (c), 0, 0, 0)

static __device__ __forceinline__ void load_lds16(const void* g, void* l) {
  __builtin_amdgcn_global_load_lds((const __attribute__((address_space(1))) void*)g,
                                   (__attribute__((address_space(3))) void*)l, 16, 0, 0);
}

#define BAR()   __builtin_amdgcn_s_barrier()
#define SCH0()  __builtin_amdgcn_sched_barrier(0)
#define VMCNT8() asm volatile("s_waitcnt vmcnt(8)" ::: "memory")
#define VMCNT7() asm volatile("s_waitcnt vmcnt(7)" ::: "memory")
#define VMCNT0() asm volatile("s_waitcnt vmcnt(0)" ::: "memory")

// ---------------- embedding + positional encoding -> bf16 x ----------------
__global__ __launch_bounds__(256) void embed_kernel(const int* __restrict__ tok,
                                                    const float* __restrict__ emb,
                                                    bf16* __restrict__ xo) {
  const int row = blockIdx.x;          // b*2048 + s
  const int s = row & 2047;
  const int t = tok[row];
  const int d0 = threadIdx.x * 4;
  const float4 e = *(const float4*)&emb[(size_t)t * 1024 + d0];
  const float* ef = (const float*)&e;
  bf16x4 o4;
#pragma unroll
  for (int j = 0; j < 4; ++j) {
    const int d = d0 + j;
    const float div = __expf(-(float)(d & ~1) * 0.00899447301950864f); // ln(1e4)/1024
    const float arg = (float)s * div;
    const float pe = (d & 1) ? cosf(arg) : sinf(arg);
    o4[j] = (bf16)(ef[j] + pe);
  }
  *(bf16x4*)&xo[(size_t)row * 1024 + d0] = o4;
}

// ------------- weight transpose: fp32 [K][N] -> bf16 [N][K], batched --------
struct TJob { const float* src; bf16* dst; int K; int N; int t0; };
struct TArgs { TJob j[6]; };

__global__ __launch_bounds__(256) void wtrans_kernel(TArgs a) {
  __shared__ float t[64][65];
  const int blk = blockIdx.x;
  const float* src = a.j[0].src; bf16* dst = a.j[0].dst;
  int K = a.j[0].K, N = a.j[0].N, t0 = a.j[0].t0;
#pragma unroll
  for (int q = 1; q < 6; ++q)
    if (blk >= a.j[q].t0) { src = a.j[q].src; dst = a.j[q].dst; K = a.j[q].K; N = a.j[q].N; t0 = a.j[q].t0; }
  const int tj = blk - t0;
  const int tilesK = K >> 6;
  const int tk = (tj % tilesK) << 6;
  const int tn = (tj / tilesK) << 6;
  const int tid = threadIdx.x;
  const int rr = tid >> 4;            // 0..15
  const int c4 = (tid & 15) * 4;
#pragma unroll
  for (int i = 0; i < 4; ++i) {
    const float4 v = *(const float4*)&src[(size_t)(tk + rr + 16 * i) * N + tn + c4];
    t[rr + 16 * i][c4 + 0] = v.x;
    t[rr + 16 * i][c4 + 1] = v.y;
    t[rr + 16 * i][c4 + 2] = v.z;
    t[rr + 16 * i][c4 + 3] = v.w;
  }
  __syncthreads();
  const int k0 = (tid & 15) * 4;
#pragma unroll
  for (int i = 0; i < 4; ++i) {
    const int n = rr + 16 * i;
    bf16x4 o;
#pragma unroll
    for (int j = 0; j < 4; ++j) o[j] = (bf16)t[k0 + j][n];
    *(bf16x4*)&dst[(size_t)(tn + n) * K + tk + k0] = o;
  }
}

// ======================= shared GEMM building blocks ========================
static __device__ __forceinline__ bf16x8 ldsfrag(const bf16* base, int row, int colb) {
  int off = row * 128 + colb;
  off ^= ((off >> 7) & 7) << 4;
  return *(const bf16x8*)((const char*)base + off);
}

// ====== 256xBN-tile 8-wave GEMM, counted-vmcnt (BN = 64*BNF, BNF=3|4) ======
template <int BNF>
static __device__ __forceinline__ void stage_tileT(const bf16* __restrict__ Ag,
    const bf16* __restrict__ Bg, int Kstr, int kt, bf16* lA, bf16* lB, int tid) {
  const char* wbaseA = (const char*)lA + ((tid >> 6) << 10);
  const char* wbaseB = (const char*)lB + ((tid >> 6) << 10);
#pragma unroll
  for (int s = 0; s < 4; ++s) {
    const int L = s * 8192 + tid * 16;
    const int off = L ^ (((L >> 7) & 7) << 4);
    load_lds16(Ag + (size_t)(off >> 7) * Kstr + kt * 64 + ((off & 127) >> 1),
               (void*)(wbaseA + s * 8192));
  }
#pragma unroll
  for (int s = 0; s < BNF; ++s) {
    const int L = s * 8192 + tid * 16;
    const int off = L ^ (((L >> 7) & 7) << 4);
    load_lds16(Bg + (size_t)(off >> 7) * Kstr + kt * 64 + ((off & 127) >> 1),
               (void*)(wbaseB + s * 8192));
  }
}

template <int BNF>
static __device__ __forceinline__ void compute_tileT(const bf16* lA, const bf16* lB,
    int wm, int wn, int lr, int lg, f32x4 (&acc)[8][BNF]) {
  bf16x8 bfr[BNF][2];
#pragma unroll
  for (int n = 0; n < BNF; ++n)
#pragma unroll
    for (int kk = 0; kk < 2; ++kk)
      bfr[n][kk] = ldsfrag(lB, wn * (16 * BNF) + n * 16 + lr, kk * 64 + lg * 16);
#pragma unroll
  for (int m = 0; m < 8; ++m) {
    const bf16x8 a0 = ldsfrag(lA, wm * 128 + m * 16 + lr, lg * 16);
    const bf16x8 a1 = ldsfrag(lA, wm * 128 + m * 16 + lr, 64 + lg * 16);
    __builtin_amdgcn_s_setprio(1);
#pragma unroll
    for (int n = 0; n < BNF; ++n) {
      acc[m][n] = MFMA16(a0, bfr[n][0], acc[m][n]);
      acc[m][n] = MFMA16(a1, bfr[n][1], acc[m][n]);
    }
    __builtin_amdgcn_s_setprio(0);
  }
}

template <int BNF>
static __device__ __forceinline__ void waitK() {
  if constexpr (BNF == 3) { VMCNT7(); } else { VMCNT8(); }
}

template <int EPI, int BNF>  // EPI 0: qkv scatter (V transposed), 1: fp32 partial, 2: bias+relu
__global__ __launch_bounds__(512, 2) void gemm256(
    const bf16* __restrict__ A, const bf16* __restrict__ Bt,
    int Kstr, int Kloop, int Nn, int nbx,
    const float* __restrict__ bias0, const float* __restrict__ bias1,
    const float* __restrict__ bias2, bf16* __restrict__ outb,
    float* __restrict__ pout,
    bf16* __restrict__ q_out, bf16* __restrict__ k_out, bf16* __restrict__ vt_out) {
  __shared__ __align__(16) bf16 ldsA[2][16384];       // 32KB each
  __shared__ __align__(16) bf16 ldsB[2][BNF * 4096];  // BNF*8KB each
  const int bz = blockIdx.y;
  const bf16* Abase = A + (size_t)bz * Kloop;
  const bf16* Bbase = Bt + (size_t)bz * Kloop;
  const int cpx = gridDim.x >> 3;
  const int wg = (blockIdx.x & 7) * cpx + (blockIdx.x >> 3);
  const int bx = wg % nbx, by = wg / nbx;
  const int tid = threadIdx.x;
  const int lane = tid & 63, wave = tid >> 6;
  const int lr = lane & 15, lg = lane >> 4;
  const int wm = wave >> 2, wn = wave & 3;
  const int m0 = by * 256, n0 = bx * (64 * BNF);

  const bf16* Ag = Abase + (size_t)m0 * Kstr;
  const bf16* Bg = Bbase + (size_t)n0 * Kstr;

  f32x4 acc[8][BNF] = {};
  const int T = Kloop >> 6;

  stage_tileT<BNF>(Ag, Bg, Kstr, 0, ldsA[0], ldsB[0], tid);
  stage_tileT<BNF>(Ag, Bg, Kstr, 1, ldsA[1], ldsB[1], tid);
  waitK<BNF>(); BAR(); SCH0();

  for (int t = 0; t + 3 < T; t += 2) {
    compute_tileT<BNF>(ldsA[0], ldsB[0], wm, wn, lr, lg, acc);
    BAR(); SCH0();
    stage_tileT<BNF>(Ag, Bg, Kstr, t + 2, ldsA[0], ldsB[0], tid);
    waitK<BNF>(); BAR(); SCH0();
    compute_tileT<BNF>(ldsA[1], ldsB[1], wm, wn, lr, lg, acc);
    BAR(); SCH0();
    stage_tileT<BNF>(Ag, Bg, Kstr, t + 3, ldsA[1], ldsB[1], tid);
    waitK<BNF>(); BAR(); SCH0();
  }
  compute_tileT<BNF>(ldsA[0], ldsB[0], wm, wn, lr, lg, acc);  // tile T-2
  VMCNT0(); BAR(); SCH0();                                    // tile T-1 landed
  compute_tileT<BNF>(ldsA[1], ldsB[1], wm, wn, lr, lg, acc);  // tile T-1

#pragma unroll
  for (int m = 0; m < 8; ++m)
#pragma unroll
    for (int n = 0; n < BNF; ++n) {
      if (EPI == 0) {
        // col range of this fragment is 16-aligned -> segment-uniform
        const int col = n0 + wn * (16 * BNF) + n * 16 + lr;
        const int which = col >> 10, hc = col & 1023;
        const int h = hc >> 6, hd = hc & 63;
        const int row0 = m0 + wm * 128 + m * 16 + lg * 4;
        const int b = row0 >> 11, s0 = row0 & 2047;
        if (which == 2) {
          // V: 4 consecutive s at fixed hd -> one bf16x4 in [bh][hd][s] layout
          bf16x4 o;
#pragma unroll
          for (int r = 0; r < 4; ++r) o[r] = (bf16)(acc[m][n][r] + bias2[hc]);
          *(bf16x4*)&vt_out[(((size_t)b * 16 + h) * 64 + hd) * 2048 + s0] = o;
        } else {
          const float* bs = (which == 0) ? bias0 : bias1;
          bf16* dst = (which == 0) ? q_out : k_out;
#pragma unroll
          for (int r = 0; r < 4; ++r)
            dst[(((size_t)b * 16 + h) * 2048 + s0 + r) * 64 + hd] =
                (bf16)(acc[m][n][r] + bs[hc]);
        }
      } else {
#pragma unroll
        for (int r = 0; r < 4; ++r) {
          const int row = m0 + wm * 128 + m * 16 + lg * 4 + r;
          const int col = n0 + wn * (16 * BNF) + n * 16 + lr;
          float val = acc[m][n][r];
          if (EPI == 1) {
            pout[(size_t)bz * 4096 * 1024 + (size_t)row * 1024 + col] = val;
          } else {
            val += bias0[col];
            outb[(size_t)row * Nn + col] = (bf16)(val > 0.f ? val : 0.f);
          }
        }
      }
    }
}

// ========== 128x128-tile 4-wave GEMM, counted-vmcnt (O-proj K=1024) =========
static __device__ __forceinline__ void stage128(const bf16* __restrict__ Ag,
    const bf16* __restrict__ Bg, int Kstr, int kt, bf16* lA, bf16* lB, int tid) {
  const char* dA = (const char*)lA + ((tid >> 6) << 10);
  const char* dB = (const char*)lB + ((tid >> 6) << 10);
#pragma unroll
  for (int s = 0; s < 4; ++s) {
    const int L = s * 4096 + tid * 16;
    const int off = L ^ (((L >> 7) & 7) << 4);
    load_lds16(Ag + (size_t)(off >> 7) * Kstr + kt * 64 + ((off & 127) >> 1),
               (void*)(dA + s * 4096));
  }
#pragma unroll
  for (int s = 0; s < 4; ++s) {
    const int L = s * 4096 + tid * 16;
    const int off = L ^ (((L >> 7) & 7) << 4);
    load_lds16(Bg + (size_t)(off >> 7) * Kstr + kt * 64 + ((off & 127) >> 1),
               (void*)(dB + s * 4096));
  }
}

static __device__ __forceinline__ void compute128(const bf16* lA, const bf16* lB,
    int wm, int wn, int lr, int lg, f32x4 (&acc)[4][4]) {
  bf16x8 bfr[4][2];
#pragma unroll
  for (int n = 0; n < 4; ++n)
#pragma unroll
    for (int kk = 0; kk < 2; ++kk)
      bfr[n][kk] = ldsfrag(lB, wn * 64 + n * 16 + lr, kk * 64 + lg * 16);
#pragma unroll
  for (int m = 0; m < 4; ++m) {
    const bf16x8 a0 = ldsfrag(lA, wm * 64 + m * 16 + lr, lg * 16);
    const bf16x8 a1 = ldsfrag(lA, wm * 64 + m * 16 + lr, 64 + lg * 16);
    __builtin_amdgcn_s_setprio(1);
#pragma unroll
    for (int n = 0; n < 4; ++n) {
      acc[m][n] = MFMA16(a0, bfr[n][0], acc[m][n]);
      acc[m][n] = MFMA16(a1, bfr[n][1], acc[m][n]);
    }
    __builtin_amdgcn_s_setprio(0);
  }
}

__global__ __launch_bounds__(256, 2) void gemm128p(
    const bf16* __restrict__ A, const bf16* __restrict__ Bt, int Kk,
    const float* __restrict__ bias, const bf16* __restrict__ resid,
    float* __restrict__ outf) {
  __shared__ __align__(16) bf16 lds[4][8192];    // A0,B0,A1,B1 (16KB each)
  const int cpx = gridDim.x >> 3;
  const int wg = (blockIdx.x & 7) * cpx + (blockIdx.x >> 3);
  const int bx = wg & 7, by = wg >> 3;           // nbx = 8 (N=1024)
  const int tid = threadIdx.x;
  const int lane = tid & 63, wave = tid >> 6;
  const int lr = lane & 15, lg = lane >> 4;
  const int wm = wave >> 1, wn = wave & 1;
  const int m0 = by * 128, n0 = bx * 128;

  const bf16* Ag = A + (size_t)m0 * Kk;
  const bf16* Bg = Bt + (size_t)n0 * Kk;
  bf16* LA0 = lds[0]; bf16* LB0 = lds[1];
  bf16* LA1 = lds[2]; bf16* LB1 = lds[3];

  f32x4 acc[4][4] = {};
  const int T = Kk >> 6;

  stage128(Ag, Bg, Kk, 0, LA0, LB0, tid);
  stage128(Ag, Bg, Kk, 1, LA1, LB1, tid);
  VMCNT8(); BAR(); SCH0();

  for (int t = 0; t + 3 < T; t += 2) {
    compute128(LA0, LB0, wm, wn, lr, lg, acc);
    BAR(); SCH0();
    stage128(Ag, Bg, Kk, t + 2, LA0, LB0, tid);
    VMCNT8(); BAR(); SCH0();
    compute128(LA1, LB1, wm, wn, lr, lg, acc);
    BAR(); SCH0();
    stage128(Ag, Bg, Kk, t + 3, LA1, LB1, tid);
    VMCNT8(); BAR(); SCH0();
  }
  compute128(LA0, LB0, wm, wn, lr, lg, acc);     // tile T-2
  VMCNT0(); BAR(); SCH0();                       // tile T-1 landed
  compute128(LA1, LB1, wm, wn, lr, lg, acc);     // tile T-1

#pragma unroll
  for (int m = 0; m < 4; ++m)
#pragma unroll
    for (int n = 0; n < 4; ++n)
#pragma unroll
      for (int r = 0; r < 4; ++r) {
        const int row = m0 + wm * 64 + m * 16 + lg * 4 + r;
        const int col = n0 + wn * 64 + n * 16 + lr;
        const float val = acc[m][n][r] + bias[col]
                        + (float)resid[(size_t)row * 1024 + col];
        outf[(size_t)row * 1024 + col] = val;
      }
}

// ------------------------- flash attention (per b,h) ------------------------
// 1D grid 256, XCD-swizzled: wid = (bid&7)*32 + (bid>>3). block: 1024 = 16
// waves; wave w owns q-rows [256*(wid&7) + 16w, +16). KVBLK=128 staged ONCE
// per 256 q-rows (16 waves share). One barrier-pair per chunk; two 64-key
// halves with no barrier between. Reg-staged K/V double buffer (1 load each
// per thread), slot-XOR swizzle, swapped QK^T, log2-domain softmax with
// defer-max. Chunk loop MUST be unrolled by 2 (rule #20, round-3 lesson).
__global__ __launch_bounds__(1024) void attn_kernel(const bf16* __restrict__ q,
                                                    const bf16* __restrict__ k,
                                                    const bf16* __restrict__ vt,
                                                    bf16* __restrict__ ctxo) {
  __shared__ __align__(16) bf16 Kl[128][64];  // rows = key, 8 slots of 16B
  __shared__ __align__(16) bf16 Vt[64][128];  // rows = hd, 16 slots of 16B
  __shared__ __align__(16) bf16 Pl[16][16][64];
  const int wid = ((blockIdx.x & 7) << 5) + (blockIdx.x >> 3);
  const int bh = wid >> 3;
  const int q0 = (wid & 7) * 256;
  const int tid = threadIdx.x;
  const int lane = tid & 63, w = tid >> 6;    // w = 0..15
  const int lr = lane & 15, lg = lane >> 4;
  const int swz = lr & 7;

  const bf16* qp = q + ((size_t)bh * 2048 + q0 + w * 16) * 64;
  bf16x8 qf0 = *(const bf16x8*)&qp[lr * 64 + lg * 8];
  bf16x8 qf1 = *(const bf16x8*)&qp[lr * 64 + lg * 8 + 32];
  const float qs = 0.18033688011112042f;      // (1/8)*log2(e)
#pragma unroll
  for (int j = 0; j < 8; ++j) {
    qf0[j] = (bf16)((float)qf0[j] * qs);
    qf1[j] = (bf16)((float)qf1[j] * qs);
  }
  bf16x8 ones8;
#pragma unroll
  for (int j = 0; j < 8; ++j) ones8[j] = (bf16)1.0f;

  const bf16* kbase = k + (size_t)bh * 2048 * 64;
  const bf16* vtb = vt + (size_t)bh * 64 * 2048;

  const int skr = tid >> 3;                     // 0..127
  const int skc = (tid & 7) * 8;
  const int skcs = skc ^ ((skr & 7) << 3);
  const int svr = tid >> 4;                     // 0..63
  const int svslot = tid & 15;
  const int svs = (svslot ^ (svr & 7)) * 8;

  f32x4 acc[4] = {};
  f32x4 accl = {};
  float mq = -1e30f;

  bf16x8 kr[2], vr[2];
  kr[0] = *(const bf16x8*)&kbase[(size_t)skr * 64 + skc];
  vr[0] = *(const bf16x8*)&vtb[(size_t)svr * 2048 + svslot * 8];

#pragma unroll 2
  for (int c = 0; c < 16; ++c) {
    const int pp = c & 1;
    *(bf16x8*)&Kl[skr][skcs] = kr[pp];
    *(bf16x8*)&Vt[svr][svs]  = vr[pp];
    if (c + 1 < 16) {
      const int key0n = (c + 1) * 128;
      kr[pp ^ 1] = *(const bf16x8*)&kbase[(size_t)(key0n + skr) * 64 + skc];
      vr[pp ^ 1] = *(const bf16x8*)&vtb[(size_t)svr * 2048 + key0n + svslot * 8];
    }
    __syncthreads();

#pragma unroll
    for (int hf = 0; hf < 2; ++hf) {
      f32x4 st[4];
      __builtin_amdgcn_s_setprio(1);
#pragma unroll
      for (int ks = 0; ks < 4; ++ks) {
        const bf16x8 kf0 = *(const bf16x8*)&Kl[hf * 64 + ks * 16 + lr][(lg ^ swz) << 3];
        const bf16x8 kf1 = *(const bf16x8*)&Kl[hf * 64 + ks * 16 + lr][((lg + 4) ^ swz) << 3];
        f32x4 sa = {};
        sa = MFMA16(kf0, qf0, sa);
        sa = MFMA16(kf1, qf1, sa);
        st[ks] = sa;
      }
      __builtin_amdgcn_s_setprio(0);

      float mx = st[0][0];
#pragma unroll
      for (int ks = 0; ks < 4; ++ks)
#pragma unroll
        for (int r = 0; r < 4; ++r) mx = fmaxf(mx, st[ks][r]);
      mx = fmaxf(mx, __shfl_xor(mx, 16));
      mx = fmaxf(mx, __shfl_xor(mx, 32));
      if (!__all(mx - mq <= 8.0f)) {               // defer-max (T13)
        const float resc = exp2f(mq - mx);
        mq = mx;
        float rq[4];
#pragma unroll
        for (int r = 0; r < 4; ++r) rq[r] = __shfl(resc, lg * 4 + r);
#pragma unroll
        for (int r = 0; r < 4; ++r) {
          accl[r] *= rq[r];
#pragma unroll
          for (int jn = 0; jn < 4; ++jn) acc[jn][r] *= rq[r];
        }
      }
#pragma unroll
      for (int ks = 0; ks < 4; ++ks) {             // P pack + vectorized store
        bf16x4 pk;
#pragma unroll
        for (int r = 0; r < 4; ++r) pk[r] = (bf16)exp2f(st[ks][r] - mq);
        const int col = (((ks * 2 + (lg >> 1)) ^ swz) << 3) + ((lg & 1) << 2);
        *(bf16x4*)&Pl[w][lr][col] = pk;
      }

      const bf16x8 pf0 = *(const bf16x8*)&Pl[w][lr][(lg ^ swz) << 3];
      const bf16x8 pf1 = *(const bf16x8*)&Pl[w][lr][((lg + 4) ^ swz) << 3];
      __builtin_amdgcn_s_setprio(1);
#pragma unroll
      for (int jn = 0; jn < 4; ++jn) {
        const bf16x8 vf0 = *(const bf16x8*)&Vt[jn * 16 + lr][hf * 64 + ((lg ^ swz) << 3)];
        const bf16x8 vf1 = *(const bf16x8*)&Vt[jn * 16 + lr][hf * 64 + (((lg + 4) ^ swz) << 3)];
        acc[jn] = MFMA16(pf0, vf0, acc[jn]);
        acc[jn] = MFMA16(pf1, vf1, acc[jn]);
      }
      accl = MFMA16(pf0, ones8, accl);
      accl = MFMA16(pf1, ones8, accl);
      __builtin_amdgcn_s_setprio(0);
    }
    __syncthreads();
  }

  const int bb = bh >> 4, hh = bh & 15;
#pragma unroll
  for (int r = 0; r < 4; ++r) {
    const float inv = 1.f / accl[r];
    const size_t rowg = (size_t)bb * 2048 + q0 + w * 16 + lg * 4 + r;
#pragma unroll
    for (int jn = 0; jn < 4; ++jn)
      ctxo[rowg * 1024 + hh * 64 + jn * 16 + lr] = (bf16)(acc[jn][r] * inv);
  }
}

// ---------- fused split-K reduce + bias + residual + LayerNorm --------------
template <int NP>
__global__ __launch_bounds__(256) void ln2_kernel(const float* __restrict__ p,
                                                  const bf16* __restrict__ resid,
                                                  const float* __restrict__ bias,
                                                  const float* __restrict__ g,
                                                  const float* __restrict__ be,
                                                  bf16* __restrict__ xo,
                                                  float* __restrict__ fout) {
  const int row = blockIdx.x, tid = threadIdx.x;
  const bf16x4 rv = *(const bf16x4*)&resid[(size_t)row * 1024 + tid * 4];
  const float4 bb = ((const float4*)bias)[tid];
  float4 v;
  v.x = bb.x + (float)rv[0];
  v.y = bb.y + (float)rv[1];
  v.z = bb.z + (float)rv[2];
  v.w = bb.w + (float)rv[3];
#pragma unroll
  for (int pl = 0; pl < NP; ++pl) {
    const float4 a = ((const float4*)(p + (size_t)pl * 4096 * 1024 + (size_t)row * 1024))[tid];
    v.x += a.x; v.y += a.y; v.z += a.z; v.w += a.w;
  }
  float s = v.x + v.y + v.z + v.w;
  float s2 = v.x * v.x + v.y * v.y + v.z * v.z + v.w * v.w;
#pragma unroll
  for (int o = 32; o > 0; o >>= 1) { s += __shfl_down(s, o); s2 += __shfl_down(s2, o); }
  __shared__ float red[8];
  if ((tid & 63) == 0) { red[tid >> 6] = s; red[4 + (tid >> 6)] = s2; }
  __syncthreads();
  s = red[0] + red[1] + red[2] + red[3];
  s2 = red[4] + red[5] + red[6] + red[7];
  const float mean = s * (1.f / 1024.f);
  const float var = s2 * (1.f / 1024.f) - mean * mean;
  const float rstd = rsqrtf(var + 1e-5f);
  const float4 gv = ((const float4*)g)[tid];
  const float4 bv = ((const float4*)be)[tid];
  float4 of;
  of.x = (v.x - mean) * rstd * gv.x + bv.x;
  of.y = (v.y - mean) * rstd * gv.y + bv.y;
  of.z = (v.z - mean) * rstd * gv.z + bv.z;
  of.w = (v.w - mean) * rstd * gv.w + bv.w;
  if (fout) {
    ((float4*)(fout + (size_t)row * 1024))[tid] = of;
  } else {
    bf16x4 o4;
    o4[0] = (bf16)of.x; o4[1] = (bf16)of.y; o4[2] = (bf16)of.z; o4[3] = (bf16)of.w;
    *(bf16x4*)&xo[(size_t)row * 1024 + tid * 4] = o4;
  }
}

// ------------------------------ LayerNorm (fp32 y) --------------------------
__global__ __launch_bounds__(256) void ln_kernel(const float* __restrict__ y,
                                                 const float* __restrict__ g,
                                                 const float* __restrict__ be,
                                                 bf16* __restrict__ xo) {
  const int row = blockIdx.x, tid = threadIdx.x;
  const float4 v = ((const float4*)(y + (size_t)row * 1024))[tid];
  float s = v.x + v.y + v.z + v.w;
  float s2 = v.x * v.x + v.y * v.y + v.z * v.z + v.w * v.w;
#pragma unroll
  for (int o = 32; o > 0; o >>= 1) { s += __shfl_down(s, o); s2 += __shfl_down(s2, o); }
  __shared__ float red[8];
  if ((tid & 63) == 0) { red[tid >> 6] = s; red[4 + (tid >> 6)] = s2; }
  __syncthreads();
  s = red[0] + red[1] + red[2] + red[3];
  s2 = red[4] + red[5] + red[6] + red[7];
  const float mean = s * (1.f / 1024.f);
  const float var = s2 * (1.f / 1024.f) - mean * mean;
  const float rstd = rsqrtf(var + 1e-5f);
  const float4 gv = ((const float4*)g)[tid];
  const float4 bv = ((const float4*)be)[tid];
  bf16x4 o4;
  o4[0] = (bf16)((v.x - mean) * rstd * gv.x + bv.x);
  o4[1] = (bf16)((v.y - mean) * rstd * gv.y + bv.y);
  o4[2] = (bf16)((v.z - mean) * rstd * gv.z + bv.z);
  o4[3] = (bf16)((v.w - mean) * rstd * gv.w + bv.w);
  *(bf16x4*)&xo[(size_t)row * 1024 + tid * 4] = o4;
}

// ----------------------------------------------------------------------------
extern "C" void kernel_launch(void* const* d_in, const int* in_sizes, int n_in,
                              void* d_out, int out_size, void* d_ws, size_t ws_size,
                              hipStream_t stream) {
  const int* tokens = (const int*)d_in[0];
  const float* emb = (const float*)d_in[2];
  const float* Wq = (const float*)d_in[3];
  const float* bq = (const float*)d_in[4];
  const float* Wk = (const float*)d_in[5];
  const float* bk = (const float*)d_in[6];
  const float* Wv = (const float*)d_in[7];
  const float* bv = (const float*)d_in[8];
  const float* Wo = (const float*)d_in[9];
  const float* bo = (const float*)d_in[10];
  const float* W1 = (const float*)d_in[11];
  const float* b1 = (const float*)d_in[12];
  const float* W2 = (const float*)d_in[13];
  const float* b2 = (const float*)d_in[14];
  const float* g1 = (const float*)d_in[15];
  const float* be1 = (const float*)d_in[16];
  const float* g2 = (const float*)d_in[17];
  const float* be2 = (const float*)d_in[18];

  char* p = (char*)d_ws;
  auto carve = [&](size_t bytes) { char* r = p; p += (bytes + 255) & ~(size_t)255; return r; };
  bf16* wt_qkv = (bf16*)carve((size_t)3072 * 1024 * 2);
  bf16* wt_o   = (bf16*)carve((size_t)1024 * 1024 * 2);
  bf16* wt_1   = (bf16*)carve((size_t)4096 * 1024 * 2);
  bf16* wt_2   = (bf16*)carve((size_t)1024 * 4096 * 2);
  bf16* xb     = (bf16*)carve((size_t)4096 * 1024 * 2);
  bf16* qb     = (bf16*)carve((size_t)4096 * 1024 * 2);
  bf16* kb     = (bf16*)carve((size_t)4096 * 1024 * 2);
  bf16* vtb    = (bf16*)carve((size_t)4096 * 1024 * 2);
  bf16* ctxb   = (bf16*)carve((size_t)4096 * 1024 * 2);
  float* yb    = (float*)carve((size_t)4096 * 1024 * 4);
  float* pb    = (float*)carve((size_t)4 * 4096 * 1024 * 4);   // split-K partials
  bf16* hb     = (bf16*)carve((size_t)4096 * 4096 * 2);

  embed_kernel<<<4096, 256, 0, stream>>>(tokens, emb, xb);

  for (int l = 0; l < 6; ++l) {
    // 64x64 tiles: jobs sized (K/64)*(N/64)
    TArgs ta;
    ta.j[0] = { Wq + (size_t)l * 1024 * 1024, wt_qkv,                  1024, 1024, 0 };
    ta.j[1] = { Wk + (size_t)l * 1024 * 1024, wt_qkv + 1024 * 1024,    1024, 1024, 256 };
    ta.j[2] = { Wv + (size_t)l * 1024 * 1024, wt_qkv + 2 * 1024 * 1024,1024, 1024, 512 };
    ta.j[3] = { Wo + (size_t)l * 1024 * 1024, wt_o,                    1024, 1024, 768 };
    ta.j[4] = { W1 + (size_t)l * 1024 * 4096, wt_1,                    1024, 4096, 1024 };
    ta.j[5] = { W2 + (size_t)l * 4096 * 1024, wt_2,                    4096, 1024, 2048 };
    wtrans_kernel<<<3072, 256, 0, stream>>>(ta);

    // QKV: 256x192 tile, nbx = 16 -> grid 256 = 1 block/CU. V written
    // directly transposed into vtb (vtrans fused).
    gemm256<0, 3><<<256, 512, 0, stream>>>(xb, wt_qkv, 1024, 1024, 3072, 16,
        bq + (size_t)l * 1024, bk + (size_t)l * 1024, bv + (size_t)l * 1024,
        nullptr, nullptr, qb, kb, vtb);

    // attn: 16-wave blocks, Q=256, grid 256
    attn_kernel<<<256, 1024, 0, stream>>>(qb, kb, vtb, ctxb);

    // O-proj: 128^2 pipeline, single-pass K=1024, grid 256
    gemm128p<<<256, 256, 0, stream>>>(ctxb, wt_o, 1024,
        bo + (size_t)l * 1024, xb, yb);
    ln_kernel<<<4096, 256, 0, stream>>>(yb, g1 + (size_t)l * 1024,
        be1 + (size_t)l * 1024, xb);

    // FFN1: 256^2 tile, grid 16x16 = 256
    gemm256<2, 4><<<256, 512, 0, stream>>>(xb, wt_1, 1024, 1024, 4096, 16,
        b1 + (size_t)l * 4096, nullptr, nullptr, hb,
        nullptr, nullptr, nullptr, nullptr);

    // FFN2: 256^2 tile split-K=4 (K-slice 1024), grid (64,4) = 256 blocks
    gemm256<1, 4><<<dim3(64, 4), 512, 0, stream>>>(hb, wt_2, 4096, 1024, 1024, 4,
        nullptr, nullptr, nullptr, nullptr, pb,
        nullptr, nullptr, nullptr);
    ln2_kernel<4><<<4096, 256, 0, stream>>>(pb, xb, b2 + (size_t)l * 1024,
        g2 + (size_t)l * 1024, be2 + (size_t)l * 1024, xb,
        (l == 5) ? (float*)d_out : nullptr);
  }
}